// Round 1
// baseline (628.188 us; speedup 1.0000x reference)
//
#include <hip/hip_runtime.h>

#define NEG 0.2f

__device__ __forceinline__ float leaky(float e) { return e > 0.f ? e : NEG * e; }

// ---------------- CSR build ----------------
__global__ void hist_kernel(const int* __restrict__ dst, int E, int* __restrict__ deg) {
    for (int e = blockIdx.x * blockDim.x + threadIdx.x; e < E; e += gridDim.x * blockDim.x)
        atomicAdd(&deg[dst[e]], 1);
}

__global__ void scan_kernel(const int* __restrict__ deg, int* __restrict__ offs, int n) {
    __shared__ int buf[1024];
    __shared__ int carry;
    int tid = threadIdx.x;
    if (tid == 0) { carry = 0; offs[0] = 0; }
    __syncthreads();
    for (int base = 0; base < n; base += 1024) {
        int v = (base + tid < n) ? deg[base + tid] : 0;
        buf[tid] = v;
        __syncthreads();
        for (int s = 1; s < 1024; s <<= 1) {
            int t = (tid >= s) ? buf[tid - s] : 0;
            __syncthreads();
            buf[tid] += t;
            __syncthreads();
        }
        int incl = buf[tid];
        int total = buf[1023];
        int c = carry;
        if (base + tid < n) offs[base + tid + 1] = c + incl;
        __syncthreads();
        if (tid == 0) carry = c + total;
        __syncthreads();
    }
}

__global__ void copy_int(const int* __restrict__ s, int* __restrict__ d, int n) {
    int i = blockIdx.x * blockDim.x + threadIdx.x;
    if (i < n) d[i] = s[i];
}

__global__ void scatter_kernel(const int* __restrict__ src, const int* __restrict__ dst, int E,
                               int* __restrict__ ctr, int* __restrict__ csr) {
    for (int e = blockIdx.x * blockDim.x + threadIdx.x; e < E; e += gridDim.x * blockDim.x) {
        int p = atomicAdd(&ctr[dst[e]], 1);
        csr[p] = src[e];
    }
}

// ---------------- GEMM: out[M x BN] = A[M x K] @ W[K x BN] (+bias) ----------------
template <int BN, int K>
__global__ __launch_bounds__(256) void gemm_kernel(const float* __restrict__ A,
                                                   const float* __restrict__ W,
                                                   const float* __restrict__ bias,
                                                   float* __restrict__ out, int M) {
    __shared__ float As[32][65];   // [k][row], padded
    __shared__ float Ws[32][BN];   // [k][col]
    const int t = threadIdx.x;
    const int tx = t & 15, ty = t >> 4;
    const int m0 = blockIdx.x * 64;

    float acc[4][BN / 16];
#pragma unroll
    for (int i = 0; i < 4; ++i)
#pragma unroll
        for (int j = 0; j < BN / 16; ++j) acc[i][j] = 0.f;

    for (int kk = 0; kk < K; kk += 32) {
#pragma unroll
        for (int i = 0; i < 2; ++i) {  // A tile: 64 rows x 32 k
            int idx = t + i * 256;
            int r = idx >> 3, c4 = (idx & 7) * 4;
            float4 v = make_float4(0.f, 0.f, 0.f, 0.f);
            if (m0 + r < M) v = *(const float4*)&A[(size_t)(m0 + r) * K + kk + c4];
            As[c4 + 0][r] = v.x; As[c4 + 1][r] = v.y; As[c4 + 2][r] = v.z; As[c4 + 3][r] = v.w;
        }
#pragma unroll
        for (int i = 0; i < BN / 32; ++i) {  // W tile: 32 k x BN cols
            int idx = t + i * 256;
            int r = idx / (BN / 4), c4 = (idx % (BN / 4)) * 4;
            *(float4*)&Ws[r][c4] = *(const float4*)&W[(size_t)(kk + r) * BN + c4];
        }
        __syncthreads();
#pragma unroll
        for (int k = 0; k < 32; ++k) {
            float a[4];
#pragma unroll
            for (int i = 0; i < 4; ++i) a[i] = As[k][ty * 4 + i];
#pragma unroll
            for (int j = 0; j < BN / 16; ++j) {
                float w = Ws[k][tx + j * 16];
#pragma unroll
                for (int i = 0; i < 4; ++i) acc[i][j] += a[i] * w;
            }
        }
        __syncthreads();
    }
#pragma unroll
    for (int i = 0; i < 4; ++i) {
        int row = m0 + ty * 4 + i;
        if (row < M) {
#pragma unroll
            for (int j = 0; j < BN / 16; ++j) {
                int c = tx + j * 16;
                out[(size_t)row * BN + c] = acc[i][j] + (bias ? bias[c] : 0.f);
            }
        }
    }
}

// ---------------- attention coefficients ----------------
__global__ void att1_kernel(const float* __restrict__ h1, const float* __restrict__ asrc,
                            const float* __restrict__ adst, float* __restrict__ a_s,
                            float* __restrict__ a_d, int n) {
    int i = blockIdx.x * blockDim.x + threadIdx.x;  // over n*3
    if (i >= n * 3) return;
    int node = i / 3, h = i % 3;
    const float4* hb = (const float4*)&h1[(size_t)node * 96 + h * 32];
    const float4* sb = (const float4*)&asrc[h * 32];
    const float4* db = (const float4*)&adst[h * 32];
    float s = 0.f, d = 0.f;
#pragma unroll
    for (int q = 0; q < 8; ++q) {
        float4 hv = hb[q], sv = sb[q], dv = db[q];
        s += hv.x * sv.x + hv.y * sv.y + hv.z * sv.z + hv.w * sv.w;
        d += hv.x * dv.x + hv.y * dv.y + hv.z * dv.z + hv.w * dv.w;
    }
    a_s[i] = s; a_d[i] = d;
}

__global__ void att2_kernel(const float* __restrict__ h2, const float* __restrict__ asrc,
                            const float* __restrict__ adst, float* __restrict__ a_s,
                            float* __restrict__ a_d, int n) {
    int w = (blockIdx.x * blockDim.x + threadIdx.x) >> 6;
    int lane = threadIdx.x & 63;
    if (w >= n) return;
    float v0 = h2[(size_t)w * 128 + lane], v1 = h2[(size_t)w * 128 + 64 + lane];
    float s = v0 * asrc[lane] + v1 * asrc[64 + lane];
    float d = v0 * adst[lane] + v1 * adst[64 + lane];
#pragma unroll
    for (int m = 32; m >= 1; m >>= 1) { s += __shfl_xor(s, m); d += __shfl_xor(d, m); }
    if (lane == 0) { a_s[w] = s; a_d[w] = d; }
}

// ---------------- GAT aggregation (one wave per destination node) ----------------
__global__ __launch_bounds__(256) void gat1_agg(const float* __restrict__ h1,
                                                const float* __restrict__ a_s,
                                                const float* __restrict__ a_d,
                                                const int* __restrict__ offs,
                                                const int* __restrict__ csr,
                                                const float* __restrict__ b1,
                                                float* __restrict__ out, int n) {
    int node = blockIdx.x * 4 + (threadIdx.x >> 6);
    if (node >= n) return;
    int lane = threadIdx.x & 63;
    int beg = offs[node], end = offs[node + 1];
    float ad0 = a_d[node * 3 + 0], ad1 = a_d[node * 3 + 1], ad2 = a_d[node * 3 + 2];
    float es0 = leaky(a_s[node * 3 + 0] + ad0);
    float es1 = leaky(a_s[node * 3 + 1] + ad1);
    float es2 = leaky(a_s[node * 3 + 2] + ad2);
    float m0 = es0, m1 = es1, m2 = es2;
    for (int j = beg + lane; j < end; j += 64) {
        int s = csr[j];
        m0 = fmaxf(m0, leaky(a_s[s * 3 + 0] + ad0));
        m1 = fmaxf(m1, leaky(a_s[s * 3 + 1] + ad1));
        m2 = fmaxf(m2, leaky(a_s[s * 3 + 2] + ad2));
    }
#pragma unroll
    for (int sh = 32; sh >= 1; sh >>= 1) {
        m0 = fmaxf(m0, __shfl_xor(m0, sh));
        m1 = fmaxf(m1, __shfl_xor(m1, sh));
        m2 = fmaxf(m2, __shfl_xor(m2, sh));
    }
    // self loop
    float w0 = __expf(es0 - m0), w1 = __expf(es1 - m1), w2 = __expf(es2 - m2);
    float den0 = w0, den1 = w1, den2 = w2;
    float wa = (lane < 32) ? w0 : w1;
    float acc0 = wa * h1[(size_t)node * 96 + lane];
    float acc1 = (lane < 32) ? w2 * h1[(size_t)node * 96 + 64 + lane] : 0.f;
    for (int j = beg; j < end; ++j) {
        int s = csr[j];
        float e0 = __expf(leaky(a_s[s * 3 + 0] + ad0) - m0);
        float e1 = __expf(leaky(a_s[s * 3 + 1] + ad1) - m1);
        float e2 = __expf(leaky(a_s[s * 3 + 2] + ad2) - m2);
        den0 += e0; den1 += e1; den2 += e2;
        float w = (lane < 32) ? e0 : e1;
        acc0 += w * h1[(size_t)s * 96 + lane];
        if (lane < 32) acc1 += e2 * h1[(size_t)s * 96 + 64 + lane];
    }
    float den = (lane < 32) ? den0 : den1;
    out[(size_t)node * 96 + lane] = acc0 / (den + 1e-16f) + b1[lane];
    if (lane < 32)
        out[(size_t)node * 96 + 64 + lane] = acc1 / (den2 + 1e-16f) + b1[64 + lane];
}

__global__ __launch_bounds__(256) void gat2_agg(const float* __restrict__ h2,
                                                const float* __restrict__ a_s,
                                                const float* __restrict__ a_d,
                                                const int* __restrict__ offs,
                                                const int* __restrict__ csr,
                                                const float* __restrict__ b2,
                                                float* __restrict__ out, int n) {
    int node = blockIdx.x * 4 + (threadIdx.x >> 6);
    if (node >= n) return;
    int lane = threadIdx.x & 63;
    int beg = offs[node], end = offs[node + 1];
    float ad = a_d[node];
    float es = leaky(a_s[node] + ad);
    float m = es;
    for (int j = beg + lane; j < end; j += 64) {
        int s = csr[j];
        m = fmaxf(m, leaky(a_s[s] + ad));
    }
#pragma unroll
    for (int sh = 32; sh >= 1; sh >>= 1) m = fmaxf(m, __shfl_xor(m, sh));
    float wSelf = __expf(es - m);
    float den = wSelf;
    float acc0 = wSelf * h2[(size_t)node * 128 + lane];
    float acc1 = wSelf * h2[(size_t)node * 128 + 64 + lane];
    for (int j = beg; j < end; ++j) {
        int s = csr[j];
        float w = __expf(leaky(a_s[s] + ad) - m);
        den += w;
        acc0 += w * h2[(size_t)s * 128 + lane];
        acc1 += w * h2[(size_t)s * 128 + 64 + lane];
    }
    float inv = 1.f / (den + 1e-16f);
    out[(size_t)node * 128 + lane] = acc0 * inv + b2[lane];
    out[(size_t)node * 128 + 64 + lane] = acc1 * inv + b2[64 + lane];
}

// ---------------- BatchNorm stats + fused epilogue ----------------
__global__ __launch_bounds__(256) void bn_stats(const float* __restrict__ x,
                                                float* __restrict__ sums, int n, int rpb) {
    __shared__ float sh[256];
    int c = threadIdx.x & 127, half = threadIdx.x >> 7;
    int r0 = blockIdx.x * rpb;
    int r1 = min(r0 + rpb, n);
    float s = 0.f, q = 0.f;
    for (int r = r0 + half; r < r1; r += 2) {
        float v = x[(size_t)r * 128 + c];
        s += v; q += v * v;
    }
    sh[threadIdx.x] = s;
    __syncthreads();
    if (half == 0) atomicAdd(&sums[c], s + sh[threadIdx.x + 128]);
    __syncthreads();
    sh[threadIdx.x] = q;
    __syncthreads();
    if (half == 0) atomicAdd(&sums[128 + c], q + sh[threadIdx.x + 128]);
}

__global__ void final_kernel(const float* __restrict__ out2, const float* __restrict__ resid,
                             const float* __restrict__ sums, const float* __restrict__ gamma,
                             const float* __restrict__ beta, float* __restrict__ out, int n) {
    int i = blockIdx.x * blockDim.x + threadIdx.x;  // over n*32 float4s
    if (i >= n * 32) return;
    int c0 = (i & 31) * 4;
    float invN = 1.f / (float)n;
    float4 v = ((const float4*)out2)[i];
    float4 r = ((const float4*)resid)[i];
    float4 o;
    float* vp = &v.x;
    float* rp = &r.x;
    float* op = &o.x;
#pragma unroll
    for (int q = 0; q < 4; ++q) {
        int c = c0 + q;
        float mu = sums[c] * invN;
        float var = sums[128 + c] * invN - mu * mu;
        float y = (vp[q] - mu) * rsqrtf(var + 1e-5f) * gamma[c] + beta[c];
        y = fmaxf(y, 0.f);
        op[q] = y + rp[q];
    }
    ((float4*)out)[i] = o;
}

extern "C" void kernel_launch(void* const* d_in, const int* in_sizes, int n_in,
                              void* d_out, int out_size, void* d_ws, size_t ws_size,
                              hipStream_t stream) {
    const float* x     = (const float*)d_in[0];
    const int*   ei    = (const int*)d_in[1];
    const float* W1    = (const float*)d_in[2];
    const float* asrc1 = (const float*)d_in[3];
    const float* adst1 = (const float*)d_in[4];
    const float* b1    = (const float*)d_in[5];
    const float* W2    = (const float*)d_in[6];
    const float* asrc2 = (const float*)d_in[7];
    const float* adst2 = (const float*)d_in[8];
    const float* b2    = (const float*)d_in[9];
    const float* gamma = (const float*)d_in[10];
    const float* beta  = (const float*)d_in[11];
    const float* Wres  = (const float*)d_in[12];
    const float* bres  = (const float*)d_in[13];

    const int n = in_sizes[0] / 128;  // 50000
    const int E = in_sizes[1] / 2;    // 800000

    char* ws = (char*)d_ws;
    size_t off = 0;
    auto alloc = [&](size_t bytes) {
        void* p = ws + off;
        off = (off + bytes + 255) & ~(size_t)255;
        return p;
    };
    float* resid = (float*)alloc((size_t)n * 128 * 4);
    float* h1    = (float*)alloc((size_t)n * 96 * 4);
    float* out1  = (float*)alloc((size_t)n * 96 * 4);
    float* h2    = (float*)alloc((size_t)n * 128 * 4);
    float* out2  = (float*)alloc((size_t)n * 128 * 4);
    float* as1   = (float*)alloc((size_t)n * 3 * 4);
    float* ad1   = (float*)alloc((size_t)n * 3 * 4);
    float* as2   = (float*)alloc((size_t)n * 4);
    float* ad2   = (float*)alloc((size_t)n * 4);
    float* sums  = (float*)alloc(256 * 4);
    int* deg     = (int*)alloc((size_t)n * 4);
    int* offs    = (int*)alloc((size_t)(n + 1) * 4);
    int* ctr     = (int*)alloc((size_t)n * 4);
    int* csr     = (int*)alloc((size_t)E * 4);

    hipMemsetAsync(deg, 0, (size_t)n * 4, stream);
    hipMemsetAsync(sums, 0, 256 * 4, stream);

    const int* srcIdx = ei;
    const int* dstIdx = ei + E;

    hist_kernel<<<2048, 256, 0, stream>>>(dstIdx, E, deg);
    scan_kernel<<<1, 1024, 0, stream>>>(deg, offs, n);
    copy_int<<<(n + 255) / 256, 256, 0, stream>>>(offs, ctr, n);
    scatter_kernel<<<2048, 256, 0, stream>>>(srcIdx, dstIdx, E, ctr, csr);

    gemm_kernel<96, 128><<<(n + 63) / 64, 256, 0, stream>>>(x, W1, nullptr, h1, n);
    att1_kernel<<<(n * 3 + 255) / 256, 256, 0, stream>>>(h1, asrc1, adst1, as1, ad1, n);
    gemm_kernel<128, 128><<<(n + 63) / 64, 256, 0, stream>>>(x, Wres, bres, resid, n);
    gat1_agg<<<(n + 3) / 4, 256, 0, stream>>>(h1, as1, ad1, offs, csr, b1, out1, n);
    gemm_kernel<128, 96><<<(n + 63) / 64, 256, 0, stream>>>(out1, W2, nullptr, h2, n);
    att2_kernel<<<(n + 3) / 4, 256, 0, stream>>>(h2, asrc2, adst2, as2, ad2, n);
    gat2_agg<<<(n + 3) / 4, 256, 0, stream>>>(h2, as2, ad2, offs, csr, b2, out2, n);
    bn_stats<<<(n + 511) / 512, 256, 0, stream>>>(out2, sums, n, 512);
    final_kernel<<<(n * 32 + 255) / 256, 256, 0, stream>>>(out2, resid, sums, gamma, beta,
                                                           (float*)d_out, n);
}

// Round 2
// 433.484 us; speedup vs baseline: 1.4492x; 1.4492x over previous
//
#include <hip/hip_runtime.h>

#define NEG 0.2f
#define NEG_INF (-1e30f)

__device__ __forceinline__ float leaky(float e) { return e > 0.f ? e : NEG * e; }

// ---------------- CSR build ----------------
__global__ void hist_kernel(const int* __restrict__ dst, int E, int* __restrict__ deg) {
    for (int e = blockIdx.x * blockDim.x + threadIdx.x; e < E; e += gridDim.x * blockDim.x)
        atomicAdd(&deg[dst[e]], 1);
}

// two-level scan: per-block inclusive scan + block sums
__global__ void scan_part(const int* __restrict__ deg, int* __restrict__ offs,
                          int* __restrict__ bsum, int n) {
    __shared__ int buf[256];
    int i = blockIdx.x * 256 + threadIdx.x;
    int v = (i < n) ? deg[i] : 0;
    buf[threadIdx.x] = v;
    __syncthreads();
    for (int s = 1; s < 256; s <<= 1) {
        int t = (threadIdx.x >= s) ? buf[threadIdx.x - s] : 0;
        __syncthreads();
        buf[threadIdx.x] += t;
        __syncthreads();
    }
    if (i < n) offs[i + 1] = buf[threadIdx.x];
    if (threadIdx.x == 255) bsum[blockIdx.x] = buf[255];
}

__global__ void scan_bsum(int* __restrict__ bsum, int nb) {
    __shared__ int buf[256];
    int v = (threadIdx.x < nb) ? bsum[threadIdx.x] : 0;
    buf[threadIdx.x] = v;
    __syncthreads();
    for (int s = 1; s < 256; s <<= 1) {
        int t = (threadIdx.x >= s) ? buf[threadIdx.x - s] : 0;
        __syncthreads();
        buf[threadIdx.x] += t;
        __syncthreads();
    }
    if (threadIdx.x < nb) bsum[threadIdx.x] = buf[threadIdx.x] - v;  // exclusive
}

__global__ void scan_add(int* __restrict__ offs, const int* __restrict__ bsum, int n) {
    int i = blockIdx.x * 256 + threadIdx.x;
    if (i < n) offs[i + 1] += bsum[blockIdx.x];
    if (i == 0) offs[0] = 0;
}

__global__ void copy_int(const int* __restrict__ s, int* __restrict__ d, int n) {
    int i = blockIdx.x * blockDim.x + threadIdx.x;
    if (i < n) d[i] = s[i];
}

__global__ void scatter_kernel(const int* __restrict__ src, const int* __restrict__ dst, int E,
                               int* __restrict__ ctr, int* __restrict__ csr) {
    for (int e = blockIdx.x * blockDim.x + threadIdx.x; e < E; e += gridDim.x * blockDim.x) {
        int p = atomicAdd(&ctr[dst[e]], 1);
        csr[p] = src[e];
    }
}

// ---------------- GEMM: out[M x BN] = A[M x K] @ W[K x BN] (+bias) ----------------
template <int BN, int K>
__global__ __launch_bounds__(256) void gemm_kernel(const float* __restrict__ A,
                                                   const float* __restrict__ W,
                                                   const float* __restrict__ bias,
                                                   float* __restrict__ out, int M) {
    __shared__ float As[32][65];
    __shared__ float Ws[32][BN];
    const int t = threadIdx.x;
    const int tx = t & 15, ty = t >> 4;
    const int m0 = blockIdx.x * 64;

    float acc[4][BN / 16];
#pragma unroll
    for (int i = 0; i < 4; ++i)
#pragma unroll
        for (int j = 0; j < BN / 16; ++j) acc[i][j] = 0.f;

    for (int kk = 0; kk < K; kk += 32) {
#pragma unroll
        for (int i = 0; i < 2; ++i) {
            int idx = t + i * 256;
            int r = idx >> 3, c4 = (idx & 7) * 4;
            float4 v = make_float4(0.f, 0.f, 0.f, 0.f);
            if (m0 + r < M) v = *(const float4*)&A[(size_t)(m0 + r) * K + kk + c4];
            As[c4 + 0][r] = v.x; As[c4 + 1][r] = v.y; As[c4 + 2][r] = v.z; As[c4 + 3][r] = v.w;
        }
#pragma unroll
        for (int i = 0; i < BN / 32; ++i) {
            int idx = t + i * 256;
            int r = idx / (BN / 4), c4 = (idx % (BN / 4)) * 4;
            *(float4*)&Ws[r][c4] = *(const float4*)&W[(size_t)(kk + r) * BN + c4];
        }
        __syncthreads();
#pragma unroll
        for (int k = 0; k < 32; ++k) {
            float a[4];
#pragma unroll
            for (int i = 0; i < 4; ++i) a[i] = As[k][ty * 4 + i];
#pragma unroll
            for (int j = 0; j < BN / 16; ++j) {
                float w = Ws[k][tx + j * 16];
#pragma unroll
                for (int i = 0; i < 4; ++i) acc[i][j] += a[i] * w;
            }
        }
        __syncthreads();
    }
#pragma unroll
    for (int i = 0; i < 4; ++i) {
        int row = m0 + ty * 4 + i;
        if (row < M) {
#pragma unroll
            for (int j = 0; j < BN / 16; ++j) {
                int c = tx + j * 16;
                out[(size_t)row * BN + c] = acc[i][j] + (bias ? bias[c] : 0.f);
            }
        }
    }
}

// ---------------- attention coefficients ----------------
__global__ void att1_kernel(const float* __restrict__ h1, const float* __restrict__ asrc,
                            const float* __restrict__ adst, float* __restrict__ a_s,
                            float* __restrict__ a_d, int n) {
    int i = blockIdx.x * blockDim.x + threadIdx.x;  // over n*3
    if (i >= n * 3) return;
    int node = i / 3, h = i % 3;
    const float4* hb = (const float4*)&h1[(size_t)node * 96 + h * 32];
    const float4* sb = (const float4*)&asrc[h * 32];
    const float4* db = (const float4*)&adst[h * 32];
    float s = 0.f, d = 0.f;
#pragma unroll
    for (int q = 0; q < 8; ++q) {
        float4 hv = hb[q], sv = sb[q], dv = db[q];
        s += hv.x * sv.x + hv.y * sv.y + hv.z * sv.z + hv.w * sv.w;
        d += hv.x * dv.x + hv.y * dv.y + hv.z * dv.z + hv.w * dv.w;
    }
    a_s[i] = s; a_d[i] = d;
}

__global__ void att2_kernel(const float* __restrict__ h2, const float* __restrict__ asrc,
                            const float* __restrict__ adst, float* __restrict__ a_s,
                            float* __restrict__ a_d, int n) {
    int w = (blockIdx.x * blockDim.x + threadIdx.x) >> 6;
    int lane = threadIdx.x & 63;
    if (w >= n) return;
    float v0 = h2[(size_t)w * 128 + lane], v1 = h2[(size_t)w * 128 + 64 + lane];
    float s = v0 * asrc[lane] + v1 * asrc[64 + lane];
    float d = v0 * adst[lane] + v1 * adst[64 + lane];
#pragma unroll
    for (int m = 32; m >= 1; m >>= 1) { s += __shfl_xor(s, m); d += __shfl_xor(d, m); }
    if (lane == 0) { a_s[w] = s; a_d[w] = d; }
}

// ---------------- GAT aggregation v2: lane-parallel exp, lean serial gather ----------------
// gat1: 96 channels (3 heads x 32). Lanes 0..47 each own a float2 channel pair.
__global__ __launch_bounds__(256) void gat1_agg(const float* __restrict__ h1,
                                                const float* __restrict__ a_s,
                                                const float* __restrict__ a_d,
                                                const int* __restrict__ offs,
                                                const int* __restrict__ csr,
                                                const float* __restrict__ b1,
                                                float* __restrict__ out, int n) {
    int node = blockIdx.x * 4 + (threadIdx.x >> 6);
    if (node >= n) return;
    int lane = threadIdx.x & 63;
    int beg = offs[node], end = offs[node + 1];
    int deg = end - beg;
    float ad0 = a_d[node * 3 + 0], ad1 = a_d[node * 3 + 1], ad2 = a_d[node * 3 + 2];
    float es0 = leaky(a_s[node * 3 + 0] + ad0);
    float es1 = leaky(a_s[node * 3 + 1] + ad1);
    float es2 = leaky(a_s[node * 3 + 2] + ad2);

    // self-loop init
    float2 acc = make_float2(0.f, 0.f);
    float2 hv0 = make_float2(0.f, 0.f);
    if (lane < 48) hv0 = *(const float2*)&h1[(size_t)node * 96 + 2 * lane];

    float den0, den1, den2;
    float m0, m1, m2;

    if (deg <= 64) {
        // ---- fast path: everything fits in one tile; cache leaky values in regs
        int s = -1;
        float l0 = NEG_INF, l1 = NEG_INF, l2 = NEG_INF;
        if (lane < deg) {
            s = csr[beg + lane];
            l0 = leaky(a_s[s * 3 + 0] + ad0);
            l1 = leaky(a_s[s * 3 + 1] + ad1);
            l2 = leaky(a_s[s * 3 + 2] + ad2);
        }
        m0 = l0; m1 = l1; m2 = l2;
#pragma unroll
        for (int sh = 32; sh >= 1; sh >>= 1) {
            m0 = fmaxf(m0, __shfl_xor(m0, sh));
            m1 = fmaxf(m1, __shfl_xor(m1, sh));
            m2 = fmaxf(m2, __shfl_xor(m2, sh));
        }
        m0 = fmaxf(m0, es0); m1 = fmaxf(m1, es1); m2 = fmaxf(m2, es2);
        float e0 = 0.f, e1 = 0.f, e2 = 0.f;
        if (lane < deg) {
            e0 = __expf(l0 - m0); e1 = __expf(l1 - m1); e2 = __expf(l2 - m2);
        }
        float w0 = __expf(es0 - m0), w1 = __expf(es1 - m1), w2 = __expf(es2 - m2);
        den0 = w0; den1 = w1; den2 = w2;
        float wSelf = (lane < 16) ? w0 : ((lane < 32) ? w1 : w2);
        acc.x = wSelf * hv0.x; acc.y = wSelf * hv0.y;

        int jj = 0;
        for (; jj + 1 < deg; jj += 2) {
            int sA = __shfl(s, jj), sB = __shfl(s, jj + 1);
            float a0 = __shfl(e0, jj), a1 = __shfl(e1, jj), a2 = __shfl(e2, jj);
            float c0 = __shfl(e0, jj + 1), c1 = __shfl(e1, jj + 1), c2 = __shfl(e2, jj + 1);
            den0 += a0 + c0; den1 += a1 + c1; den2 += a2 + c2;
            if (lane < 48) {
                float2 ha = *(const float2*)&h1[(size_t)sA * 96 + 2 * lane];
                float2 hb = *(const float2*)&h1[(size_t)sB * 96 + 2 * lane];
                float wA = (lane < 16) ? a0 : ((lane < 32) ? a1 : a2);
                float wB = (lane < 16) ? c0 : ((lane < 32) ? c1 : c2);
                acc.x += wA * ha.x + wB * hb.x;
                acc.y += wA * ha.y + wB * hb.y;
            }
        }
        if (jj < deg) {
            int sA = __shfl(s, jj);
            float a0 = __shfl(e0, jj), a1 = __shfl(e1, jj), a2 = __shfl(e2, jj);
            den0 += a0; den1 += a1; den2 += a2;
            if (lane < 48) {
                float2 ha = *(const float2*)&h1[(size_t)sA * 96 + 2 * lane];
                float wA = (lane < 16) ? a0 : ((lane < 32) ? a1 : a2);
                acc.x += wA * ha.x; acc.y += wA * ha.y;
            }
        }
    } else {
        // ---- generic path: global max first, then tiles of 64
        m0 = es0; m1 = es1; m2 = es2;
        for (int j = beg + lane; j < end; j += 64) {
            int s = csr[j];
            m0 = fmaxf(m0, leaky(a_s[s * 3 + 0] + ad0));
            m1 = fmaxf(m1, leaky(a_s[s * 3 + 1] + ad1));
            m2 = fmaxf(m2, leaky(a_s[s * 3 + 2] + ad2));
        }
#pragma unroll
        for (int sh = 32; sh >= 1; sh >>= 1) {
            m0 = fmaxf(m0, __shfl_xor(m0, sh));
            m1 = fmaxf(m1, __shfl_xor(m1, sh));
            m2 = fmaxf(m2, __shfl_xor(m2, sh));
        }
        float w0 = __expf(es0 - m0), w1 = __expf(es1 - m1), w2 = __expf(es2 - m2);
        den0 = w0; den1 = w1; den2 = w2;
        float wSelf = (lane < 16) ? w0 : ((lane < 32) ? w1 : w2);
        acc.x = wSelf * hv0.x; acc.y = wSelf * hv0.y;
        for (int t0 = beg; t0 < end; t0 += 64) {
            int cnt = min(64, end - t0);
            int s = -1;
            float e0 = 0.f, e1 = 0.f, e2 = 0.f;
            if (lane < cnt) {
                s = csr[t0 + lane];
                e0 = __expf(leaky(a_s[s * 3 + 0] + ad0) - m0);
                e1 = __expf(leaky(a_s[s * 3 + 1] + ad1) - m1);
                e2 = __expf(leaky(a_s[s * 3 + 2] + ad2) - m2);
            }
            for (int jj = 0; jj < cnt; ++jj) {
                int sA = __shfl(s, jj);
                float a0 = __shfl(e0, jj), a1 = __shfl(e1, jj), a2 = __shfl(e2, jj);
                den0 += a0; den1 += a1; den2 += a2;
                if (lane < 48) {
                    float2 ha = *(const float2*)&h1[(size_t)sA * 96 + 2 * lane];
                    float wA = (lane < 16) ? a0 : ((lane < 32) ? a1 : a2);
                    acc.x += wA * ha.x; acc.y += wA * ha.y;
                }
            }
        }
    }

    if (lane < 48) {
        float den = (lane < 16) ? den0 : ((lane < 32) ? den1 : den2);
        float inv = 1.f / (den + 1e-16f);
        float2 o;
        o.x = acc.x * inv + b1[2 * lane];
        o.y = acc.y * inv + b1[2 * lane + 1];
        *(float2*)&out[(size_t)node * 96 + 2 * lane] = o;
    }
}

// gat2: 128 channels, 1 head. All 64 lanes own a float2 pair.
__global__ __launch_bounds__(256) void gat2_agg(const float* __restrict__ h2,
                                                const float* __restrict__ a_s,
                                                const float* __restrict__ a_d,
                                                const int* __restrict__ offs,
                                                const int* __restrict__ csr,
                                                const float* __restrict__ b2,
                                                float* __restrict__ out, int n) {
    int node = blockIdx.x * 4 + (threadIdx.x >> 6);
    if (node >= n) return;
    int lane = threadIdx.x & 63;
    int beg = offs[node], end = offs[node + 1];
    int deg = end - beg;
    float ad = a_d[node];
    float es = leaky(a_s[node] + ad);
    float2 hv0 = *(const float2*)&h2[(size_t)node * 128 + 2 * lane];
    float2 acc;
    float den, m;

    if (deg <= 64) {
        int s = -1;
        float l = NEG_INF;
        if (lane < deg) {
            s = csr[beg + lane];
            l = leaky(a_s[s] + ad);
        }
        m = l;
#pragma unroll
        for (int sh = 32; sh >= 1; sh >>= 1) m = fmaxf(m, __shfl_xor(m, sh));
        m = fmaxf(m, es);
        float e = (lane < deg) ? __expf(l - m) : 0.f;
        float wSelf = __expf(es - m);
        den = wSelf;
        acc.x = wSelf * hv0.x; acc.y = wSelf * hv0.y;

        int jj = 0;
        for (; jj + 1 < deg; jj += 2) {
            int sA = __shfl(s, jj), sB = __shfl(s, jj + 1);
            float wA = __shfl(e, jj), wB = __shfl(e, jj + 1);
            den += wA + wB;
            float2 ha = *(const float2*)&h2[(size_t)sA * 128 + 2 * lane];
            float2 hb = *(const float2*)&h2[(size_t)sB * 128 + 2 * lane];
            acc.x += wA * ha.x + wB * hb.x;
            acc.y += wA * ha.y + wB * hb.y;
        }
        if (jj < deg) {
            int sA = __shfl(s, jj);
            float wA = __shfl(e, jj);
            den += wA;
            float2 ha = *(const float2*)&h2[(size_t)sA * 128 + 2 * lane];
            acc.x += wA * ha.x; acc.y += wA * ha.y;
        }
    } else {
        m = es;
        for (int j = beg + lane; j < end; j += 64) {
            int s = csr[j];
            m = fmaxf(m, leaky(a_s[s] + ad));
        }
#pragma unroll
        for (int sh = 32; sh >= 1; sh >>= 1) m = fmaxf(m, __shfl_xor(m, sh));
        float wSelf = __expf(es - m);
        den = wSelf;
        acc.x = wSelf * hv0.x; acc.y = wSelf * hv0.y;
        for (int t0 = beg; t0 < end; t0 += 64) {
            int cnt = min(64, end - t0);
            int s = -1;
            float e = 0.f;
            if (lane < cnt) {
                s = csr[t0 + lane];
                e = __expf(leaky(a_s[s] + ad) - m);
            }
            for (int jj = 0; jj < cnt; ++jj) {
                int sA = __shfl(s, jj);
                float wA = __shfl(e, jj);
                den += wA;
                float2 ha = *(const float2*)&h2[(size_t)sA * 128 + 2 * lane];
                acc.x += wA * ha.x; acc.y += wA * ha.y;
            }
        }
    }

    float inv = 1.f / (den + 1e-16f);
    float2 o;
    o.x = acc.x * inv + b2[2 * lane];
    o.y = acc.y * inv + b2[2 * lane + 1];
    *(float2*)&out[(size_t)node * 128 + 2 * lane] = o;
}

// ---------------- BatchNorm stats + fused epilogue ----------------
__global__ __launch_bounds__(256) void bn_stats(const float* __restrict__ x,
                                                float* __restrict__ sums, int n, int rpb) {
    __shared__ float sh[256];
    int c = threadIdx.x & 127, half = threadIdx.x >> 7;
    int r0 = blockIdx.x * rpb;
    int r1 = min(r0 + rpb, n);
    float s = 0.f, q = 0.f;
    for (int r = r0 + half; r < r1; r += 2) {
        float v = x[(size_t)r * 128 + c];
        s += v; q += v * v;
    }
    sh[threadIdx.x] = s;
    __syncthreads();
    if (half == 0) atomicAdd(&sums[c], s + sh[threadIdx.x + 128]);
    __syncthreads();
    sh[threadIdx.x] = q;
    __syncthreads();
    if (half == 0) atomicAdd(&sums[128 + c], q + sh[threadIdx.x + 128]);
}

__global__ void final_kernel(const float* __restrict__ out2, const float* __restrict__ resid,
                             const float* __restrict__ sums, const float* __restrict__ gamma,
                             const float* __restrict__ beta, float* __restrict__ out, int n) {
    int i = blockIdx.x * blockDim.x + threadIdx.x;  // over n*32 float4s
    if (i >= n * 32) return;
    int c0 = (i & 31) * 4;
    float invN = 1.f / (float)n;
    float4 v = ((const float4*)out2)[i];
    float4 r = ((const float4*)resid)[i];
    float4 o;
    float* vp = &v.x;
    float* rp = &r.x;
    float* op = &o.x;
#pragma unroll
    for (int q = 0; q < 4; ++q) {
        int c = c0 + q;
        float mu = sums[c] * invN;
        float var = sums[128 + c] * invN - mu * mu;
        float y = (vp[q] - mu) * rsqrtf(var + 1e-5f) * gamma[c] + beta[c];
        y = fmaxf(y, 0.f);
        op[q] = y + rp[q];
    }
    ((float4*)out)[i] = o;
}

extern "C" void kernel_launch(void* const* d_in, const int* in_sizes, int n_in,
                              void* d_out, int out_size, void* d_ws, size_t ws_size,
                              hipStream_t stream) {
    const float* x     = (const float*)d_in[0];
    const int*   ei    = (const int*)d_in[1];
    const float* W1    = (const float*)d_in[2];
    const float* asrc1 = (const float*)d_in[3];
    const float* adst1 = (const float*)d_in[4];
    const float* b1    = (const float*)d_in[5];
    const float* W2    = (const float*)d_in[6];
    const float* asrc2 = (const float*)d_in[7];
    const float* adst2 = (const float*)d_in[8];
    const float* b2    = (const float*)d_in[9];
    const float* gamma = (const float*)d_in[10];
    const float* beta  = (const float*)d_in[11];
    const float* Wres  = (const float*)d_in[12];
    const float* bres  = (const float*)d_in[13];

    const int n = in_sizes[0] / 128;  // 50000
    const int E = in_sizes[1] / 2;    // 800000

    char* ws = (char*)d_ws;
    size_t off = 0;
    auto alloc = [&](size_t bytes) {
        void* p = ws + off;
        off = (off + bytes + 255) & ~(size_t)255;
        return p;
    };
    float* resid = (float*)alloc((size_t)n * 128 * 4);
    float* h1    = (float*)alloc((size_t)n * 96 * 4);
    float* out1  = (float*)alloc((size_t)n * 96 * 4);
    float* h2    = (float*)alloc((size_t)n * 128 * 4);
    float* out2  = (float*)alloc((size_t)n * 128 * 4);
    float* as1   = (float*)alloc((size_t)n * 3 * 4);
    float* ad1   = (float*)alloc((size_t)n * 3 * 4);
    float* as2   = (float*)alloc((size_t)n * 4);
    float* ad2   = (float*)alloc((size_t)n * 4);
    float* sums  = (float*)alloc(256 * 4);
    int* deg     = (int*)alloc((size_t)n * 4);
    int* offs    = (int*)alloc((size_t)(n + 1) * 4);
    int* ctr     = (int*)alloc((size_t)n * 4);
    int* bsum    = (int*)alloc(256 * 4);
    int* csr     = (int*)alloc((size_t)E * 4);

    hipMemsetAsync(deg, 0, (size_t)n * 4, stream);
    hipMemsetAsync(sums, 0, 256 * 4, stream);

    const int* srcIdx = ei;
    const int* dstIdx = ei + E;
    const int nb = (n + 255) / 256;  // 196

    hist_kernel<<<2048, 256, 0, stream>>>(dstIdx, E, deg);
    scan_part<<<nb, 256, 0, stream>>>(deg, offs, bsum, n);
    scan_bsum<<<1, 256, 0, stream>>>(bsum, nb);
    scan_add<<<nb, 256, 0, stream>>>(offs, bsum, n);
    copy_int<<<(n + 255) / 256, 256, 0, stream>>>(offs, ctr, n);
    scatter_kernel<<<2048, 256, 0, stream>>>(srcIdx, dstIdx, E, ctr, csr);

    gemm_kernel<96, 128><<<(n + 63) / 64, 256, 0, stream>>>(x, W1, nullptr, h1, n);
    att1_kernel<<<(n * 3 + 255) / 256, 256, 0, stream>>>(h1, asrc1, adst1, as1, ad1, n);
    gemm_kernel<128, 128><<<(n + 63) / 64, 256, 0, stream>>>(x, Wres, bres, resid, n);
    gat1_agg<<<(n + 3) / 4, 256, 0, stream>>>(h1, as1, ad1, offs, csr, b1, out1, n);
    gemm_kernel<128, 96><<<(n + 63) / 64, 256, 0, stream>>>(out1, W2, nullptr, h2, n);
    att2_kernel<<<(n + 3) / 4, 256, 0, stream>>>(h2, asrc2, adst2, as2, ad2, n);
    gat2_agg<<<(n + 3) / 4, 256, 0, stream>>>(h2, as2, ad2, offs, csr, b2, out2, n);
    bn_stats<<<(n + 511) / 512, 256, 0, stream>>>(out2, sums, n, 512);
    final_kernel<<<(n * 32 + 255) / 256, 256, 0, stream>>>(out2, resid, sums, gamma, beta,
                                                           (float*)d_out, n);
}

// Round 3
// 412.303 us; speedup vs baseline: 1.5236x; 1.0514x over previous
//
#include <hip/hip_runtime.h>

#define NEG 0.2f
#define NEG_INF (-1e30f)

__device__ __forceinline__ float leaky(float e) { return e > 0.f ? e : NEG * e; }

// ---------------- CSR build ----------------
__global__ void hist_kernel(const int* __restrict__ dst, int E, int* __restrict__ deg) {
    for (int e = blockIdx.x * blockDim.x + threadIdx.x; e < E; e += gridDim.x * blockDim.x)
        atomicAdd(&deg[dst[e]], 1);
}

// two-level scan: per-block inclusive scan + block sums
__global__ void scan_part(const int* __restrict__ deg, int* __restrict__ offs,
                          int* __restrict__ bsum, int n) {
    __shared__ int buf[256];
    int i = blockIdx.x * 256 + threadIdx.x;
    int v = (i < n) ? deg[i] : 0;
    buf[threadIdx.x] = v;
    __syncthreads();
    for (int s = 1; s < 256; s <<= 1) {
        int t = (threadIdx.x >= s) ? buf[threadIdx.x - s] : 0;
        __syncthreads();
        buf[threadIdx.x] += t;
        __syncthreads();
    }
    if (i < n) offs[i + 1] = buf[threadIdx.x];
    if (threadIdx.x == 255) bsum[blockIdx.x] = buf[255];
}

__global__ void scan_bsum(int* __restrict__ bsum, int nb) {
    __shared__ int buf[256];
    int v = (threadIdx.x < nb) ? bsum[threadIdx.x] : 0;
    buf[threadIdx.x] = v;
    __syncthreads();
    for (int s = 1; s < 256; s <<= 1) {
        int t = (threadIdx.x >= s) ? buf[threadIdx.x - s] : 0;
        __syncthreads();
        buf[threadIdx.x] += t;
        __syncthreads();
    }
    if (threadIdx.x < nb) bsum[threadIdx.x] = buf[threadIdx.x] - v;  // exclusive
}

__global__ void scan_add(int* __restrict__ offs, const int* __restrict__ bsum, int n) {
    int i = blockIdx.x * 256 + threadIdx.x;
    if (i < n) offs[i + 1] += bsum[blockIdx.x];
    if (i == 0) offs[0] = 0;
}

__global__ void copy_int(const int* __restrict__ s, int* __restrict__ d, int n) {
    int i = blockIdx.x * blockDim.x + threadIdx.x;
    if (i < n) d[i] = s[i];
}

__global__ void scatter_kernel(const int* __restrict__ src, const int* __restrict__ dst, int E,
                               int* __restrict__ ctr, int* __restrict__ csr) {
    for (int e = blockIdx.x * blockDim.x + threadIdx.x; e < E; e += gridDim.x * blockDim.x) {
        int p = atomicAdd(&ctr[dst[e]], 1);
        csr[p] = src[e];
    }
}

// ---------------- GEMM: out[M x BN] = A[M x K] @ W[K x BN] (+bias) ----------------
template <int BN, int K>
__global__ __launch_bounds__(256) void gemm_kernel(const float* __restrict__ A,
                                                   const float* __restrict__ W,
                                                   const float* __restrict__ bias,
                                                   float* __restrict__ out, int M) {
    __shared__ float As[32][65];
    __shared__ float Ws[32][BN];
    const int t = threadIdx.x;
    const int tx = t & 15, ty = t >> 4;
    const int m0 = blockIdx.x * 64;

    float acc[4][BN / 16];
#pragma unroll
    for (int i = 0; i < 4; ++i)
#pragma unroll
        for (int j = 0; j < BN / 16; ++j) acc[i][j] = 0.f;

    for (int kk = 0; kk < K; kk += 32) {
#pragma unroll
        for (int i = 0; i < 2; ++i) {
            int idx = t + i * 256;
            int r = idx >> 3, c4 = (idx & 7) * 4;
            float4 v = make_float4(0.f, 0.f, 0.f, 0.f);
            if (m0 + r < M) v = *(const float4*)&A[(size_t)(m0 + r) * K + kk + c4];
            As[c4 + 0][r] = v.x; As[c4 + 1][r] = v.y; As[c4 + 2][r] = v.z; As[c4 + 3][r] = v.w;
        }
#pragma unroll
        for (int i = 0; i < BN / 32; ++i) {
            int idx = t + i * 256;
            int r = idx / (BN / 4), c4 = (idx % (BN / 4)) * 4;
            *(float4*)&Ws[r][c4] = *(const float4*)&W[(size_t)(kk + r) * BN + c4];
        }
        __syncthreads();
#pragma unroll
        for (int k = 0; k < 32; ++k) {
            float a[4];
#pragma unroll
            for (int i = 0; i < 4; ++i) a[i] = As[k][ty * 4 + i];
#pragma unroll
            for (int j = 0; j < BN / 16; ++j) {
                float w = Ws[k][tx + j * 16];
#pragma unroll
                for (int i = 0; i < 4; ++i) acc[i][j] += a[i] * w;
            }
        }
        __syncthreads();
    }
#pragma unroll
    for (int i = 0; i < 4; ++i) {
        int row = m0 + ty * 4 + i;
        if (row < M) {
#pragma unroll
            for (int j = 0; j < BN / 16; ++j) {
                int c = tx + j * 16;
                out[(size_t)row * BN + c] = acc[i][j] + (bias ? bias[c] : 0.f);
            }
        }
    }
}

// ---------------- attention coefficients ----------------
__global__ void att1_kernel(const float* __restrict__ h1, const float* __restrict__ asrc,
                            const float* __restrict__ adst, float* __restrict__ a_s,
                            float* __restrict__ a_d, int n) {
    int i = blockIdx.x * blockDim.x + threadIdx.x;  // over n*3
    if (i >= n * 3) return;
    int node = i / 3, h = i % 3;
    const float4* hb = (const float4*)&h1[(size_t)node * 96 + h * 32];
    const float4* sb = (const float4*)&asrc[h * 32];
    const float4* db = (const float4*)&adst[h * 32];
    float s = 0.f, d = 0.f;
#pragma unroll
    for (int q = 0; q < 8; ++q) {
        float4 hv = hb[q], sv = sb[q], dv = db[q];
        s += hv.x * sv.x + hv.y * sv.y + hv.z * sv.z + hv.w * sv.w;
        d += hv.x * dv.x + hv.y * dv.y + hv.z * dv.z + hv.w * dv.w;
    }
    a_s[i] = s; a_d[i] = d;
}

__global__ void att2_kernel(const float* __restrict__ h2, const float* __restrict__ asrc,
                            const float* __restrict__ adst, float* __restrict__ a_s,
                            float* __restrict__ a_d, int n) {
    int w = (blockIdx.x * blockDim.x + threadIdx.x) >> 6;
    int lane = threadIdx.x & 63;
    if (w >= n) return;
    float v0 = h2[(size_t)w * 128 + lane], v1 = h2[(size_t)w * 128 + 64 + lane];
    float s = v0 * asrc[lane] + v1 * asrc[64 + lane];
    float d = v0 * adst[lane] + v1 * adst[64 + lane];
#pragma unroll
    for (int m = 32; m >= 1; m >>= 1) { s += __shfl_xor(s, m); d += __shfl_xor(d, m); }
    if (lane == 0) { a_s[w] = s; a_d[w] = d; }
}

// ---------------- GAT aggregation: lane-parallel exp, lean serial gather ----------------
__global__ __launch_bounds__(256) void gat1_agg(const float* __restrict__ h1,
                                                const float* __restrict__ a_s,
                                                const float* __restrict__ a_d,
                                                const int* __restrict__ offs,
                                                const int* __restrict__ csr,
                                                const float* __restrict__ b1,
                                                float* __restrict__ out, int n) {
    int node = blockIdx.x * 4 + (threadIdx.x >> 6);
    if (node >= n) return;
    int lane = threadIdx.x & 63;
    int beg = offs[node], end = offs[node + 1];
    int deg = end - beg;
    float ad0 = a_d[node * 3 + 0], ad1 = a_d[node * 3 + 1], ad2 = a_d[node * 3 + 2];
    float es0 = leaky(a_s[node * 3 + 0] + ad0);
    float es1 = leaky(a_s[node * 3 + 1] + ad1);
    float es2 = leaky(a_s[node * 3 + 2] + ad2);

    float2 acc = make_float2(0.f, 0.f);
    float2 hv0 = make_float2(0.f, 0.f);
    if (lane < 48) hv0 = *(const float2*)&h1[(size_t)node * 96 + 2 * lane];

    float den0, den1, den2;
    float m0, m1, m2;

    if (deg <= 64) {
        int s = -1;
        float l0 = NEG_INF, l1 = NEG_INF, l2 = NEG_INF;
        if (lane < deg) {
            s = csr[beg + lane];
            l0 = leaky(a_s[s * 3 + 0] + ad0);
            l1 = leaky(a_s[s * 3 + 1] + ad1);
            l2 = leaky(a_s[s * 3 + 2] + ad2);
        }
        m0 = l0; m1 = l1; m2 = l2;
#pragma unroll
        for (int sh = 32; sh >= 1; sh >>= 1) {
            m0 = fmaxf(m0, __shfl_xor(m0, sh));
            m1 = fmaxf(m1, __shfl_xor(m1, sh));
            m2 = fmaxf(m2, __shfl_xor(m2, sh));
        }
        m0 = fmaxf(m0, es0); m1 = fmaxf(m1, es1); m2 = fmaxf(m2, es2);
        float e0 = 0.f, e1 = 0.f, e2 = 0.f;
        if (lane < deg) {
            e0 = __expf(l0 - m0); e1 = __expf(l1 - m1); e2 = __expf(l2 - m2);
        }
        float w0 = __expf(es0 - m0), w1 = __expf(es1 - m1), w2 = __expf(es2 - m2);
        den0 = w0; den1 = w1; den2 = w2;
        float wSelf = (lane < 16) ? w0 : ((lane < 32) ? w1 : w2);
        acc.x = wSelf * hv0.x; acc.y = wSelf * hv0.y;

        int jj = 0;
        for (; jj + 1 < deg; jj += 2) {
            int sA = __shfl(s, jj), sB = __shfl(s, jj + 1);
            float a0 = __shfl(e0, jj), a1 = __shfl(e1, jj), a2 = __shfl(e2, jj);
            float c0 = __shfl(e0, jj + 1), c1 = __shfl(e1, jj + 1), c2 = __shfl(e2, jj + 1);
            den0 += a0 + c0; den1 += a1 + c1; den2 += a2 + c2;
            if (lane < 48) {
                float2 ha = *(const float2*)&h1[(size_t)sA * 96 + 2 * lane];
                float2 hb = *(const float2*)&h1[(size_t)sB * 96 + 2 * lane];
                float wA = (lane < 16) ? a0 : ((lane < 32) ? a1 : a2);
                float wB = (lane < 16) ? c0 : ((lane < 32) ? c1 : c2);
                acc.x += wA * ha.x + wB * hb.x;
                acc.y += wA * ha.y + wB * hb.y;
            }
        }
        if (jj < deg) {
            int sA = __shfl(s, jj);
            float a0 = __shfl(e0, jj), a1 = __shfl(e1, jj), a2 = __shfl(e2, jj);
            den0 += a0; den1 += a1; den2 += a2;
            if (lane < 48) {
                float2 ha = *(const float2*)&h1[(size_t)sA * 96 + 2 * lane];
                float wA = (lane < 16) ? a0 : ((lane < 32) ? a1 : a2);
                acc.x += wA * ha.x; acc.y += wA * ha.y;
            }
        }
    } else {
        m0 = es0; m1 = es1; m2 = es2;
        for (int j = beg + lane; j < end; j += 64) {
            int s = csr[j];
            m0 = fmaxf(m0, leaky(a_s[s * 3 + 0] + ad0));
            m1 = fmaxf(m1, leaky(a_s[s * 3 + 1] + ad1));
            m2 = fmaxf(m2, leaky(a_s[s * 3 + 2] + ad2));
        }
#pragma unroll
        for (int sh = 32; sh >= 1; sh >>= 1) {
            m0 = fmaxf(m0, __shfl_xor(m0, sh));
            m1 = fmaxf(m1, __shfl_xor(m1, sh));
            m2 = fmaxf(m2, __shfl_xor(m2, sh));
        }
        float w0 = __expf(es0 - m0), w1 = __expf(es1 - m1), w2 = __expf(es2 - m2);
        den0 = w0; den1 = w1; den2 = w2;
        float wSelf = (lane < 16) ? w0 : ((lane < 32) ? w1 : w2);
        acc.x = wSelf * hv0.x; acc.y = wSelf * hv0.y;
        for (int t0 = beg; t0 < end; t0 += 64) {
            int cnt = min(64, end - t0);
            int s = -1;
            float e0 = 0.f, e1 = 0.f, e2 = 0.f;
            if (lane < cnt) {
                s = csr[t0 + lane];
                e0 = __expf(leaky(a_s[s * 3 + 0] + ad0) - m0);
                e1 = __expf(leaky(a_s[s * 3 + 1] + ad1) - m1);
                e2 = __expf(leaky(a_s[s * 3 + 2] + ad2) - m2);
            }
            for (int jj = 0; jj < cnt; ++jj) {
                int sA = __shfl(s, jj);
                float a0 = __shfl(e0, jj), a1 = __shfl(e1, jj), a2 = __shfl(e2, jj);
                den0 += a0; den1 += a1; den2 += a2;
                if (lane < 48) {
                    float2 ha = *(const float2*)&h1[(size_t)sA * 96 + 2 * lane];
                    float wA = (lane < 16) ? a0 : ((lane < 32) ? a1 : a2);
                    acc.x += wA * ha.x; acc.y += wA * ha.y;
                }
            }
        }
    }

    if (lane < 48) {
        float den = (lane < 16) ? den0 : ((lane < 32) ? den1 : den2);
        float inv = 1.f / (den + 1e-16f);
        float2 o;
        o.x = acc.x * inv + b1[2 * lane];
        o.y = acc.y * inv + b1[2 * lane + 1];
        *(float2*)&out[(size_t)node * 96 + 2 * lane] = o;
    }
}

__global__ __launch_bounds__(256) void gat2_agg(const float* __restrict__ h2,
                                                const float* __restrict__ a_s,
                                                const float* __restrict__ a_d,
                                                const int* __restrict__ offs,
                                                const int* __restrict__ csr,
                                                const float* __restrict__ b2,
                                                float* __restrict__ out, int n) {
    int node = blockIdx.x * 4 + (threadIdx.x >> 6);
    if (node >= n) return;
    int lane = threadIdx.x & 63;
    int beg = offs[node], end = offs[node + 1];
    int deg = end - beg;
    float ad = a_d[node];
    float es = leaky(a_s[node] + ad);
    float2 hv0 = *(const float2*)&h2[(size_t)node * 128 + 2 * lane];
    float2 acc;
    float den, m;

    if (deg <= 64) {
        int s = -1;
        float l = NEG_INF;
        if (lane < deg) {
            s = csr[beg + lane];
            l = leaky(a_s[s] + ad);
        }
        m = l;
#pragma unroll
        for (int sh = 32; sh >= 1; sh >>= 1) m = fmaxf(m, __shfl_xor(m, sh));
        m = fmaxf(m, es);
        float e = (lane < deg) ? __expf(l - m) : 0.f;
        float wSelf = __expf(es - m);
        den = wSelf;
        acc.x = wSelf * hv0.x; acc.y = wSelf * hv0.y;

        int jj = 0;
        for (; jj + 1 < deg; jj += 2) {
            int sA = __shfl(s, jj), sB = __shfl(s, jj + 1);
            float wA = __shfl(e, jj), wB = __shfl(e, jj + 1);
            den += wA + wB;
            float2 ha = *(const float2*)&h2[(size_t)sA * 128 + 2 * lane];
            float2 hb = *(const float2*)&h2[(size_t)sB * 128 + 2 * lane];
            acc.x += wA * ha.x + wB * hb.x;
            acc.y += wA * ha.y + wB * hb.y;
        }
        if (jj < deg) {
            int sA = __shfl(s, jj);
            float wA = __shfl(e, jj);
            den += wA;
            float2 ha = *(const float2*)&h2[(size_t)sA * 128 + 2 * lane];
            acc.x += wA * ha.x; acc.y += wA * ha.y;
        }
    } else {
        m = es;
        for (int j = beg + lane; j < end; j += 64) {
            int s = csr[j];
            m = fmaxf(m, leaky(a_s[s] + ad));
        }
#pragma unroll
        for (int sh = 32; sh >= 1; sh >>= 1) m = fmaxf(m, __shfl_xor(m, sh));
        float wSelf = __expf(es - m);
        den = wSelf;
        acc.x = wSelf * hv0.x; acc.y = wSelf * hv0.y;
        for (int t0 = beg; t0 < end; t0 += 64) {
            int cnt = min(64, end - t0);
            int s = -1;
            float e = 0.f;
            if (lane < cnt) {
                s = csr[t0 + lane];
                e = __expf(leaky(a_s[s] + ad) - m);
            }
            for (int jj = 0; jj < cnt; ++jj) {
                int sA = __shfl(s, jj);
                float wA = __shfl(e, jj);
                den += wA;
                float2 ha = *(const float2*)&h2[(size_t)sA * 128 + 2 * lane];
                acc.x += wA * ha.x; acc.y += wA * ha.y;
            }
        }
    }

    float inv = 1.f / (den + 1e-16f);
    float2 o;
    o.x = acc.x * inv + b2[2 * lane];
    o.y = acc.y * inv + b2[2 * lane + 1];
    *(float2*)&out[(size_t)node * 128 + 2 * lane] = o;
}

// ---------------- BatchNorm stats (wide grid, float4, LDS tree) ----------------
__global__ __launch_bounds__(256) void bn_stats(const float* __restrict__ x,
                                                float* __restrict__ sums, int n, int rpb) {
    __shared__ float4 shs[8][32];
    __shared__ float4 shq[8][32];
    int tid = threadIdx.x;
    int c = tid & 31;   // float4 column (4 channels)
    int rg = tid >> 5;  // row group 0..7
    int r0 = blockIdx.x * rpb;
    int r1 = min(r0 + rpb, n);
    float4 s = make_float4(0.f, 0.f, 0.f, 0.f);
    float4 q = make_float4(0.f, 0.f, 0.f, 0.f);
    for (int r = r0 + rg; r < r1; r += 8) {
        float4 v = ((const float4*)x)[(size_t)r * 32 + c];
        s.x += v.x; s.y += v.y; s.z += v.z; s.w += v.w;
        q.x += v.x * v.x; q.y += v.y * v.y; q.z += v.z * v.z; q.w += v.w * v.w;
    }
    shs[rg][c] = s; shq[rg][c] = q;
    __syncthreads();
#pragma unroll
    for (int h = 4; h >= 1; h >>= 1) {
        if (rg < h) {
            float4 a = shs[rg + h][c], b = shq[rg + h][c];
            float4 cs = shs[rg][c], cq = shq[rg][c];
            cs.x += a.x; cs.y += a.y; cs.z += a.z; cs.w += a.w;
            cq.x += b.x; cq.y += b.y; cq.z += b.z; cq.w += b.w;
            shs[rg][c] = cs; shq[rg][c] = cq;
        }
        __syncthreads();
    }
    if (rg == 0) {
        float4 S = shs[0][c], Q = shq[0][c];
        atomicAdd(&sums[c * 4 + 0], S.x);
        atomicAdd(&sums[c * 4 + 1], S.y);
        atomicAdd(&sums[c * 4 + 2], S.z);
        atomicAdd(&sums[c * 4 + 3], S.w);
        atomicAdd(&sums[128 + c * 4 + 0], Q.x);
        atomicAdd(&sums[128 + c * 4 + 1], Q.y);
        atomicAdd(&sums[128 + c * 4 + 2], Q.z);
        atomicAdd(&sums[128 + c * 4 + 3], Q.w);
    }
}

__global__ void bn_finalize(const float* __restrict__ sums, const float* __restrict__ gamma,
                            const float* __restrict__ beta, float* __restrict__ ss, int n) {
    int c = threadIdx.x;  // 128
    float invN = 1.f / (float)n;
    float mu = sums[c] * invN;
    float var = sums[128 + c] * invN - mu * mu;
    float g = gamma[c] * rsqrtf(var + 1e-5f);
    ss[c] = g;
    ss[128 + c] = beta[c] - mu * g;
}

__global__ void final_kernel(const float* __restrict__ out2, const float* __restrict__ resid,
                             const float* __restrict__ ss, float* __restrict__ out, int n) {
    int i = blockIdx.x * blockDim.x + threadIdx.x;  // over n*32 float4s
    if (i >= n * 32) return;
    int c0 = (i & 31) * 4;
    float4 v = ((const float4*)out2)[i];
    float4 r = ((const float4*)resid)[i];
    float4 o;
    const float* vp = &v.x;
    const float* rp = &r.x;
    float* op = &o.x;
#pragma unroll
    for (int q = 0; q < 4; ++q) {
        int c = c0 + q;
        float y = vp[q] * ss[c] + ss[128 + c];
        y = fmaxf(y, 0.f);
        op[q] = y + rp[q];
    }
    ((float4*)out)[i] = o;
}

extern "C" void kernel_launch(void* const* d_in, const int* in_sizes, int n_in,
                              void* d_out, int out_size, void* d_ws, size_t ws_size,
                              hipStream_t stream) {
    const float* x     = (const float*)d_in[0];
    const int*   ei    = (const int*)d_in[1];
    const float* W1    = (const float*)d_in[2];
    const float* asrc1 = (const float*)d_in[3];
    const float* adst1 = (const float*)d_in[4];
    const float* b1    = (const float*)d_in[5];
    const float* W2    = (const float*)d_in[6];
    const float* asrc2 = (const float*)d_in[7];
    const float* adst2 = (const float*)d_in[8];
    const float* b2    = (const float*)d_in[9];
    const float* gamma = (const float*)d_in[10];
    const float* beta  = (const float*)d_in[11];
    const float* Wres  = (const float*)d_in[12];
    const float* bres  = (const float*)d_in[13];

    const int n = in_sizes[0] / 128;  // 50000
    const int E = in_sizes[1] / 2;    // 800000

    char* ws = (char*)d_ws;
    size_t off = 0;
    auto alloc = [&](size_t bytes) {
        void* p = ws + off;
        off = (off + bytes + 255) & ~(size_t)255;
        return p;
    };
    float* resid = (float*)alloc((size_t)n * 128 * 4);
    float* h1    = (float*)alloc((size_t)n * 96 * 4);
    float* out1  = (float*)alloc((size_t)n * 96 * 4);
    float* h2    = (float*)alloc((size_t)n * 128 * 4);
    float* out2  = (float*)alloc((size_t)n * 128 * 4);
    float* as1   = (float*)alloc((size_t)n * 3 * 4);
    float* ad1   = (float*)alloc((size_t)n * 3 * 4);
    float* as2   = (float*)alloc((size_t)n * 4);
    float* ad2   = (float*)alloc((size_t)n * 4);
    float* sums  = (float*)alloc(256 * 4);
    float* ss    = (float*)alloc(256 * 4);
    int* deg     = (int*)alloc((size_t)n * 4);
    int* offs    = (int*)alloc((size_t)(n + 1) * 4);
    int* ctr     = (int*)alloc((size_t)n * 4);
    int* bsum    = (int*)alloc(256 * 4);
    int* csr     = (int*)alloc((size_t)E * 4);

    hipMemsetAsync(deg, 0, (size_t)n * 4, stream);
    hipMemsetAsync(sums, 0, 256 * 4, stream);

    const int* srcIdx = ei;
    const int* dstIdx = ei + E;
    const int nb = (n + 255) / 256;  // 196

    hist_kernel<<<2048, 256, 0, stream>>>(dstIdx, E, deg);
    scan_part<<<nb, 256, 0, stream>>>(deg, offs, bsum, n);
    scan_bsum<<<1, 256, 0, stream>>>(bsum, nb);
    scan_add<<<nb, 256, 0, stream>>>(offs, bsum, n);
    copy_int<<<(n + 255) / 256, 256, 0, stream>>>(offs, ctr, n);
    scatter_kernel<<<2048, 256, 0, stream>>>(srcIdx, dstIdx, E, ctr, csr);

    gemm_kernel<96, 128><<<(n + 63) / 64, 256, 0, stream>>>(x, W1, nullptr, h1, n);
    att1_kernel<<<(n * 3 + 255) / 256, 256, 0, stream>>>(h1, asrc1, adst1, as1, ad1, n);
    gemm_kernel<128, 128><<<(n + 63) / 64, 256, 0, stream>>>(x, Wres, bres, resid, n);
    gat1_agg<<<(n + 3) / 4, 256, 0, stream>>>(h1, as1, ad1, offs, csr, b1, out1, n);
    gemm_kernel<128, 96><<<(n + 63) / 64, 256, 0, stream>>>(out1, W2, nullptr, h2, n);
    att2_kernel<<<(n + 3) / 4, 256, 0, stream>>>(h2, asrc2, adst2, as2, ad2, n);
    gat2_agg<<<(n + 3) / 4, 256, 0, stream>>>(h2, as2, ad2, offs, csr, b2, out2, n);
    bn_stats<<<512, 256, 0, stream>>>(out2, sums, n, (n + 511) / 512);
    bn_finalize<<<1, 128, 0, stream>>>(sums, gamma, beta, ss, n);
    final_kernel<<<(n * 32 + 255) / 256, 256, 0, stream>>>(out2, resid, ss, (float*)d_out, n);
}

// Round 4
// 360.927 us; speedup vs baseline: 1.7405x; 1.1423x over previous
//
#include <hip/hip_runtime.h>

#define NEG 0.2f
#define NEG_INF (-1e30f)

typedef __attribute__((ext_vector_type(8))) short bf16x8;
typedef __attribute__((ext_vector_type(4))) float f32x4;

__device__ __forceinline__ float leaky(float e) { return e > 0.f ? e : NEG * e; }

__device__ __forceinline__ unsigned short f2bf(float f) {
    unsigned int u = __float_as_uint(f);
    unsigned int r = u + 0x7fffu + ((u >> 16) & 1u);
    return (unsigned short)(r >> 16);
}
__device__ __forceinline__ float2 bf2f2(unsigned int u) {
    float2 r;
    r.x = __uint_as_float(u << 16);
    r.y = __uint_as_float(u & 0xffff0000u);
    return r;
}

// ---------------- fp32 -> bf16 conversion ----------------
__global__ void f2b_kernel(const float* __restrict__ in, unsigned short* __restrict__ out,
                           int n4) {
    int i = blockIdx.x * blockDim.x + threadIdx.x;
    if (i >= n4) return;
    float4 v = ((const float4*)in)[i];
    ushort4 o;
    o.x = f2bf(v.x); o.y = f2bf(v.y); o.z = f2bf(v.z); o.w = f2bf(v.w);
    ((ushort4*)out)[i] = o;
}

// ---------------- CSR build ----------------
__global__ void hist_kernel(const int* __restrict__ dst, int E, int* __restrict__ deg) {
    for (int e = blockIdx.x * blockDim.x + threadIdx.x; e < E; e += gridDim.x * blockDim.x)
        atomicAdd(&deg[dst[e]], 1);
}

__global__ void scan_part(const int* __restrict__ deg, int* __restrict__ offs,
                          int* __restrict__ bsum, int n) {
    __shared__ int buf[256];
    int i = blockIdx.x * 256 + threadIdx.x;
    int v = (i < n) ? deg[i] : 0;
    buf[threadIdx.x] = v;
    __syncthreads();
    for (int s = 1; s < 256; s <<= 1) {
        int t = (threadIdx.x >= s) ? buf[threadIdx.x - s] : 0;
        __syncthreads();
        buf[threadIdx.x] += t;
        __syncthreads();
    }
    if (i < n) offs[i + 1] = buf[threadIdx.x];
    if (threadIdx.x == 255) bsum[blockIdx.x] = buf[255];
}

__global__ void scan_bsum(int* __restrict__ bsum, int nb) {
    __shared__ int buf[256];
    int v = (threadIdx.x < nb) ? bsum[threadIdx.x] : 0;
    buf[threadIdx.x] = v;
    __syncthreads();
    for (int s = 1; s < 256; s <<= 1) {
        int t = (threadIdx.x >= s) ? buf[threadIdx.x - s] : 0;
        __syncthreads();
        buf[threadIdx.x] += t;
        __syncthreads();
    }
    if (threadIdx.x < nb) bsum[threadIdx.x] = buf[threadIdx.x] - v;  // exclusive
}

__global__ void scan_add(int* __restrict__ offs, const int* __restrict__ bsum, int n) {
    int i = blockIdx.x * 256 + threadIdx.x;
    if (i < n) offs[i + 1] += bsum[blockIdx.x];
    if (i == 0) offs[0] = 0;
}

__global__ void copy_int(const int* __restrict__ s, int* __restrict__ d, int n) {
    int i = blockIdx.x * blockDim.x + threadIdx.x;
    if (i < n) d[i] = s[i];
}

__global__ void scatter_kernel(const int* __restrict__ src, const int* __restrict__ dst, int E,
                               int* __restrict__ ctr, int* __restrict__ csr) {
    for (int e = blockIdx.x * blockDim.x + threadIdx.x; e < E; e += gridDim.x * blockDim.x) {
        int p = atomicAdd(&ctr[dst[e]], 1);
        csr[p] = src[e];
    }
}

// ---------------- MFMA GEMM: out[M x N] = A[M x K](bf16) @ B[K x N](bf16) ----------------
// one wave per 16x16 output tile, K in steps of 32.
template <int K, int N>
__global__ __launch_bounds__(256) void mfma_gemm(const unsigned short* __restrict__ A,
                                                 const unsigned short* __restrict__ B,
                                                 const float* __restrict__ bias,
                                                 float* __restrict__ outF,
                                                 unsigned short* __restrict__ outB, int M) {
    const int ctiles = N / 16;
    int w = blockIdx.x * 4 + (threadIdx.x >> 6);
    int rt = w / ctiles, ct = w % ctiles;
    if (rt * 16 >= M) return;
    int lane = threadIdx.x & 63;
    int m = lane & 15, kb = lane >> 4;           // A row / B col = m; k-block = kb
    const unsigned short* arow = A + (size_t)(rt * 16 + m) * K + kb * 8;
    const unsigned short* bcol = B + ct * 16 + m;
    f32x4 acc = {0.f, 0.f, 0.f, 0.f};
#pragma unroll
    for (int kk = 0; kk < K; kk += 32) {
        bf16x8 a = *(const bf16x8*)(arow + kk);
        bf16x8 b;
        int k0 = kk + kb * 8;
#pragma unroll
        for (int i = 0; i < 8; ++i) b[i] = (short)bcol[(size_t)(k0 + i) * N];
        acc = __builtin_amdgcn_mfma_f32_16x16x32_bf16(a, b, acc, 0, 0, 0);
    }
    int col = ct * 16 + m;
    float bv = bias ? bias[col] : 0.f;
#pragma unroll
    for (int r = 0; r < 4; ++r) {
        int row = rt * 16 + kb * 4 + r;
        float v = acc[r] + bv;
        if (outF) outF[(size_t)row * N + col] = v;
        if (outB) outB[(size_t)row * N + col] = f2bf(v);
    }
}

// ---------------- attention coefficients ----------------
__global__ void att1_kernel(const float* __restrict__ h1, const float* __restrict__ asrc,
                            const float* __restrict__ adst, float* __restrict__ a_s,
                            float* __restrict__ a_d, int n) {
    int i = blockIdx.x * blockDim.x + threadIdx.x;  // over n*3
    if (i >= n * 3) return;
    int node = i / 3, h = i % 3;
    const float4* hb = (const float4*)&h1[(size_t)node * 96 + h * 32];
    const float4* sb = (const float4*)&asrc[h * 32];
    const float4* db = (const float4*)&adst[h * 32];
    float s = 0.f, d = 0.f;
#pragma unroll
    for (int q = 0; q < 8; ++q) {
        float4 hv = hb[q], sv = sb[q], dv = db[q];
        s += hv.x * sv.x + hv.y * sv.y + hv.z * sv.z + hv.w * sv.w;
        d += hv.x * dv.x + hv.y * dv.y + hv.z * dv.z + hv.w * dv.w;
    }
    a_s[i] = s; a_d[i] = d;
}

__global__ void att2_kernel(const float* __restrict__ h2, const float* __restrict__ asrc,
                            const float* __restrict__ adst, float* __restrict__ a_s,
                            float* __restrict__ a_d, int n) {
    int w = (blockIdx.x * blockDim.x + threadIdx.x) >> 6;
    int lane = threadIdx.x & 63;
    if (w >= n) return;
    float v0 = h2[(size_t)w * 128 + lane], v1 = h2[(size_t)w * 128 + 64 + lane];
    float s = v0 * asrc[lane] + v1 * asrc[64 + lane];
    float d = v0 * adst[lane] + v1 * adst[64 + lane];
#pragma unroll
    for (int m = 32; m >= 1; m >>= 1) { s += __shfl_xor(s, m); d += __shfl_xor(d, m); }
    if (lane == 0) { a_s[w] = s; a_d[w] = d; }
}

// ---------------- GAT aggregation: bf16 gathers, lane-parallel exp ----------------
__global__ __launch_bounds__(256) void gat1_agg(const unsigned short* __restrict__ h1b,
                                                const float* __restrict__ a_s,
                                                const float* __restrict__ a_d,
                                                const int* __restrict__ offs,
                                                const int* __restrict__ csr,
                                                const float* __restrict__ b1,
                                                unsigned short* __restrict__ out1b, int n) {
    int node = blockIdx.x * 4 + (threadIdx.x >> 6);
    if (node >= n) return;
    int lane = threadIdx.x & 63;
    int beg = offs[node], end = offs[node + 1];
    int deg = end - beg;
    float ad0 = a_d[node * 3 + 0], ad1 = a_d[node * 3 + 1], ad2 = a_d[node * 3 + 2];
    float es0 = leaky(a_s[node * 3 + 0] + ad0);
    float es1 = leaky(a_s[node * 3 + 1] + ad1);
    float es2 = leaky(a_s[node * 3 + 2] + ad2);

    float2 acc = make_float2(0.f, 0.f);
    float2 hv0 = make_float2(0.f, 0.f);
    if (lane < 48) hv0 = bf2f2(*(const unsigned int*)&h1b[(size_t)node * 96 + 2 * lane]);

    float den0, den1, den2;
    float m0, m1, m2;

    if (deg <= 64) {
        int s = -1;
        float l0 = NEG_INF, l1 = NEG_INF, l2 = NEG_INF;
        if (lane < deg) {
            s = csr[beg + lane];
            l0 = leaky(a_s[s * 3 + 0] + ad0);
            l1 = leaky(a_s[s * 3 + 1] + ad1);
            l2 = leaky(a_s[s * 3 + 2] + ad2);
        }
        m0 = l0; m1 = l1; m2 = l2;
#pragma unroll
        for (int sh = 32; sh >= 1; sh >>= 1) {
            m0 = fmaxf(m0, __shfl_xor(m0, sh));
            m1 = fmaxf(m1, __shfl_xor(m1, sh));
            m2 = fmaxf(m2, __shfl_xor(m2, sh));
        }
        m0 = fmaxf(m0, es0); m1 = fmaxf(m1, es1); m2 = fmaxf(m2, es2);
        float e0 = 0.f, e1 = 0.f, e2 = 0.f;
        if (lane < deg) {
            e0 = __expf(l0 - m0); e1 = __expf(l1 - m1); e2 = __expf(l2 - m2);
        }
        float w0 = __expf(es0 - m0), w1 = __expf(es1 - m1), w2 = __expf(es2 - m2);
        den0 = w0; den1 = w1; den2 = w2;
        float wSelf = (lane < 16) ? w0 : ((lane < 32) ? w1 : w2);
        acc.x = wSelf * hv0.x; acc.y = wSelf * hv0.y;

        int jj = 0;
        for (; jj + 1 < deg; jj += 2) {
            int sA = __shfl(s, jj), sB = __shfl(s, jj + 1);
            float a0 = __shfl(e0, jj), a1 = __shfl(e1, jj), a2 = __shfl(e2, jj);
            float c0 = __shfl(e0, jj + 1), c1 = __shfl(e1, jj + 1), c2 = __shfl(e2, jj + 1);
            den0 += a0 + c0; den1 += a1 + c1; den2 += a2 + c2;
            if (lane < 48) {
                float2 ha = bf2f2(*(const unsigned int*)&h1b[(size_t)sA * 96 + 2 * lane]);
                float2 hb = bf2f2(*(const unsigned int*)&h1b[(size_t)sB * 96 + 2 * lane]);
                float wA = (lane < 16) ? a0 : ((lane < 32) ? a1 : a2);
                float wB = (lane < 16) ? c0 : ((lane < 32) ? c1 : c2);
                acc.x += wA * ha.x + wB * hb.x;
                acc.y += wA * ha.y + wB * hb.y;
            }
        }
        if (jj < deg) {
            int sA = __shfl(s, jj);
            float a0 = __shfl(e0, jj), a1 = __shfl(e1, jj), a2 = __shfl(e2, jj);
            den0 += a0; den1 += a1; den2 += a2;
            if (lane < 48) {
                float2 ha = bf2f2(*(const unsigned int*)&h1b[(size_t)sA * 96 + 2 * lane]);
                float wA = (lane < 16) ? a0 : ((lane < 32) ? a1 : a2);
                acc.x += wA * ha.x; acc.y += wA * ha.y;
            }
        }
    } else {
        m0 = es0; m1 = es1; m2 = es2;
        for (int j = beg + lane; j < end; j += 64) {
            int s = csr[j];
            m0 = fmaxf(m0, leaky(a_s[s * 3 + 0] + ad0));
            m1 = fmaxf(m1, leaky(a_s[s * 3 + 1] + ad1));
            m2 = fmaxf(m2, leaky(a_s[s * 3 + 2] + ad2));
        }
#pragma unroll
        for (int sh = 32; sh >= 1; sh >>= 1) {
            m0 = fmaxf(m0, __shfl_xor(m0, sh));
            m1 = fmaxf(m1, __shfl_xor(m1, sh));
            m2 = fmaxf(m2, __shfl_xor(m2, sh));
        }
        float w0 = __expf(es0 - m0), w1 = __expf(es1 - m1), w2 = __expf(es2 - m2);
        den0 = w0; den1 = w1; den2 = w2;
        float wSelf = (lane < 16) ? w0 : ((lane < 32) ? w1 : w2);
        acc.x = wSelf * hv0.x; acc.y = wSelf * hv0.y;
        for (int t0 = beg; t0 < end; t0 += 64) {
            int cnt = min(64, end - t0);
            int s = -1;
            float e0 = 0.f, e1 = 0.f, e2 = 0.f;
            if (lane < cnt) {
                s = csr[t0 + lane];
                e0 = __expf(leaky(a_s[s * 3 + 0] + ad0) - m0);
                e1 = __expf(leaky(a_s[s * 3 + 1] + ad1) - m1);
                e2 = __expf(leaky(a_s[s * 3 + 2] + ad2) - m2);
            }
            for (int jj = 0; jj < cnt; ++jj) {
                int sA = __shfl(s, jj);
                float a0 = __shfl(e0, jj), a1 = __shfl(e1, jj), a2 = __shfl(e2, jj);
                den0 += a0; den1 += a1; den2 += a2;
                if (lane < 48) {
                    float2 ha = bf2f2(*(const unsigned int*)&h1b[(size_t)sA * 96 + 2 * lane]);
                    float wA = (lane < 16) ? a0 : ((lane < 32) ? a1 : a2);
                    acc.x += wA * ha.x; acc.y += wA * ha.y;
                }
            }
        }
    }

    if (lane < 48) {
        float den = (lane < 16) ? den0 : ((lane < 32) ? den1 : den2);
        float inv = 1.f / (den + 1e-16f);
        ushort2 o;
        o.x = f2bf(acc.x * inv + b1[2 * lane]);
        o.y = f2bf(acc.y * inv + b1[2 * lane + 1]);
        *(ushort2*)&out1b[(size_t)node * 96 + 2 * lane] = o;
    }
}

__global__ __launch_bounds__(256) void gat2_agg(const unsigned short* __restrict__ h2b,
                                                const float* __restrict__ a_s,
                                                const float* __restrict__ a_d,
                                                const int* __restrict__ offs,
                                                const int* __restrict__ csr,
                                                const float* __restrict__ b2,
                                                float* __restrict__ out, int n) {
    int node = blockIdx.x * 4 + (threadIdx.x >> 6);
    if (node >= n) return;
    int lane = threadIdx.x & 63;
    int beg = offs[node], end = offs[node + 1];
    int deg = end - beg;
    float ad = a_d[node];
    float es = leaky(a_s[node] + ad);
    float2 hv0 = bf2f2(*(const unsigned int*)&h2b[(size_t)node * 128 + 2 * lane]);
    float2 acc;
    float den, m;

    if (deg <= 64) {
        int s = -1;
        float l = NEG_INF;
        if (lane < deg) {
            s = csr[beg + lane];
            l = leaky(a_s[s] + ad);
        }
        m = l;
#pragma unroll
        for (int sh = 32; sh >= 1; sh >>= 1) m = fmaxf(m, __shfl_xor(m, sh));
        m = fmaxf(m, es);
        float e = (lane < deg) ? __expf(l - m) : 0.f;
        float wSelf = __expf(es - m);
        den = wSelf;
        acc.x = wSelf * hv0.x; acc.y = wSelf * hv0.y;

        int jj = 0;
        for (; jj + 1 < deg; jj += 2) {
            int sA = __shfl(s, jj), sB = __shfl(s, jj + 1);
            float wA = __shfl(e, jj), wB = __shfl(e, jj + 1);
            den += wA + wB;
            float2 ha = bf2f2(*(const unsigned int*)&h2b[(size_t)sA * 128 + 2 * lane]);
            float2 hb = bf2f2(*(const unsigned int*)&h2b[(size_t)sB * 128 + 2 * lane]);
            acc.x += wA * ha.x + wB * hb.x;
            acc.y += wA * ha.y + wB * hb.y;
        }
        if (jj < deg) {
            int sA = __shfl(s, jj);
            float wA = __shfl(e, jj);
            den += wA;
            float2 ha = bf2f2(*(const unsigned int*)&h2b[(size_t)sA * 128 + 2 * lane]);
            acc.x += wA * ha.x; acc.y += wA * ha.y;
        }
    } else {
        m = es;
        for (int j = beg + lane; j < end; j += 64) {
            int s = csr[j];
            m = fmaxf(m, leaky(a_s[s] + ad));
        }
#pragma unroll
        for (int sh = 32; sh >= 1; sh >>= 1) m = fmaxf(m, __shfl_xor(m, sh));
        float wSelf = __expf(es - m);
        den = wSelf;
        acc.x = wSelf * hv0.x; acc.y = wSelf * hv0.y;
        for (int t0 = beg; t0 < end; t0 += 64) {
            int cnt = min(64, end - t0);
            int s = -1;
            float e = 0.f;
            if (lane < cnt) {
                s = csr[t0 + lane];
                e = __expf(leaky(a_s[s] + ad) - m);
            }
            for (int jj = 0; jj < cnt; ++jj) {
                int sA = __shfl(s, jj);
                float wA = __shfl(e, jj);
                den += wA;
                float2 ha = bf2f2(*(const unsigned int*)&h2b[(size_t)sA * 128 + 2 * lane]);
                acc.x += wA * ha.x; acc.y += wA * ha.y;
            }
        }
    }

    float inv = 1.f / (den + 1e-16f);
    float2 o;
    o.x = acc.x * inv + b2[2 * lane];
    o.y = acc.y * inv + b2[2 * lane + 1];
    *(float2*)&out[(size_t)node * 128 + 2 * lane] = o;
}

// ---------------- BatchNorm stats (wide grid, float4, LDS tree) ----------------
__global__ __launch_bounds__(256) void bn_stats(const float* __restrict__ x,
                                                float* __restrict__ sums, int n, int rpb) {
    __shared__ float4 shs[8][32];
    __shared__ float4 shq[8][32];
    int tid = threadIdx.x;
    int c = tid & 31;
    int rg = tid >> 5;
    int r0 = blockIdx.x * rpb;
    int r1 = min(r0 + rpb, n);
    float4 s = make_float4(0.f, 0.f, 0.f, 0.f);
    float4 q = make_float4(0.f, 0.f, 0.f, 0.f);
    for (int r = r0 + rg; r < r1; r += 8) {
        float4 v = ((const float4*)x)[(size_t)r * 32 + c];
        s.x += v.x; s.y += v.y; s.z += v.z; s.w += v.w;
        q.x += v.x * v.x; q.y += v.y * v.y; q.z += v.z * v.z; q.w += v.w * v.w;
    }
    shs[rg][c] = s; shq[rg][c] = q;
    __syncthreads();
#pragma unroll
    for (int h = 4; h >= 1; h >>= 1) {
        if (rg < h) {
            float4 a = shs[rg + h][c], b = shq[rg + h][c];
            float4 cs = shs[rg][c], cq = shq[rg][c];
            cs.x += a.x; cs.y += a.y; cs.z += a.z; cs.w += a.w;
            cq.x += b.x; cq.y += b.y; cq.z += b.z; cq.w += b.w;
            shs[rg][c] = cs; shq[rg][c] = cq;
        }
        __syncthreads();
    }
    if (rg == 0) {
        float4 S = shs[0][c], Q = shq[0][c];
        atomicAdd(&sums[c * 4 + 0], S.x);
        atomicAdd(&sums[c * 4 + 1], S.y);
        atomicAdd(&sums[c * 4 + 2], S.z);
        atomicAdd(&sums[c * 4 + 3], S.w);
        atomicAdd(&sums[128 + c * 4 + 0], Q.x);
        atomicAdd(&sums[128 + c * 4 + 1], Q.y);
        atomicAdd(&sums[128 + c * 4 + 2], Q.z);
        atomicAdd(&sums[128 + c * 4 + 3], Q.w);
    }
}

__global__ void bn_finalize(const float* __restrict__ sums, const float* __restrict__ gamma,
                            const float* __restrict__ beta, float* __restrict__ ss, int n) {
    int c = threadIdx.x;  // 128
    float invN = 1.f / (float)n;
    float mu = sums[c] * invN;
    float var = sums[128 + c] * invN - mu * mu;
    float g = gamma[c] * rsqrtf(var + 1e-5f);
    ss[c] = g;
    ss[128 + c] = beta[c] - mu * g;
}

__global__ void final_kernel(const float* __restrict__ out2, const float* __restrict__ resid,
                             const float* __restrict__ ss, float* __restrict__ out, int n) {
    int i = blockIdx.x * blockDim.x + threadIdx.x;  // over n*32 float4s
    if (i >= n * 32) return;
    int c0 = (i & 31) * 4;
    float4 v = ((const float4*)out2)[i];
    float4 r = ((const float4*)resid)[i];
    float4 o;
    const float* vp = &v.x;
    const float* rp = &r.x;
    float* op = &o.x;
#pragma unroll
    for (int q = 0; q < 4; ++q) {
        int c = c0 + q;
        float y = vp[q] * ss[c] + ss[128 + c];
        y = fmaxf(y, 0.f);
        op[q] = y + rp[q];
    }
    ((float4*)out)[i] = o;
}

extern "C" void kernel_launch(void* const* d_in, const int* in_sizes, int n_in,
                              void* d_out, int out_size, void* d_ws, size_t ws_size,
                              hipStream_t stream) {
    const float* x     = (const float*)d_in[0];
    const int*   ei    = (const int*)d_in[1];
    const float* W1    = (const float*)d_in[2];
    const float* asrc1 = (const float*)d_in[3];
    const float* adst1 = (const float*)d_in[4];
    const float* b1    = (const float*)d_in[5];
    const float* W2    = (const float*)d_in[6];
    const float* asrc2 = (const float*)d_in[7];
    const float* adst2 = (const float*)d_in[8];
    const float* b2    = (const float*)d_in[9];
    const float* gamma = (const float*)d_in[10];
    const float* beta  = (const float*)d_in[11];
    const float* Wres  = (const float*)d_in[12];
    const float* bres  = (const float*)d_in[13];

    const int n = in_sizes[0] / 128;  // 50000
    const int E = in_sizes[1] / 2;    // 800000

    char* ws = (char*)d_ws;
    size_t off = 0;
    auto alloc = [&](size_t bytes) {
        void* p = ws + off;
        off = (off + bytes + 255) & ~(size_t)255;
        return p;
    };
    float* resid = (float*)alloc((size_t)n * 128 * 4);
    float* h1    = (float*)alloc((size_t)n * 96 * 4);
    float* h2    = (float*)alloc((size_t)n * 128 * 4);
    float* out2  = (float*)alloc((size_t)n * 128 * 4);
    float* as1   = (float*)alloc((size_t)n * 3 * 4);
    float* ad1   = (float*)alloc((size_t)n * 3 * 4);
    float* as2   = (float*)alloc((size_t)n * 4);
    float* ad2   = (float*)alloc((size_t)n * 4);
    float* sums  = (float*)alloc(256 * 4);
    float* ss    = (float*)alloc(256 * 4);
    unsigned short* xb    = (unsigned short*)alloc((size_t)n * 128 * 2);
    unsigned short* h1b   = (unsigned short*)alloc((size_t)n * 96 * 2);
    unsigned short* h2b   = (unsigned short*)alloc((size_t)n * 128 * 2);
    unsigned short* out1b = (unsigned short*)alloc((size_t)n * 96 * 2);
    unsigned short* w1b   = (unsigned short*)alloc(128 * 96 * 2);
    unsigned short* w2b   = (unsigned short*)alloc(96 * 128 * 2);
    unsigned short* wresb = (unsigned short*)alloc(128 * 128 * 2);
    int* deg  = (int*)alloc((size_t)n * 4);
    int* offs = (int*)alloc((size_t)(n + 1) * 4);
    int* ctr  = (int*)alloc((size_t)n * 4);
    int* bsum = (int*)alloc(256 * 4);
    int* csr  = (int*)alloc((size_t)E * 4);

    hipMemsetAsync(deg, 0, (size_t)n * 4, stream);
    hipMemsetAsync(sums, 0, 256 * 4, stream);

    const int* srcIdx = ei;
    const int* dstIdx = ei + E;
    const int nb = (n + 255) / 256;

    // conversions
    f2b_kernel<<<(n * 32 + 255) / 256, 256, 0, stream>>>(x, xb, n * 32);
    f2b_kernel<<<(128 * 96 / 4 + 255) / 256, 256, 0, stream>>>(W1, w1b, 128 * 96 / 4);
    f2b_kernel<<<(96 * 128 / 4 + 255) / 256, 256, 0, stream>>>(W2, w2b, 96 * 128 / 4);
    f2b_kernel<<<(128 * 128 / 4 + 255) / 256, 256, 0, stream>>>(Wres, wresb, 128 * 128 / 4);

    // CSR
    hist_kernel<<<2048, 256, 0, stream>>>(dstIdx, E, deg);
    scan_part<<<nb, 256, 0, stream>>>(deg, offs, bsum, n);
    scan_bsum<<<1, 256, 0, stream>>>(bsum, nb);
    scan_add<<<nb, 256, 0, stream>>>(offs, bsum, n);
    copy_int<<<(n + 255) / 256, 256, 0, stream>>>(offs, ctr, n);
    scatter_kernel<<<2048, 256, 0, stream>>>(srcIdx, dstIdx, E, ctr, csr);

    const int mt = n / 16 + (n % 16 ? 1 : 0);  // 3125
    // gemm1: h1 = x @ W1  (fp32 + bf16 out)
    mfma_gemm<128, 96><<<(mt * 6 + 3) / 4, 256, 0, stream>>>(xb, w1b, nullptr, h1, h1b, n);
    att1_kernel<<<(n * 3 + 255) / 256, 256, 0, stream>>>(h1, asrc1, adst1, as1, ad1, n);
    // resid = x @ Wres + bres (fp32 only)
    mfma_gemm<128, 128><<<(mt * 8 + 3) / 4, 256, 0, stream>>>(xb, wresb, bres, resid, nullptr, n);
    gat1_agg<<<(n + 3) / 4, 256, 0, stream>>>(h1b, as1, ad1, offs, csr, b1, out1b, n);
    // gemm2: h2 = out1 @ W2 (fp32 + bf16 out)
    mfma_gemm<96, 128><<<(mt * 8 + 3) / 4, 256, 0, stream>>>(out1b, w2b, nullptr, h2, h2b, n);
    att2_kernel<<<(n + 3) / 4, 256, 0, stream>>>(h2, asrc2, adst2, as2, ad2, n);
    gat2_agg<<<(n + 3) / 4, 256, 0, stream>>>(h2b, as2, ad2, offs, csr, b2, out2, n);
    bn_stats<<<512, 256, 0, stream>>>(out2, sums, n, (n + 511) / 512);
    bn_finalize<<<1, 128, 0, stream>>>(sums, gamma, beta, ss, n);
    final_kernel<<<(n * 32 + 255) / 256, 256, 0, stream>>>(out2, resid, ss, (float*)d_out, n);
}

// Round 5
// 313.404 us; speedup vs baseline: 2.0044x; 1.1516x over previous
//
#include <hip/hip_runtime.h>

#define NEG 0.2f
#define NEG_INF (-1e30f)

typedef __attribute__((ext_vector_type(8))) short bf16x8;
typedef __attribute__((ext_vector_type(4))) float f32x4;

__device__ __forceinline__ float leaky(float e) { return e > 0.f ? e : NEG * e; }

__device__ __forceinline__ unsigned short f2bf(float f) {
    unsigned int u = __float_as_uint(f);
    unsigned int r = u + 0x7fffu + ((u >> 16) & 1u);
    return (unsigned short)(r >> 16);
}
__device__ __forceinline__ float2 bf2f2(unsigned int u) {
    float2 r;
    r.x = __uint_as_float(u << 16);
    r.y = __uint_as_float(u & 0xffff0000u);
    return r;
}

// ---------------- fp32 -> bf16 conversion (x only) ----------------
__global__ void f2b_kernel(const float* __restrict__ in, unsigned short* __restrict__ out,
                           int n4) {
    int i = blockIdx.x * blockDim.x + threadIdx.x;
    if (i >= n4) return;
    float4 v = ((const float4*)in)[i];
    ushort4 o;
    o.x = f2bf(v.x); o.y = f2bf(v.y); o.z = f2bf(v.z); o.w = f2bf(v.w);
    ((ushort4*)out)[i] = o;
}

// ---------------- weight reorder into MFMA B-fragment layout ----------------
// Bp[((ct*KT + kt)*64 + lane)*8 + i] = bf16(W[(kt*32 + (lane>>4)*8 + i)*N + ct*16 + (lane&15)])
template <int K, int N>
__global__ void reorder_w(const float* __restrict__ W, unsigned short* __restrict__ Bp) {
    int idx = blockIdx.x * 256 + threadIdx.x;
    if (idx >= N * K) return;
    int i = idx & 7;
    int rest = idx >> 3;
    int lane = rest & 63;
    rest >>= 6;
    int kt = rest % (K / 32);
    int ct = rest / (K / 32);
    int m = lane & 15, kb = lane >> 4;
    int k = kt * 32 + kb * 8 + i, col = ct * 16 + m;
    Bp[idx] = f2bf(W[(size_t)k * N + col]);
}

// ---------------- CSR build ----------------
__global__ void hist_kernel(const int* __restrict__ dst, int E, int* __restrict__ deg) {
    for (int e = blockIdx.x * blockDim.x + threadIdx.x; e < E; e += gridDim.x * blockDim.x)
        atomicAdd(&deg[dst[e]], 1);
}

__global__ void scan_part(const int* __restrict__ deg, int* __restrict__ offs,
                          int* __restrict__ bsum, int n) {
    __shared__ int buf[256];
    int i = blockIdx.x * 256 + threadIdx.x;
    int v = (i < n) ? deg[i] : 0;
    buf[threadIdx.x] = v;
    __syncthreads();
    for (int s = 1; s < 256; s <<= 1) {
        int t = (threadIdx.x >= s) ? buf[threadIdx.x - s] : 0;
        __syncthreads();
        buf[threadIdx.x] += t;
        __syncthreads();
    }
    if (i < n) offs[i + 1] = buf[threadIdx.x];
    if (threadIdx.x == 255) bsum[blockIdx.x] = buf[255];
}

__global__ void scan_bsum(int* __restrict__ bsum, int nb) {
    __shared__ int buf[256];
    int v = (threadIdx.x < nb) ? bsum[threadIdx.x] : 0;
    buf[threadIdx.x] = v;
    __syncthreads();
    for (int s = 1; s < 256; s <<= 1) {
        int t = (threadIdx.x >= s) ? buf[threadIdx.x - s] : 0;
        __syncthreads();
        buf[threadIdx.x] += t;
        __syncthreads();
    }
    if (threadIdx.x < nb) bsum[threadIdx.x] = buf[threadIdx.x] - v;  // exclusive
}

__global__ void scan_add(int* __restrict__ offs, int* __restrict__ ctr,
                         const int* __restrict__ bsum, int n) {
    int i = blockIdx.x * 256 + threadIdx.x;
    if (i < n) {
        int v = offs[i + 1] + bsum[blockIdx.x];
        offs[i + 1] = v;
        if (i + 1 < n) ctr[i + 1] = v;
    }
    if (i == 0) { offs[0] = 0; ctr[0] = 0; }
}

__global__ void scatter_kernel(const int* __restrict__ src, const int* __restrict__ dst, int E,
                               int* __restrict__ ctr, int* __restrict__ csr) {
    for (int e = blockIdx.x * blockDim.x + threadIdx.x; e < E; e += gridDim.x * blockDim.x) {
        int p = atomicAdd(&ctr[dst[e]], 1);
        csr[p] = src[e];
    }
}

// ---------------- MFMA GEMM: one wave per 16-row tile, all col-tiles ----------------
// A [M x K] bf16, Bp pre-packed fragments, optional fused attention dots.
template <int K, int N, int HEADS>
__global__ __launch_bounds__(256) void mfma_gemm(const unsigned short* __restrict__ A,
                                                 const unsigned short* __restrict__ Bp,
                                                 const float* __restrict__ bias,
                                                 float* __restrict__ outF,
                                                 unsigned short* __restrict__ outB,
                                                 const float* __restrict__ asrc,
                                                 const float* __restrict__ adst,
                                                 float* __restrict__ a_s,
                                                 float* __restrict__ a_d, int M) {
    constexpr int KT = K / 32, CT = N / 16;
    int w = blockIdx.x * 4 + (threadIdx.x >> 6);
    int row0 = w * 16;
    if (row0 >= M) return;
    int lane = threadIdx.x & 63;
    int m = lane & 15, kb = lane >> 4;
    const unsigned short* arow = A + (size_t)(row0 + m) * K + kb * 8;

    f32x4 acc[CT];
#pragma unroll
    for (int ct = 0; ct < CT; ++ct) acc[ct] = (f32x4){0.f, 0.f, 0.f, 0.f};

#pragma unroll
    for (int kt = 0; kt < KT; ++kt) {
        bf16x8 a = *(const bf16x8*)(arow + kt * 32);
#pragma unroll
        for (int ct = 0; ct < CT; ++ct) {
            bf16x8 b = *(const bf16x8*)(Bp + ((size_t)(ct * KT + kt) * 64 + lane) * 8);
            acc[ct] = __builtin_amdgcn_mfma_f32_16x16x32_bf16(a, b, acc[ct], 0, 0, 0);
        }
    }

#pragma unroll
    for (int r = 0; r < 4; ++r) {
        int row = row0 + kb * 4 + r;
#pragma unroll
        for (int ct = 0; ct < CT; ++ct) {
            int col = ct * 16 + m;
            float v = acc[ct][r] + (bias ? bias[col] : 0.f);
            if (outF) outF[(size_t)row * N + col] = v;
            if (outB) outB[(size_t)row * N + col] = f2bf(v);
        }
    }

    if (HEADS > 0) {
        float asv[CT], adv[CT];
#pragma unroll
        for (int ct = 0; ct < CT; ++ct) {
            int col = ct * 16 + m;
            asv[ct] = asrc[col];
            adv[ct] = adst[col];
        }
        constexpr int TPH = CT / (HEADS > 0 ? HEADS : 1);
#pragma unroll
        for (int r = 0; r < 4; ++r) {
            int row = row0 + kb * 4 + r;
#pragma unroll
            for (int h = 0; h < HEADS; ++h) {
                float s = 0.f, d = 0.f;
#pragma unroll
                for (int t = 0; t < TPH; ++t) {
                    int ct = h * TPH + t;
                    s += acc[ct][r] * asv[ct];
                    d += acc[ct][r] * adv[ct];
                }
#pragma unroll
                for (int off = 1; off <= 8; off <<= 1) {
                    s += __shfl_xor(s, off);
                    d += __shfl_xor(d, off);
                }
                if (m == 0) {
                    a_s[(size_t)row * HEADS + h] = s;
                    a_d[(size_t)row * HEADS + h] = d;
                }
            }
        }
    }
}

// ---------------- GAT aggregation: LDS edge scratch, lean serial gather ----------------
__global__ __launch_bounds__(256) void gat1_agg(const unsigned short* __restrict__ h1b,
                                                const float* __restrict__ a_s,
                                                const float* __restrict__ a_d,
                                                const int* __restrict__ offs,
                                                const int* __restrict__ csr,
                                                const float* __restrict__ b1,
                                                unsigned short* __restrict__ out1b, int n) {
    __shared__ uint2 sc[4][3][64];
    int wid = threadIdx.x >> 6;
    int node = blockIdx.x * 4 + wid;
    if (node >= n) return;
    int lane = threadIdx.x & 63;
    int head = lane >> 4; if (head > 2) head = 2;
    int beg = offs[node], end = offs[node + 1];
    int deg = end - beg;
    float ad0 = a_d[node * 3 + 0], ad1 = a_d[node * 3 + 1], ad2 = a_d[node * 3 + 2];
    float es0 = leaky(a_s[node * 3 + 0] + ad0);
    float es1 = leaky(a_s[node * 3 + 1] + ad1);
    float es2 = leaky(a_s[node * 3 + 2] + ad2);
    float2 hv0 = make_float2(0.f, 0.f);
    if (lane < 48) hv0 = bf2f2(*(const unsigned int*)&h1b[(size_t)node * 96 + 2 * lane]);

    float den;
    float2 acc;

    if (deg <= 64) {
        int s = 0;
        float l0 = NEG_INF, l1 = NEG_INF, l2 = NEG_INF;
        if (lane < deg) {
            s = csr[beg + lane];
            l0 = leaky(a_s[s * 3 + 0] + ad0);
            l1 = leaky(a_s[s * 3 + 1] + ad1);
            l2 = leaky(a_s[s * 3 + 2] + ad2);
        }
        float m0 = l0, m1 = l1, m2 = l2;
#pragma unroll
        for (int sh = 32; sh >= 1; sh >>= 1) {
            m0 = fmaxf(m0, __shfl_xor(m0, sh));
            m1 = fmaxf(m1, __shfl_xor(m1, sh));
            m2 = fmaxf(m2, __shfl_xor(m2, sh));
        }
        m0 = fmaxf(m0, es0); m1 = fmaxf(m1, es1); m2 = fmaxf(m2, es2);
        float e0 = 0.f, e1 = 0.f, e2 = 0.f;
        if (lane < deg) {
            e0 = __expf(l0 - m0); e1 = __expf(l1 - m1); e2 = __expf(l2 - m2);
        }
        sc[wid][0][lane] = make_uint2((unsigned)s, __float_as_uint(e0));
        sc[wid][1][lane] = make_uint2((unsigned)s, __float_as_uint(e1));
        sc[wid][2][lane] = make_uint2((unsigned)s, __float_as_uint(e2));
        float w0 = __expf(es0 - m0), w1 = __expf(es1 - m1), w2 = __expf(es2 - m2);
        den = (head == 0) ? w0 : ((head == 1) ? w1 : w2);
        float wSelf = (lane < 16) ? w0 : ((lane < 32) ? w1 : w2);
        acc.x = wSelf * hv0.x; acc.y = wSelf * hv0.y;

        int jj = 0;
        for (; jj + 1 < deg; jj += 2) {
            uint2 eA = sc[wid][head][jj];
            uint2 eB = sc[wid][head][jj + 1];
            float wA = __uint_as_float(eA.y), wB = __uint_as_float(eB.y);
            den += wA + wB;
            if (lane < 48) {
                float2 ha = bf2f2(*(const unsigned int*)&h1b[(size_t)eA.x * 96 + 2 * lane]);
                float2 hb = bf2f2(*(const unsigned int*)&h1b[(size_t)eB.x * 96 + 2 * lane]);
                acc.x += wA * ha.x + wB * hb.x;
                acc.y += wA * ha.y + wB * hb.y;
            }
        }
        if (jj < deg) {
            uint2 eA = sc[wid][head][jj];
            float wA = __uint_as_float(eA.y);
            den += wA;
            if (lane < 48) {
                float2 ha = bf2f2(*(const unsigned int*)&h1b[(size_t)eA.x * 96 + 2 * lane]);
                acc.x += wA * ha.x; acc.y += wA * ha.y;
            }
        }
    } else {
        float m0 = es0, m1 = es1, m2 = es2;
        for (int j = beg + lane; j < end; j += 64) {
            int s = csr[j];
            m0 = fmaxf(m0, leaky(a_s[s * 3 + 0] + ad0));
            m1 = fmaxf(m1, leaky(a_s[s * 3 + 1] + ad1));
            m2 = fmaxf(m2, leaky(a_s[s * 3 + 2] + ad2));
        }
#pragma unroll
        for (int sh = 32; sh >= 1; sh >>= 1) {
            m0 = fmaxf(m0, __shfl_xor(m0, sh));
            m1 = fmaxf(m1, __shfl_xor(m1, sh));
            m2 = fmaxf(m2, __shfl_xor(m2, sh));
        }
        float w0 = __expf(es0 - m0), w1 = __expf(es1 - m1), w2 = __expf(es2 - m2);
        den = (head == 0) ? w0 : ((head == 1) ? w1 : w2);
        float wSelf = (lane < 16) ? w0 : ((lane < 32) ? w1 : w2);
        acc.x = wSelf * hv0.x; acc.y = wSelf * hv0.y;
        for (int t0 = beg; t0 < end; t0 += 64) {
            int cnt = min(64, end - t0);
            int s = 0;
            float e0 = 0.f, e1 = 0.f, e2 = 0.f;
            if (lane < cnt) {
                s = csr[t0 + lane];
                e0 = __expf(leaky(a_s[s * 3 + 0] + ad0) - m0);
                e1 = __expf(leaky(a_s[s * 3 + 1] + ad1) - m1);
                e2 = __expf(leaky(a_s[s * 3 + 2] + ad2) - m2);
            }
            sc[wid][0][lane] = make_uint2((unsigned)s, __float_as_uint(e0));
            sc[wid][1][lane] = make_uint2((unsigned)s, __float_as_uint(e1));
            sc[wid][2][lane] = make_uint2((unsigned)s, __float_as_uint(e2));
            for (int jj = 0; jj < cnt; ++jj) {
                uint2 eA = sc[wid][head][jj];
                float wA = __uint_as_float(eA.y);
                den += wA;
                if (lane < 48) {
                    float2 ha = bf2f2(*(const unsigned int*)&h1b[(size_t)eA.x * 96 + 2 * lane]);
                    acc.x += wA * ha.x; acc.y += wA * ha.y;
                }
            }
        }
    }

    if (lane < 48) {
        float inv = 1.f / (den + 1e-16f);
        ushort2 o;
        o.x = f2bf(acc.x * inv + b1[2 * lane]);
        o.y = f2bf(acc.y * inv + b1[2 * lane + 1]);
        *(ushort2*)&out1b[(size_t)node * 96 + 2 * lane] = o;
    }
}

__global__ __launch_bounds__(256) void gat2_agg(const unsigned short* __restrict__ h2b,
                                                const float* __restrict__ a_s,
                                                const float* __restrict__ a_d,
                                                const int* __restrict__ offs,
                                                const int* __restrict__ csr,
                                                const float* __restrict__ b2,
                                                float* __restrict__ out, int n) {
    __shared__ uint2 sc[4][64];
    int wid = threadIdx.x >> 6;
    int node = blockIdx.x * 4 + wid;
    if (node >= n) return;
    int lane = threadIdx.x & 63;
    int beg = offs[node], end = offs[node + 1];
    int deg = end - beg;
    float ad = a_d[node];
    float es = leaky(a_s[node] + ad);
    float2 hv0 = bf2f2(*(const unsigned int*)&h2b[(size_t)node * 128 + 2 * lane]);
    float den;
    float2 acc;

    if (deg <= 64) {
        int s = 0;
        float l = NEG_INF;
        if (lane < deg) {
            s = csr[beg + lane];
            l = leaky(a_s[s] + ad);
        }
        float m = l;
#pragma unroll
        for (int sh = 32; sh >= 1; sh >>= 1) m = fmaxf(m, __shfl_xor(m, sh));
        m = fmaxf(m, es);
        float e = (lane < deg) ? __expf(l - m) : 0.f;
        sc[wid][lane] = make_uint2((unsigned)s, __float_as_uint(e));
        float wSelf = __expf(es - m);
        den = wSelf;
        acc.x = wSelf * hv0.x; acc.y = wSelf * hv0.y;

        int jj = 0;
        for (; jj + 1 < deg; jj += 2) {
            uint2 eA = sc[wid][jj];
            uint2 eB = sc[wid][jj + 1];
            float wA = __uint_as_float(eA.y), wB = __uint_as_float(eB.y);
            den += wA + wB;
            float2 ha = bf2f2(*(const unsigned int*)&h2b[(size_t)eA.x * 128 + 2 * lane]);
            float2 hb = bf2f2(*(const unsigned int*)&h2b[(size_t)eB.x * 128 + 2 * lane]);
            acc.x += wA * ha.x + wB * hb.x;
            acc.y += wA * ha.y + wB * hb.y;
        }
        if (jj < deg) {
            uint2 eA = sc[wid][jj];
            float wA = __uint_as_float(eA.y);
            den += wA;
            float2 ha = bf2f2(*(const unsigned int*)&h2b[(size_t)eA.x * 128 + 2 * lane]);
            acc.x += wA * ha.x; acc.y += wA * ha.y;
        }
    } else {
        float m = es;
        for (int j = beg + lane; j < end; j += 64) {
            int s = csr[j];
            m = fmaxf(m, leaky(a_s[s] + ad));
        }
#pragma unroll
        for (int sh = 32; sh >= 1; sh >>= 1) m = fmaxf(m, __shfl_xor(m, sh));
        float wSelf = __expf(es - m);
        den = wSelf;
        acc.x = wSelf * hv0.x; acc.y = wSelf * hv0.y;
        for (int t0 = beg; t0 < end; t0 += 64) {
            int cnt = min(64, end - t0);
            int s = 0;
            float e = 0.f;
            if (lane < cnt) {
                s = csr[t0 + lane];
                e = __expf(leaky(a_s[s] + ad) - m);
            }
            sc[wid][lane] = make_uint2((unsigned)s, __float_as_uint(e));
            for (int jj = 0; jj < cnt; ++jj) {
                uint2 eA = sc[wid][jj];
                float wA = __uint_as_float(eA.y);
                den += wA;
                float2 ha = bf2f2(*(const unsigned int*)&h2b[(size_t)eA.x * 128 + 2 * lane]);
                acc.x += wA * ha.x; acc.y += wA * ha.y;
            }
        }
    }

    float inv = 1.f / (den + 1e-16f);
    float2 o;
    o.x = acc.x * inv + b2[2 * lane];
    o.y = acc.y * inv + b2[2 * lane + 1];
    *(float2*)&out[(size_t)node * 128 + 2 * lane] = o;
}

// ---------------- BatchNorm stats (wide grid, float4, LDS tree) ----------------
__global__ __launch_bounds__(256) void bn_stats(const float* __restrict__ x,
                                                float* __restrict__ sums, int n, int rpb) {
    __shared__ float4 shs[8][32];
    __shared__ float4 shq[8][32];
    int tid = threadIdx.x;
    int c = tid & 31;
    int rg = tid >> 5;
    int r0 = blockIdx.x * rpb;
    int r1 = min(r0 + rpb, n);
    float4 s = make_float4(0.f, 0.f, 0.f, 0.f);
    float4 q = make_float4(0.f, 0.f, 0.f, 0.f);
    for (int r = r0 + rg; r < r1; r += 8) {
        float4 v = ((const float4*)x)[(size_t)r * 32 + c];
        s.x += v.x; s.y += v.y; s.z += v.z; s.w += v.w;
        q.x += v.x * v.x; q.y += v.y * v.y; q.z += v.z * v.z; q.w += v.w * v.w;
    }
    shs[rg][c] = s; shq[rg][c] = q;
    __syncthreads();
#pragma unroll
    for (int h = 4; h >= 1; h >>= 1) {
        if (rg < h) {
            float4 a = shs[rg + h][c], b = shq[rg + h][c];
            float4 cs = shs[rg][c], cq = shq[rg][c];
            cs.x += a.x; cs.y += a.y; cs.z += a.z; cs.w += a.w;
            cq.x += b.x; cq.y += b.y; cq.z += b.z; cq.w += b.w;
            shs[rg][c] = cs; shq[rg][c] = cq;
        }
        __syncthreads();
    }
    if (rg == 0) {
        float4 S = shs[0][c], Q = shq[0][c];
        atomicAdd(&sums[c * 4 + 0], S.x);
        atomicAdd(&sums[c * 4 + 1], S.y);
        atomicAdd(&sums[c * 4 + 2], S.z);
        atomicAdd(&sums[c * 4 + 3], S.w);
        atomicAdd(&sums[128 + c * 4 + 0], Q.x);
        atomicAdd(&sums[128 + c * 4 + 1], Q.y);
        atomicAdd(&sums[128 + c * 4 + 2], Q.z);
        atomicAdd(&sums[128 + c * 4 + 3], Q.w);
    }
}

// ---------------- fused BN-normalize + ReLU + residual ----------------
__global__ void final_kernel(const float* __restrict__ out2, const float* __restrict__ resid,
                             const float* __restrict__ sums, const float* __restrict__ gamma,
                             const float* __restrict__ beta, float* __restrict__ out, int n) {
    int i = blockIdx.x * blockDim.x + threadIdx.x;  // over n*32 float4s
    if (i >= n * 32) return;
    int c0 = (i & 31) * 4;
    float invN = 1.f / (float)n;
    float4 v = ((const float4*)out2)[i];
    float4 r = ((const float4*)resid)[i];
    float4 o;
    const float* vp = &v.x;
    const float* rp = &r.x;
    float* op = &o.x;
#pragma unroll
    for (int q = 0; q < 4; ++q) {
        int c = c0 + q;
        float mu = sums[c] * invN;
        float var = sums[128 + c] * invN - mu * mu;
        float g = gamma[c] * rsqrtf(var + 1e-5f);
        float y = (vp[q] - mu) * g + beta[c];
        y = fmaxf(y, 0.f);
        op[q] = y + rp[q];
    }
    ((float4*)out)[i] = o;
}

extern "C" void kernel_launch(void* const* d_in, const int* in_sizes, int n_in,
                              void* d_out, int out_size, void* d_ws, size_t ws_size,
                              hipStream_t stream) {
    const float* x     = (const float*)d_in[0];
    const int*   ei    = (const int*)d_in[1];
    const float* W1    = (const float*)d_in[2];
    const float* asrc1 = (const float*)d_in[3];
    const float* adst1 = (const float*)d_in[4];
    const float* b1    = (const float*)d_in[5];
    const float* W2    = (const float*)d_in[6];
    const float* asrc2 = (const float*)d_in[7];
    const float* adst2 = (const float*)d_in[8];
    const float* b2    = (const float*)d_in[9];
    const float* gamma = (const float*)d_in[10];
    const float* beta  = (const float*)d_in[11];
    const float* Wres  = (const float*)d_in[12];
    const float* bres  = (const float*)d_in[13];

    const int n = in_sizes[0] / 128;  // 50000
    const int E = in_sizes[1] / 2;    // 800000

    char* ws = (char*)d_ws;
    size_t off = 0;
    auto alloc = [&](size_t bytes) {
        void* p = ws + off;
        off = (off + bytes + 255) & ~(size_t)255;
        return p;
    };
    float* resid = (float*)alloc((size_t)n * 128 * 4);
    float* out2  = (float*)alloc((size_t)n * 128 * 4);
    float* as1   = (float*)alloc((size_t)n * 3 * 4);
    float* ad1   = (float*)alloc((size_t)n * 3 * 4);
    float* as2   = (float*)alloc((size_t)n * 4);
    float* ad2   = (float*)alloc((size_t)n * 4);
    float* sums  = (float*)alloc(256 * 4);
    unsigned short* xb    = (unsigned short*)alloc((size_t)n * 128 * 2);
    unsigned short* h1b   = (unsigned short*)alloc((size_t)n * 96 * 2);
    unsigned short* h2b   = (unsigned short*)alloc((size_t)n * 128 * 2);
    unsigned short* out1b = (unsigned short*)alloc((size_t)n * 96 * 2);
    unsigned short* w1p   = (unsigned short*)alloc(128 * 96 * 2);
    unsigned short* w2p   = (unsigned short*)alloc(96 * 128 * 2);
    unsigned short* wresp = (unsigned short*)alloc(128 * 128 * 2);
    int* deg  = (int*)alloc((size_t)n * 4);
    int* offs = (int*)alloc((size_t)(n + 1) * 4);
    int* ctr  = (int*)alloc((size_t)(n + 1) * 4);
    int* bsum = (int*)alloc(256 * 4);
    int* csr  = (int*)alloc((size_t)E * 4);

    hipMemsetAsync(deg, 0, (size_t)n * 4, stream);
    hipMemsetAsync(sums, 0, 256 * 4, stream);

    const int* srcIdx = ei;
    const int* dstIdx = ei + E;
    const int nb = (n + 255) / 256;

    // conversions / weight packing
    f2b_kernel<<<(n * 32 + 255) / 256, 256, 0, stream>>>(x, xb, n * 32);
    reorder_w<128, 96><<<(128 * 96 + 255) / 256, 256, 0, stream>>>(W1, w1p);
    reorder_w<96, 128><<<(96 * 128 + 255) / 256, 256, 0, stream>>>(W2, w2p);
    reorder_w<128, 128><<<(128 * 128 + 255) / 256, 256, 0, stream>>>(Wres, wresp);

    // CSR
    hist_kernel<<<2048, 256, 0, stream>>>(dstIdx, E, deg);
    scan_part<<<nb, 256, 0, stream>>>(deg, offs, bsum, n);
    scan_bsum<<<1, 256, 0, stream>>>(bsum, nb);
    scan_add<<<nb, 256, 0, stream>>>(offs, ctr, bsum, n);
    scatter_kernel<<<2048, 256, 0, stream>>>(srcIdx, dstIdx, E, ctr, csr);

    const int mt = (n + 15) / 16;          // 3125 row tiles
    const int gblk = (mt + 3) / 4;         // 4 waves per block

    // gemm1: h1b = bf16(x @ W1), fused a_s1/a_d1
    mfma_gemm<128, 96, 3><<<gblk, 256, 0, stream>>>(xb, w1p, nullptr, nullptr, h1b,
                                                    asrc1, adst1, as1, ad1, n);
    // resid = x @ Wres + bres (fp32)
    mfma_gemm<128, 128, 0><<<gblk, 256, 0, stream>>>(xb, wresp, bres, resid, nullptr,
                                                     nullptr, nullptr, nullptr, nullptr, n);
    gat1_agg<<<(n + 3) / 4, 256, 0, stream>>>(h1b, as1, ad1, offs, csr, b1, out1b, n);
    // gemm2: h2b = bf16(out1 @ W2), fused a_s2/a_d2
    mfma_gemm<96, 128, 1><<<gblk, 256, 0, stream>>>(out1b, w2p, nullptr, nullptr, h2b,
                                                    asrc2, adst2, as2, ad2, n);
    gat2_agg<<<(n + 3) / 4, 256, 0, stream>>>(h2b, as2, ad2, offs, csr, b2, out2, n);
    bn_stats<<<512, 256, 0, stream>>>(out2, sums, n, (n + 511) / 512);
    final_kernel<<<(n * 32 + 255) / 256, 256, 0, stream>>>(out2, resid, sums, gamma, beta,
                                                           (float*)d_out, n);
}

// Round 6
// 300.615 us; speedup vs baseline: 2.0897x; 1.0425x over previous
//
#include <hip/hip_runtime.h>

#define NEG 0.2f
#define NEG_INF (-1e30f)

typedef __attribute__((ext_vector_type(8))) short bf16x8;
typedef __attribute__((ext_vector_type(4))) float f32x4;

__device__ __forceinline__ float leaky(float e) { return e > 0.f ? e : NEG * e; }

__device__ __forceinline__ unsigned short f2bf(float f) {
    unsigned int u = __float_as_uint(f);
    unsigned int r = u + 0x7fffu + ((u >> 16) & 1u);
    return (unsigned short)(r >> 16);
}
__device__ __forceinline__ float2 bf2f2(unsigned int u) {
    float2 r;
    r.x = __uint_as_float(u << 16);
    r.y = __uint_as_float(u & 0xffff0000u);
    return r;
}

// ---------------- fused prep: x->bf16 + weight packing ----------------
__device__ __forceinline__ void pack_w(const float* __restrict__ W,
                                       unsigned short* __restrict__ Bp, int K, int N, int idx) {
    int i = idx & 7;
    int rest = idx >> 3;
    int lane = rest & 63;
    rest >>= 6;
    int KT = K / 32;
    int kt = rest % KT;
    int ct = rest / KT;
    int m = lane & 15, kb = lane >> 4;
    int k = kt * 32 + kb * 8 + i, col = ct * 16 + m;
    Bp[idx] = f2bf(W[(size_t)k * N + col]);
}

__global__ __launch_bounds__(256) void prep_kernel(const float* __restrict__ x,
                                                   unsigned short* __restrict__ xb, int n4,
                                                   const float* __restrict__ W1,
                                                   unsigned short* __restrict__ w1p,
                                                   const float* __restrict__ W2,
                                                   unsigned short* __restrict__ w2p,
                                                   const float* __restrict__ Wres,
                                                   unsigned short* __restrict__ wresp) {
    int nxb = (n4 + 255) / 256;
    int b = blockIdx.x;
    if (b < nxb) {
        int i = b * 256 + threadIdx.x;
        if (i < n4) {
            float4 v = ((const float4*)x)[i];
            ushort4 o;
            o.x = f2bf(v.x); o.y = f2bf(v.y); o.z = f2bf(v.z); o.w = f2bf(v.w);
            ((ushort4*)xb)[i] = o;
        }
        return;
    }
    b -= nxb;
    if (b < 48) { pack_w(W1, w1p, 128, 96, b * 256 + threadIdx.x); return; }
    b -= 48;
    if (b < 48) { pack_w(W2, w2p, 96, 128, b * 256 + threadIdx.x); return; }
    b -= 48;
    if (b < 64) { pack_w(Wres, wresp, 128, 128, b * 256 + threadIdx.x); }
}

// ---------------- CSR build ----------------
__global__ void hist_kernel(const int* __restrict__ dst, int E, int* __restrict__ deg) {
    for (int e = blockIdx.x * blockDim.x + threadIdx.x; e < E; e += gridDim.x * blockDim.x)
        atomicAdd(&deg[dst[e]], 1);
}

__global__ void scan_part(const int* __restrict__ deg, int* __restrict__ offs,
                          int* __restrict__ bsum, int n) {
    __shared__ int buf[256];
    int i = blockIdx.x * 256 + threadIdx.x;
    int v = (i < n) ? deg[i] : 0;
    buf[threadIdx.x] = v;
    __syncthreads();
    for (int s = 1; s < 256; s <<= 1) {
        int t = (threadIdx.x >= s) ? buf[threadIdx.x - s] : 0;
        __syncthreads();
        buf[threadIdx.x] += t;
        __syncthreads();
    }
    if (i < n) offs[i + 1] = buf[threadIdx.x];
    if (threadIdx.x == 255) bsum[blockIdx.x] = buf[255];
}

__global__ void scan_bsum(int* __restrict__ bsum, int nb) {
    __shared__ int buf[256];
    int v = (threadIdx.x < nb) ? bsum[threadIdx.x] : 0;
    buf[threadIdx.x] = v;
    __syncthreads();
    for (int s = 1; s < 256; s <<= 1) {
        int t = (threadIdx.x >= s) ? buf[threadIdx.x - s] : 0;
        __syncthreads();
        buf[threadIdx.x] += t;
        __syncthreads();
    }
    if (threadIdx.x < nb) bsum[threadIdx.x] = buf[threadIdx.x] - v;  // exclusive
}

__global__ void scan_add(int* __restrict__ offs, int* __restrict__ ctr,
                         const int* __restrict__ bsum, int n) {
    int i = blockIdx.x * 256 + threadIdx.x;
    if (i < n) {
        int v = offs[i + 1] + bsum[blockIdx.x];
        offs[i + 1] = v;
        if (i + 1 < n) ctr[i + 1] = v;
    }
    if (i == 0) { offs[0] = 0; ctr[0] = 0; }
}

__global__ void scatter_kernel(const int* __restrict__ src, const int* __restrict__ dst, int E,
                               int* __restrict__ ctr, int* __restrict__ csr) {
    for (int e = blockIdx.x * blockDim.x + threadIdx.x; e < E; e += gridDim.x * blockDim.x) {
        int p = atomicAdd(&ctr[dst[e]], 1);
        csr[p] = src[e];
    }
}

// ---------------- MFMA GEMM: one wave per 16-row tile, all col-tiles ----------------
template <int K, int N, int HEADS>
__global__ __launch_bounds__(256) void mfma_gemm(const unsigned short* __restrict__ A,
                                                 const unsigned short* __restrict__ Bp,
                                                 const float* __restrict__ bias,
                                                 float* __restrict__ outF,
                                                 unsigned short* __restrict__ outB,
                                                 const float* __restrict__ asrc,
                                                 const float* __restrict__ adst,
                                                 float* __restrict__ a_s,
                                                 float* __restrict__ a_d, int M) {
    constexpr int KT = K / 32, CT = N / 16;
    int w = blockIdx.x * 4 + (threadIdx.x >> 6);
    int row0 = w * 16;
    if (row0 >= M) return;
    int lane = threadIdx.x & 63;
    int m = lane & 15, kb = lane >> 4;
    const unsigned short* arow = A + (size_t)(row0 + m) * K + kb * 8;

    f32x4 acc[CT];
#pragma unroll
    for (int ct = 0; ct < CT; ++ct) acc[ct] = (f32x4){0.f, 0.f, 0.f, 0.f};

#pragma unroll
    for (int kt = 0; kt < KT; ++kt) {
        bf16x8 a = *(const bf16x8*)(arow + kt * 32);
#pragma unroll
        for (int ct = 0; ct < CT; ++ct) {
            bf16x8 b = *(const bf16x8*)(Bp + ((size_t)(ct * KT + kt) * 64 + lane) * 8);
            acc[ct] = __builtin_amdgcn_mfma_f32_16x16x32_bf16(a, b, acc[ct], 0, 0, 0);
        }
    }

#pragma unroll
    for (int r = 0; r < 4; ++r) {
        int row = row0 + kb * 4 + r;
#pragma unroll
        for (int ct = 0; ct < CT; ++ct) {
            int col = ct * 16 + m;
            float v = acc[ct][r] + (bias ? bias[col] : 0.f);
            if (outF) outF[(size_t)row * N + col] = v;
            if (outB) outB[(size_t)row * N + col] = f2bf(v);
        }
    }

    if (HEADS > 0) {
        float asv[CT], adv[CT];
#pragma unroll
        for (int ct = 0; ct < CT; ++ct) {
            int col = ct * 16 + m;
            asv[ct] = asrc[col];
            adv[ct] = adst[col];
        }
        constexpr int TPH = CT / (HEADS > 0 ? HEADS : 1);
#pragma unroll
        for (int r = 0; r < 4; ++r) {
            int row = row0 + kb * 4 + r;
#pragma unroll
            for (int h = 0; h < HEADS; ++h) {
                float s = 0.f, d = 0.f;
#pragma unroll
                for (int t = 0; t < TPH; ++t) {
                    int ct = h * TPH + t;
                    s += acc[ct][r] * asv[ct];
                    d += acc[ct][r] * adv[ct];
                }
#pragma unroll
                for (int off = 1; off <= 8; off <<= 1) {
                    s += __shfl_xor(s, off);
                    d += __shfl_xor(d, off);
                }
                if (m == 0) {
                    a_s[(size_t)row * HEADS + h] = s;
                    a_d[(size_t)row * HEADS + h] = d;
                }
            }
        }
    }
}

// ---------------- GAT aggregation: LDS edge scratch, lean serial gather ----------------
__global__ __launch_bounds__(256) void gat1_agg(const unsigned short* __restrict__ h1b,
                                                const float* __restrict__ a_s,
                                                const float* __restrict__ a_d,
                                                const int* __restrict__ offs,
                                                const int* __restrict__ csr,
                                                const float* __restrict__ b1,
                                                unsigned short* __restrict__ out1b, int n) {
    __shared__ uint2 sc[4][3][64];
    int wid = threadIdx.x >> 6;
    int node = blockIdx.x * 4 + wid;
    if (node >= n) return;
    int lane = threadIdx.x & 63;
    int head = lane >> 4; if (head > 2) head = 2;
    int beg = offs[node], end = offs[node + 1];
    int deg = end - beg;
    float ad0 = a_d[node * 3 + 0], ad1 = a_d[node * 3 + 1], ad2 = a_d[node * 3 + 2];
    float es0 = leaky(a_s[node * 3 + 0] + ad0);
    float es1 = leaky(a_s[node * 3 + 1] + ad1);
    float es2 = leaky(a_s[node * 3 + 2] + ad2);
    float2 hv0 = make_float2(0.f, 0.f);
    if (lane < 48) hv0 = bf2f2(*(const unsigned int*)&h1b[(size_t)node * 96 + 2 * lane]);

    float den;
    float2 acc;

    if (deg <= 64) {
        int s = 0;
        float l0 = NEG_INF, l1 = NEG_INF, l2 = NEG_INF;
        if (lane < deg) {
            s = csr[beg + lane];
            l0 = leaky(a_s[s * 3 + 0] + ad0);
            l1 = leaky(a_s[s * 3 + 1] + ad1);
            l2 = leaky(a_s[s * 3 + 2] + ad2);
        }
        float m0 = l0, m1 = l1, m2 = l2;
#pragma unroll
        for (int sh = 32; sh >= 1; sh >>= 1) {
            m0 = fmaxf(m0, __shfl_xor(m0, sh));
            m1 = fmaxf(m1, __shfl_xor(m1, sh));
            m2 = fmaxf(m2, __shfl_xor(m2, sh));
        }
        m0 = fmaxf(m0, es0); m1 = fmaxf(m1, es1); m2 = fmaxf(m2, es2);
        float e0 = 0.f, e1 = 0.f, e2 = 0.f;
        if (lane < deg) {
            e0 = __expf(l0 - m0); e1 = __expf(l1 - m1); e2 = __expf(l2 - m2);
        }
        sc[wid][0][lane] = make_uint2((unsigned)s, __float_as_uint(e0));
        sc[wid][1][lane] = make_uint2((unsigned)s, __float_as_uint(e1));
        sc[wid][2][lane] = make_uint2((unsigned)s, __float_as_uint(e2));
        float w0 = __expf(es0 - m0), w1 = __expf(es1 - m1), w2 = __expf(es2 - m2);
        den = (head == 0) ? w0 : ((head == 1) ? w1 : w2);
        float wSelf = (lane < 16) ? w0 : ((lane < 32) ? w1 : w2);
        acc.x = wSelf * hv0.x; acc.y = wSelf * hv0.y;

        int jj = 0;
        for (; jj + 1 < deg; jj += 2) {
            uint2 eA = sc[wid][head][jj];
            uint2 eB = sc[wid][head][jj + 1];
            float wA = __uint_as_float(eA.y), wB = __uint_as_float(eB.y);
            den += wA + wB;
            if (lane < 48) {
                float2 ha = bf2f2(*(const unsigned int*)&h1b[(size_t)eA.x * 96 + 2 * lane]);
                float2 hb = bf2f2(*(const unsigned int*)&h1b[(size_t)eB.x * 96 + 2 * lane]);
                acc.x += wA * ha.x + wB * hb.x;
                acc.y += wA * ha.y + wB * hb.y;
            }
        }
        if (jj < deg) {
            uint2 eA = sc[wid][head][jj];
            float wA = __uint_as_float(eA.y);
            den += wA;
            if (lane < 48) {
                float2 ha = bf2f2(*(const unsigned int*)&h1b[(size_t)eA.x * 96 + 2 * lane]);
                acc.x += wA * ha.x; acc.y += wA * ha.y;
            }
        }
    } else {
        float m0 = es0, m1 = es1, m2 = es2;
        for (int j = beg + lane; j < end; j += 64) {
            int s = csr[j];
            m0 = fmaxf(m0, leaky(a_s[s * 3 + 0] + ad0));
            m1 = fmaxf(m1, leaky(a_s[s * 3 + 1] + ad1));
            m2 = fmaxf(m2, leaky(a_s[s * 3 + 2] + ad2));
        }
#pragma unroll
        for (int sh = 32; sh >= 1; sh >>= 1) {
            m0 = fmaxf(m0, __shfl_xor(m0, sh));
            m1 = fmaxf(m1, __shfl_xor(m1, sh));
            m2 = fmaxf(m2, __shfl_xor(m2, sh));
        }
        float w0 = __expf(es0 - m0), w1 = __expf(es1 - m1), w2 = __expf(es2 - m2);
        den = (head == 0) ? w0 : ((head == 1) ? w1 : w2);
        float wSelf = (lane < 16) ? w0 : ((lane < 32) ? w1 : w2);
        acc.x = wSelf * hv0.x; acc.y = wSelf * hv0.y;
        for (int t0 = beg; t0 < end; t0 += 64) {
            int cnt = min(64, end - t0);
            int s = 0;
            float e0 = 0.f, e1 = 0.f, e2 = 0.f;
            if (lane < cnt) {
                s = csr[t0 + lane];
                e0 = __expf(leaky(a_s[s * 3 + 0] + ad0) - m0);
                e1 = __expf(leaky(a_s[s * 3 + 1] + ad1) - m1);
                e2 = __expf(leaky(a_s[s * 3 + 2] + ad2) - m2);
            }
            sc[wid][0][lane] = make_uint2((unsigned)s, __float_as_uint(e0));
            sc[wid][1][lane] = make_uint2((unsigned)s, __float_as_uint(e1));
            sc[wid][2][lane] = make_uint2((unsigned)s, __float_as_uint(e2));
            for (int jj = 0; jj < cnt; ++jj) {
                uint2 eA = sc[wid][head][jj];
                float wA = __uint_as_float(eA.y);
                den += wA;
                if (lane < 48) {
                    float2 ha = bf2f2(*(const unsigned int*)&h1b[(size_t)eA.x * 96 + 2 * lane]);
                    acc.x += wA * ha.x; acc.y += wA * ha.y;
                }
            }
        }
    }

    if (lane < 48) {
        float inv = 1.f / (den + 1e-16f);
        ushort2 o;
        o.x = f2bf(acc.x * inv + b1[2 * lane]);
        o.y = f2bf(acc.y * inv + b1[2 * lane + 1]);
        *(ushort2*)&out1b[(size_t)node * 96 + 2 * lane] = o;
    }
}

__global__ __launch_bounds__(256) void gat2_agg(const unsigned short* __restrict__ h2b,
                                                const float* __restrict__ a_s,
                                                const float* __restrict__ a_d,
                                                const int* __restrict__ offs,
                                                const int* __restrict__ csr,
                                                const float* __restrict__ b2,
                                                float* __restrict__ out, int n) {
    __shared__ uint2 sc[4][64];
    int wid = threadIdx.x >> 6;
    int node = blockIdx.x * 4 + wid;
    if (node >= n) return;
    int lane = threadIdx.x & 63;
    int beg = offs[node], end = offs[node + 1];
    int deg = end - beg;
    float ad = a_d[node];
    float es = leaky(a_s[node] + ad);
    float2 hv0 = bf2f2(*(const unsigned int*)&h2b[(size_t)node * 128 + 2 * lane]);
    float den;
    float2 acc;

    if (deg <= 64) {
        int s = 0;
        float l = NEG_INF;
        if (lane < deg) {
            s = csr[beg + lane];
            l = leaky(a_s[s] + ad);
        }
        float m = l;
#pragma unroll
        for (int sh = 32; sh >= 1; sh >>= 1) m = fmaxf(m, __shfl_xor(m, sh));
        m = fmaxf(m, es);
        float e = (lane < deg) ? __expf(l - m) : 0.f;
        sc[wid][lane] = make_uint2((unsigned)s, __float_as_uint(e));
        float wSelf = __expf(es - m);
        den = wSelf;
        acc.x = wSelf * hv0.x; acc.y = wSelf * hv0.y;

        int jj = 0;
        for (; jj + 1 < deg; jj += 2) {
            uint2 eA = sc[wid][jj];
            uint2 eB = sc[wid][jj + 1];
            float wA = __uint_as_float(eA.y), wB = __uint_as_float(eB.y);
            den += wA + wB;
            float2 ha = bf2f2(*(const unsigned int*)&h2b[(size_t)eA.x * 128 + 2 * lane]);
            float2 hb = bf2f2(*(const unsigned int*)&h2b[(size_t)eB.x * 128 + 2 * lane]);
            acc.x += wA * ha.x + wB * hb.x;
            acc.y += wA * ha.y + wB * hb.y;
        }
        if (jj < deg) {
            uint2 eA = sc[wid][jj];
            float wA = __uint_as_float(eA.y);
            den += wA;
            float2 ha = bf2f2(*(const unsigned int*)&h2b[(size_t)eA.x * 128 + 2 * lane]);
            acc.x += wA * ha.x; acc.y += wA * ha.y;
        }
    } else {
        float m = es;
        for (int j = beg + lane; j < end; j += 64) {
            int s = csr[j];
            m = fmaxf(m, leaky(a_s[s] + ad));
        }
#pragma unroll
        for (int sh = 32; sh >= 1; sh >>= 1) m = fmaxf(m, __shfl_xor(m, sh));
        float wSelf = __expf(es - m);
        den = wSelf;
        acc.x = wSelf * hv0.x; acc.y = wSelf * hv0.y;
        for (int t0 = beg; t0 < end; t0 += 64) {
            int cnt = min(64, end - t0);
            int s = 0;
            float e = 0.f;
            if (lane < cnt) {
                s = csr[t0 + lane];
                e = __expf(leaky(a_s[s] + ad) - m);
            }
            sc[wid][lane] = make_uint2((unsigned)s, __float_as_uint(e));
            for (int jj = 0; jj < cnt; ++jj) {
                uint2 eA = sc[wid][jj];
                float wA = __uint_as_float(eA.y);
                den += wA;
                float2 ha = bf2f2(*(const unsigned int*)&h2b[(size_t)eA.x * 128 + 2 * lane]);
                acc.x += wA * ha.x; acc.y += wA * ha.y;
            }
        }
    }

    float inv = 1.f / (den + 1e-16f);
    float2 o;
    o.x = acc.x * inv + b2[2 * lane];
    o.y = acc.y * inv + b2[2 * lane + 1];
    *(float2*)&out[(size_t)node * 128 + 2 * lane] = o;
}

// ---------------- BatchNorm stats: 4-wide ILP unroll ----------------
__global__ __launch_bounds__(256) void bn_stats(const float* __restrict__ x,
                                                float* __restrict__ sums, int n, int rpb) {
    __shared__ float4 shs[8][32];
    __shared__ float4 shq[8][32];
    int tid = threadIdx.x;
    int c = tid & 31;
    int rg = tid >> 5;
    int r0 = blockIdx.x * rpb;
    int r1 = min(r0 + rpb, n);
    float4 s0 = make_float4(0.f, 0.f, 0.f, 0.f), s1 = s0, s2 = s0, s3 = s0;
    float4 q0 = s0, q1 = s0, q2 = s0, q3 = s0;
    int r = r0 + rg;
    for (; r + 24 < r1; r += 32) {
        float4 v0 = ((const float4*)x)[(size_t)(r +  0) * 32 + c];
        float4 v1 = ((const float4*)x)[(size_t)(r +  8) * 32 + c];
        float4 v2 = ((const float4*)x)[(size_t)(r + 16) * 32 + c];
        float4 v3 = ((const float4*)x)[(size_t)(r + 24) * 32 + c];
        s0.x += v0.x; s0.y += v0.y; s0.z += v0.z; s0.w += v0.w;
        q0.x += v0.x * v0.x; q0.y += v0.y * v0.y; q0.z += v0.z * v0.z; q0.w += v0.w * v0.w;
        s1.x += v1.x; s1.y += v1.y; s1.z += v1.z; s1.w += v1.w;
        q1.x += v1.x * v1.x; q1.y += v1.y * v1.y; q1.z += v1.z * v1.z; q1.w += v1.w * v1.w;
        s2.x += v2.x; s2.y += v2.y; s2.z += v2.z; s2.w += v2.w;
        q2.x += v2.x * v2.x; q2.y += v2.y * v2.y; q2.z += v2.z * v2.z; q2.w += v2.w * v2.w;
        s3.x += v3.x; s3.y += v3.y; s3.z += v3.z; s3.w += v3.w;
        q3.x += v3.x * v3.x; q3.y += v3.y * v3.y; q3.z += v3.z * v3.z; q3.w += v3.w * v3.w;
    }
    for (; r < r1; r += 8) {
        float4 v = ((const float4*)x)[(size_t)r * 32 + c];
        s0.x += v.x; s0.y += v.y; s0.z += v.z; s0.w += v.w;
        q0.x += v.x * v.x; q0.y += v.y * v.y; q0.z += v.z * v.z; q0.w += v.w * v.w;
    }
    float4 s = make_float4(s0.x + s1.x + s2.x + s3.x, s0.y + s1.y + s2.y + s3.y,
                           s0.z + s1.z + s2.z + s3.z, s0.w + s1.w + s2.w + s3.w);
    float4 q = make_float4(q0.x + q1.x + q2.x + q3.x, q0.y + q1.y + q2.y + q3.y,
                           q0.z + q1.z + q2.z + q3.z, q0.w + q1.w + q2.w + q3.w);
    shs[rg][c] = s; shq[rg][c] = q;
    __syncthreads();
#pragma unroll
    for (int h = 4; h >= 1; h >>= 1) {
        if (rg < h) {
            float4 a = shs[rg + h][c], b = shq[rg + h][c];
            float4 cs = shs[rg][c], cq = shq[rg][c];
            cs.x += a.x; cs.y += a.y; cs.z += a.z; cs.w += a.w;
            cq.x += b.x; cq.y += b.y; cq.z += b.z; cq.w += b.w;
            shs[rg][c] = cs; shq[rg][c] = cq;
        }
        __syncthreads();
    }
    if (rg == 0) {
        float4 S = shs[0][c], Q = shq[0][c];
        atomicAdd(&sums[c * 4 + 0], S.x);
        atomicAdd(&sums[c * 4 + 1], S.y);
        atomicAdd(&sums[c * 4 + 2], S.z);
        atomicAdd(&sums[c * 4 + 3], S.w);
        atomicAdd(&sums[128 + c * 4 + 0], Q.x);
        atomicAdd(&sums[128 + c * 4 + 1], Q.y);
        atomicAdd(&sums[128 + c * 4 + 2], Q.z);
        atomicAdd(&sums[128 + c * 4 + 3], Q.w);
    }
}

// ---------------- fused BN-normalize + ReLU + residual ----------------
__global__ void final_kernel(const float* __restrict__ out2, const float* __restrict__ resid,
                             const float* __restrict__ sums, const float* __restrict__ gamma,
                             const float* __restrict__ beta, float* __restrict__ out, int n) {
    int i = blockIdx.x * blockDim.x + threadIdx.x;  // over n*32 float4s
    if (i >= n * 32) return;
    int c0 = (i & 31) * 4;
    float invN = 1.f / (float)n;
    float4 v = ((const float4*)out2)[i];
    float4 r = ((const float4*)resid)[i];
    float4 o;
    const float* vp = &v.x;
    const float* rp = &r.x;
    float* op = &o.x;
#pragma unroll
    for (int q = 0; q < 4; ++q) {
        int c = c0 + q;
        float mu = sums[c] * invN;
        float var = sums[128 + c] * invN - mu * mu;
        float g = gamma[c] * rsqrtf(var + 1e-5f);
        float y = (vp[q] - mu) * g + beta[c];
        y = fmaxf(y, 0.f);
        op[q] = y + rp[q];
    }
    ((float4*)out)[i] = o;
}

extern "C" void kernel_launch(void* const* d_in, const int* in_sizes, int n_in,
                              void* d_out, int out_size, void* d_ws, size_t ws_size,
                              hipStream_t stream) {
    const float* x     = (const float*)d_in[0];
    const int*   ei    = (const int*)d_in[1];
    const float* W1    = (const float*)d_in[2];
    const float* asrc1 = (const float*)d_in[3];
    const float* adst1 = (const float*)d_in[4];
    const float* b1    = (const float*)d_in[5];
    const float* W2    = (const float*)d_in[6];
    const float* asrc2 = (const float*)d_in[7];
    const float* adst2 = (const float*)d_in[8];
    const float* b2    = (const float*)d_in[9];
    const float* gamma = (const float*)d_in[10];
    const float* beta  = (const float*)d_in[11];
    const float* Wres  = (const float*)d_in[12];
    const float* bres  = (const float*)d_in[13];

    const int n = in_sizes[0] / 128;  // 50000
    const int E = in_sizes[1] / 2;    // 800000

    char* ws = (char*)d_ws;
    size_t off = 0;
    auto alloc = [&](size_t bytes) {
        void* p = ws + off;
        off = (off + bytes + 255) & ~(size_t)255;
        return p;
    };
    float* resid = (float*)alloc((size_t)n * 128 * 4);
    float* out2  = (float*)alloc((size_t)n * 128 * 4);
    float* as1   = (float*)alloc((size_t)n * 3 * 4);
    float* ad1   = (float*)alloc((size_t)n * 3 * 4);
    float* as2   = (float*)alloc((size_t)n * 4);
    float* ad2   = (float*)alloc((size_t)n * 4);
    float* sums  = (float*)alloc(256 * 4);
    unsigned short* xb    = (unsigned short*)alloc((size_t)n * 128 * 2);
    unsigned short* h1b   = (unsigned short*)alloc((size_t)n * 96 * 2);
    unsigned short* h2b   = (unsigned short*)alloc((size_t)n * 128 * 2);
    unsigned short* out1b = (unsigned short*)alloc((size_t)n * 96 * 2);
    unsigned short* w1p   = (unsigned short*)alloc(128 * 96 * 2);
    unsigned short* w2p   = (unsigned short*)alloc(96 * 128 * 2);
    unsigned short* wresp = (unsigned short*)alloc(128 * 128 * 2);
    int* deg  = (int*)alloc((size_t)n * 4);
    int* offs = (int*)alloc((size_t)(n + 1) * 4);
    int* ctr  = (int*)alloc((size_t)(n + 1) * 4);
    int* bsum = (int*)alloc(256 * 4);
    int* csr  = (int*)alloc((size_t)E * 4);

    hipMemsetAsync(deg, 0, (size_t)n * 4, stream);
    hipMemsetAsync(sums, 0, 256 * 4, stream);

    const int* srcIdx = ei;
    const int* dstIdx = ei + E;
    const int nb = (n + 255) / 256;

    // fused prep: x->bf16 + 3 weight packs
    const int nxb = (n * 32 + 255) / 256;
    prep_kernel<<<nxb + 160, 256, 0, stream>>>(x, xb, n * 32, W1, w1p, W2, w2p, Wres, wresp);

    // CSR
    hist_kernel<<<2048, 256, 0, stream>>>(dstIdx, E, deg);
    scan_part<<<nb, 256, 0, stream>>>(deg, offs, bsum, n);
    scan_bsum<<<1, 256, 0, stream>>>(bsum, nb);
    scan_add<<<nb, 256, 0, stream>>>(offs, ctr, bsum, n);
    scatter_kernel<<<2048, 256, 0, stream>>>(srcIdx, dstIdx, E, ctr, csr);

    const int mt = (n + 15) / 16;          // 3125 row tiles
    const int gblk = (mt + 3) / 4;

    mfma_gemm<128, 96, 3><<<gblk, 256, 0, stream>>>(xb, w1p, nullptr, nullptr, h1b,
                                                    asrc1, adst1, as1, ad1, n);
    mfma_gemm<128, 128, 0><<<gblk, 256, 0, stream>>>(xb, wresp, bres, resid, nullptr,
                                                     nullptr, nullptr, nullptr, nullptr, n);
    gat1_agg<<<(n + 3) / 4, 256, 0, stream>>>(h1b, as1, ad1, offs, csr, b1, out1b, n);
    mfma_gemm<96, 128, 1><<<gblk, 256, 0, stream>>>(out1b, w2p, nullptr, nullptr, h2b,
                                                    asrc2, adst2, as2, ad2, n);
    gat2_agg<<<(n + 3) / 4, 256, 0, stream>>>(h2b, as2, ad2, offs, csr, b2, out2, n);
    bn_stats<<<512, 256, 0, stream>>>(out2, sums, n, (n + 511) / 512);
    final_kernel<<<(n * 32 + 255) / 256, 256, 0, stream>>>(out2, resid, sums, gamma, beta,
                                                           (float*)d_out, n);
}

// Round 7
// 262.512 us; speedup vs baseline: 2.3930x; 1.1451x over previous
//
#include <hip/hip_runtime.h>

#define NEG 0.2f
#define NEG_INF (-1e30f)

typedef __attribute__((ext_vector_type(8))) short bf16x8;
typedef __attribute__((ext_vector_type(4))) float f32x4;

__device__ __forceinline__ float leaky(float e) { return e > 0.f ? e : NEG * e; }

__device__ __forceinline__ unsigned short f2bf(float f) {
    unsigned int u = __float_as_uint(f);
    unsigned int r = u + 0x7fffu + ((u >> 16) & 1u);
    return (unsigned short)(r >> 16);
}
__device__ __forceinline__ float2 bf2f2(unsigned int u) {
    float2 r;
    r.x = __uint_as_float(u << 16);
    r.y = __uint_as_float(u & 0xffff0000u);
    return r;
}

// ---------------- fused prep: x->bf16 + weight packing ----------------
__device__ __forceinline__ void pack_w(const float* __restrict__ W,
                                       unsigned short* __restrict__ Bp, int K, int N, int idx) {
    int i = idx & 7;
    int rest = idx >> 3;
    int lane = rest & 63;
    rest >>= 6;
    int KT = K / 32;
    int kt = rest % KT;
    int ct = rest / KT;
    int m = lane & 15, kb = lane >> 4;
    int k = kt * 32 + kb * 8 + i, col = ct * 16 + m;
    Bp[idx] = f2bf(W[(size_t)k * N + col]);
}

__global__ __launch_bounds__(256) void prep_kernel(const float* __restrict__ x,
                                                   unsigned short* __restrict__ xb, int n4,
                                                   const float* __restrict__ W1,
                                                   unsigned short* __restrict__ w1p,
                                                   const float* __restrict__ W2,
                                                   unsigned short* __restrict__ w2p,
                                                   const float* __restrict__ Wres,
                                                   unsigned short* __restrict__ wresp) {
    int nxb = (n4 + 255) / 256;
    int b = blockIdx.x;
    if (b < nxb) {
        int i = b * 256 + threadIdx.x;
        if (i < n4) {
            float4 v = ((const float4*)x)[i];
            ushort4 o;
            o.x = f2bf(v.x); o.y = f2bf(v.y); o.z = f2bf(v.z); o.w = f2bf(v.w);
            ((ushort4*)xb)[i] = o;
        }
        return;
    }
    b -= nxb;
    if (b < 48) { pack_w(W1, w1p, 128, 96, b * 256 + threadIdx.x); return; }
    b -= 48;
    if (b < 48) { pack_w(W2, w2p, 96, 128, b * 256 + threadIdx.x); return; }
    b -= 48;
    if (b < 64) { pack_w(Wres, wresp, 128, 128, b * 256 + threadIdx.x); }
}

// ---------------- CSR build ----------------
__global__ void hist_kernel(const int* __restrict__ dst, int E, int* __restrict__ deg) {
    for (int e = blockIdx.x * blockDim.x + threadIdx.x; e < E; e += gridDim.x * blockDim.x)
        atomicAdd(&deg[dst[e]], 1);
}

__global__ void scan_part(const int* __restrict__ deg, int* __restrict__ offs,
                          int* __restrict__ bsum, int n) {
    __shared__ int buf[256];
    int i = blockIdx.x * 256 + threadIdx.x;
    int v = (i < n) ? deg[i] : 0;
    buf[threadIdx.x] = v;
    __syncthreads();
    for (int s = 1; s < 256; s <<= 1) {
        int t = (threadIdx.x >= s) ? buf[threadIdx.x - s] : 0;
        __syncthreads();
        buf[threadIdx.x] += t;
        __syncthreads();
    }
    if (i < n) offs[i + 1] = buf[threadIdx.x];
    if (threadIdx.x == 255) bsum[blockIdx.x] = buf[255];
}

__global__ void scan_bsum(int* __restrict__ bsum, int nb) {
    __shared__ int buf[256];
    int v = (threadIdx.x < nb) ? bsum[threadIdx.x] : 0;
    buf[threadIdx.x] = v;
    __syncthreads();
    for (int s = 1; s < 256; s <<= 1) {
        int t = (threadIdx.x >= s) ? buf[threadIdx.x - s] : 0;
        __syncthreads();
        buf[threadIdx.x] += t;
        __syncthreads();
    }
    if (threadIdx.x < nb) bsum[threadIdx.x] = buf[threadIdx.x] - v;  // exclusive
}

__global__ void scan_add(int* __restrict__ offs, int* __restrict__ ctr,
                         const int* __restrict__ bsum, int n) {
    int i = blockIdx.x * 256 + threadIdx.x;
    if (i < n) {
        int v = offs[i + 1] + bsum[blockIdx.x];
        offs[i + 1] = v;
        if (i + 1 < n) ctr[i + 1] = v;
    }
    if (i == 0) { offs[0] = 0; ctr[0] = 0; }
}

__global__ void scatter_kernel(const int* __restrict__ src, const int* __restrict__ dst, int E,
                               int* __restrict__ ctr, int* __restrict__ csr) {
    for (int e = blockIdx.x * blockDim.x + threadIdx.x; e < E; e += gridDim.x * blockDim.x) {
        int p = atomicAdd(&ctr[dst[e]], 1);
        csr[p] = src[e];
    }
}

// ---------------- MFMA GEMM: one wave per 16-row tile, all col-tiles ----------------
template <int K, int N, int HEADS>
__global__ __launch_bounds__(256) void mfma_gemm(const unsigned short* __restrict__ A,
                                                 const unsigned short* __restrict__ Bp,
                                                 const float* __restrict__ bias,
                                                 float* __restrict__ outF,
                                                 unsigned short* __restrict__ outB,
                                                 const float* __restrict__ asrc,
                                                 const float* __restrict__ adst,
                                                 float* __restrict__ a_s,
                                                 float* __restrict__ a_d, int M) {
    constexpr int KT = K / 32, CT = N / 16;
    int w = blockIdx.x * 4 + (threadIdx.x >> 6);
    int row0 = w * 16;
    if (row0 >= M) return;
    int lane = threadIdx.x & 63;
    int m = lane & 15, kb = lane >> 4;
    const unsigned short* arow = A + (size_t)(row0 + m) * K + kb * 8;

    f32x4 acc[CT];
#pragma unroll
    for (int ct = 0; ct < CT; ++ct) acc[ct] = (f32x4){0.f, 0.f, 0.f, 0.f};

#pragma unroll
    for (int kt = 0; kt < KT; ++kt) {
        bf16x8 a = *(const bf16x8*)(arow + kt * 32);
#pragma unroll
        for (int ct = 0; ct < CT; ++ct) {
            bf16x8 b = *(const bf16x8*)(Bp + ((size_t)(ct * KT + kt) * 64 + lane) * 8);
            acc[ct] = __builtin_amdgcn_mfma_f32_16x16x32_bf16(a, b, acc[ct], 0, 0, 0);
        }
    }

#pragma unroll
    for (int r = 0; r < 4; ++r) {
        int row = row0 + kb * 4 + r;
#pragma unroll
        for (int ct = 0; ct < CT; ++ct) {
            int col = ct * 16 + m;
            float v = acc[ct][r] + (bias ? bias[col] : 0.f);
            if (outF) outF[(size_t)row * N + col] = v;
            if (outB) outB[(size_t)row * N + col] = f2bf(v);
        }
    }

    if (HEADS > 0) {
        float asv[CT], adv[CT];
#pragma unroll
        for (int ct = 0; ct < CT; ++ct) {
            int col = ct * 16 + m;
            asv[ct] = asrc[col];
            adv[ct] = adst[col];
        }
        constexpr int TPH = CT / (HEADS > 0 ? HEADS : 1);
#pragma unroll
        for (int r = 0; r < 4; ++r) {
            int row = row0 + kb * 4 + r;
#pragma unroll
            for (int h = 0; h < HEADS; ++h) {
                float s = 0.f, d = 0.f;
#pragma unroll
                for (int t = 0; t < TPH; ++t) {
                    int ct = h * TPH + t;
                    s += acc[ct][r] * asv[ct];
                    d += acc[ct][r] * adv[ct];
                }
#pragma unroll
                for (int off = 1; off <= 8; off <<= 1) {
                    s += __shfl_xor(s, off);
                    d += __shfl_xor(d, off);
                }
                if (m == 0) {
                    a_s[(size_t)row * HEADS + h] = s;
                    a_d[(size_t)row * HEADS + h] = d;
                }
            }
        }
    }
}

// ---------------- GAT aggregation: LDS edge scratch, lean serial gather ----------------
__global__ __launch_bounds__(256) void gat1_agg(const unsigned short* __restrict__ h1b,
                                                const float* __restrict__ a_s,
                                                const float* __restrict__ a_d,
                                                const int* __restrict__ offs,
                                                const int* __restrict__ csr,
                                                const float* __restrict__ b1,
                                                unsigned short* __restrict__ out1b, int n) {
    __shared__ uint2 sc[4][3][64];
    int wid = threadIdx.x >> 6;
    int node = blockIdx.x * 4 + wid;
    if (node >= n) return;
    int lane = threadIdx.x & 63;
    int head = lane >> 4; if (head > 2) head = 2;
    int beg = offs[node], end = offs[node + 1];
    int deg = end - beg;
    float ad0 = a_d[node * 3 + 0], ad1 = a_d[node * 3 + 1], ad2 = a_d[node * 3 + 2];
    float es0 = leaky(a_s[node * 3 + 0] + ad0);
    float es1 = leaky(a_s[node * 3 + 1] + ad1);
    float es2 = leaky(a_s[node * 3 + 2] + ad2);
    float2 hv0 = make_float2(0.f, 0.f);
    if (lane < 48) hv0 = bf2f2(*(const unsigned int*)&h1b[(size_t)node * 96 + 2 * lane]);

    float den;
    float2 acc;

    if (deg <= 64) {
        int s = 0;
        float l0 = NEG_INF, l1 = NEG_INF, l2 = NEG_INF;
        if (lane < deg) {
            s = csr[beg + lane];
            l0 = leaky(a_s[s * 3 + 0] + ad0);
            l1 = leaky(a_s[s * 3 + 1] + ad1);
            l2 = leaky(a_s[s * 3 + 2] + ad2);
        }
        float m0 = l0, m1 = l1, m2 = l2;
#pragma unroll
        for (int sh = 32; sh >= 1; sh >>= 1) {
            m0 = fmaxf(m0, __shfl_xor(m0, sh));
            m1 = fmaxf(m1, __shfl_xor(m1, sh));
            m2 = fmaxf(m2, __shfl_xor(m2, sh));
        }
        m0 = fmaxf(m0, es0); m1 = fmaxf(m1, es1); m2 = fmaxf(m2, es2);
        float e0 = 0.f, e1 = 0.f, e2 = 0.f;
        if (lane < deg) {
            e0 = __expf(l0 - m0); e1 = __expf(l1 - m1); e2 = __expf(l2 - m2);
        }
        sc[wid][0][lane] = make_uint2((unsigned)s, __float_as_uint(e0));
        sc[wid][1][lane] = make_uint2((unsigned)s, __float_as_uint(e1));
        sc[wid][2][lane] = make_uint2((unsigned)s, __float_as_uint(e2));
        float w0 = __expf(es0 - m0), w1 = __expf(es1 - m1), w2 = __expf(es2 - m2);
        den = (head == 0) ? w0 : ((head == 1) ? w1 : w2);
        float wSelf = (lane < 16) ? w0 : ((lane < 32) ? w1 : w2);
        acc.x = wSelf * hv0.x; acc.y = wSelf * hv0.y;

        int jj = 0;
        for (; jj + 1 < deg; jj += 2) {
            uint2 eA = sc[wid][head][jj];
            uint2 eB = sc[wid][head][jj + 1];
            float wA = __uint_as_float(eA.y), wB = __uint_as_float(eB.y);
            den += wA + wB;
            if (lane < 48) {
                float2 ha = bf2f2(*(const unsigned int*)&h1b[(size_t)eA.x * 96 + 2 * lane]);
                float2 hb = bf2f2(*(const unsigned int*)&h1b[(size_t)eB.x * 96 + 2 * lane]);
                acc.x += wA * ha.x + wB * hb.x;
                acc.y += wA * ha.y + wB * hb.y;
            }
        }
        if (jj < deg) {
            uint2 eA = sc[wid][head][jj];
            float wA = __uint_as_float(eA.y);
            den += wA;
            if (lane < 48) {
                float2 ha = bf2f2(*(const unsigned int*)&h1b[(size_t)eA.x * 96 + 2 * lane]);
                acc.x += wA * ha.x; acc.y += wA * ha.y;
            }
        }
    } else {
        float m0 = es0, m1 = es1, m2 = es2;
        for (int j = beg + lane; j < end; j += 64) {
            int s = csr[j];
            m0 = fmaxf(m0, leaky(a_s[s * 3 + 0] + ad0));
            m1 = fmaxf(m1, leaky(a_s[s * 3 + 1] + ad1));
            m2 = fmaxf(m2, leaky(a_s[s * 3 + 2] + ad2));
        }
#pragma unroll
        for (int sh = 32; sh >= 1; sh >>= 1) {
            m0 = fmaxf(m0, __shfl_xor(m0, sh));
            m1 = fmaxf(m1, __shfl_xor(m1, sh));
            m2 = fmaxf(m2, __shfl_xor(m2, sh));
        }
        float w0 = __expf(es0 - m0), w1 = __expf(es1 - m1), w2 = __expf(es2 - m2);
        den = (head == 0) ? w0 : ((head == 1) ? w1 : w2);
        float wSelf = (lane < 16) ? w0 : ((lane < 32) ? w1 : w2);
        acc.x = wSelf * hv0.x; acc.y = wSelf * hv0.y;
        for (int t0 = beg; t0 < end; t0 += 64) {
            int cnt = min(64, end - t0);
            int s = 0;
            float e0 = 0.f, e1 = 0.f, e2 = 0.f;
            if (lane < cnt) {
                s = csr[t0 + lane];
                e0 = __expf(leaky(a_s[s * 3 + 0] + ad0) - m0);
                e1 = __expf(leaky(a_s[s * 3 + 1] + ad1) - m1);
                e2 = __expf(leaky(a_s[s * 3 + 2] + ad2) - m2);
            }
            sc[wid][0][lane] = make_uint2((unsigned)s, __float_as_uint(e0));
            sc[wid][1][lane] = make_uint2((unsigned)s, __float_as_uint(e1));
            sc[wid][2][lane] = make_uint2((unsigned)s, __float_as_uint(e2));
            for (int jj = 0; jj < cnt; ++jj) {
                uint2 eA = sc[wid][head][jj];
                float wA = __uint_as_float(eA.y);
                den += wA;
                if (lane < 48) {
                    float2 ha = bf2f2(*(const unsigned int*)&h1b[(size_t)eA.x * 96 + 2 * lane]);
                    acc.x += wA * ha.x; acc.y += wA * ha.y;
                }
            }
        }
    }

    if (lane < 48) {
        float inv = 1.f / (den + 1e-16f);
        ushort2 o;
        o.x = f2bf(acc.x * inv + b1[2 * lane]);
        o.y = f2bf(acc.y * inv + b1[2 * lane + 1]);
        *(ushort2*)&out1b[(size_t)node * 96 + 2 * lane] = o;
    }
}

// gat2: 128 ch, 1 head; writes bf16 out2 AND accumulates BN partial sums.
__global__ __launch_bounds__(256) void gat2_agg(const unsigned short* __restrict__ h2b,
                                                const float* __restrict__ a_s,
                                                const float* __restrict__ a_d,
                                                const int* __restrict__ offs,
                                                const int* __restrict__ csr,
                                                const float* __restrict__ b2,
                                                unsigned short* __restrict__ out2b,
                                                float* __restrict__ part, int n) {
    __shared__ uint2 sc[4][64];
    __shared__ float4 red[4][64];
    int wid = threadIdx.x >> 6;
    int node = blockIdx.x * 4 + wid;
    int lane = threadIdx.x & 63;
    float2 o = make_float2(0.f, 0.f);

    if (node < n) {
        int beg = offs[node], end = offs[node + 1];
        int deg = end - beg;
        float ad = a_d[node];
        float es = leaky(a_s[node] + ad);
        float2 hv0 = bf2f2(*(const unsigned int*)&h2b[(size_t)node * 128 + 2 * lane]);
        float den;
        float2 acc;

        if (deg <= 64) {
            int s = 0;
            float l = NEG_INF;
            if (lane < deg) {
                s = csr[beg + lane];
                l = leaky(a_s[s] + ad);
            }
            float m = l;
#pragma unroll
            for (int sh = 32; sh >= 1; sh >>= 1) m = fmaxf(m, __shfl_xor(m, sh));
            m = fmaxf(m, es);
            float e = (lane < deg) ? __expf(l - m) : 0.f;
            sc[wid][lane] = make_uint2((unsigned)s, __float_as_uint(e));
            float wSelf = __expf(es - m);
            den = wSelf;
            acc.x = wSelf * hv0.x; acc.y = wSelf * hv0.y;

            int jj = 0;
            for (; jj + 1 < deg; jj += 2) {
                uint2 eA = sc[wid][jj];
                uint2 eB = sc[wid][jj + 1];
                float wA = __uint_as_float(eA.y), wB = __uint_as_float(eB.y);
                den += wA + wB;
                float2 ha = bf2f2(*(const unsigned int*)&h2b[(size_t)eA.x * 128 + 2 * lane]);
                float2 hb = bf2f2(*(const unsigned int*)&h2b[(size_t)eB.x * 128 + 2 * lane]);
                acc.x += wA * ha.x + wB * hb.x;
                acc.y += wA * ha.y + wB * hb.y;
            }
            if (jj < deg) {
                uint2 eA = sc[wid][jj];
                float wA = __uint_as_float(eA.y);
                den += wA;
                float2 ha = bf2f2(*(const unsigned int*)&h2b[(size_t)eA.x * 128 + 2 * lane]);
                acc.x += wA * ha.x; acc.y += wA * ha.y;
            }
        } else {
            float m = es;
            for (int j = beg + lane; j < end; j += 64) {
                int s = csr[j];
                m = fmaxf(m, leaky(a_s[s] + ad));
            }
#pragma unroll
            for (int sh = 32; sh >= 1; sh >>= 1) m = fmaxf(m, __shfl_xor(m, sh));
            float wSelf = __expf(es - m);
            den = wSelf;
            acc.x = wSelf * hv0.x; acc.y = wSelf * hv0.y;
            for (int t0 = beg; t0 < end; t0 += 64) {
                int cnt = min(64, end - t0);
                int s = 0;
                float e = 0.f;
                if (lane < cnt) {
                    s = csr[t0 + lane];
                    e = __expf(leaky(a_s[s] + ad) - m);
                }
                sc[wid][lane] = make_uint2((unsigned)s, __float_as_uint(e));
                for (int jj = 0; jj < cnt; ++jj) {
                    uint2 eA = sc[wid][jj];
                    float wA = __uint_as_float(eA.y);
                    den += wA;
                    float2 ha = bf2f2(*(const unsigned int*)&h2b[(size_t)eA.x * 128 + 2 * lane]);
                    acc.x += wA * ha.x; acc.y += wA * ha.y;
                }
            }
        }

        float inv = 1.f / (den + 1e-16f);
        o.x = acc.x * inv + b2[2 * lane];
        o.y = acc.y * inv + b2[2 * lane + 1];
        ushort2 ob;
        ob.x = f2bf(o.x); ob.y = f2bf(o.y);
        *(ushort2*)&out2b[(size_t)node * 128 + 2 * lane] = ob;
    }

    // ---- block-level BN partial reduction (all threads participate) ----
    red[wid][lane] = make_float4(o.x, o.y, o.x * o.x, o.y * o.y);
    __syncthreads();
    if (wid == 0) {
        float4 a = red[0][lane], b = red[1][lane], c = red[2][lane], d = red[3][lane];
        float sx = a.x + b.x + c.x + d.x;
        float sy = a.y + b.y + c.y + d.y;
        float qx = a.z + b.z + c.z + d.z;
        float qy = a.w + b.w + c.w + d.w;
        float* p = part + (size_t)(blockIdx.x & 63) * 256;
        atomicAdd(&p[2 * lane + 0], sx);
        atomicAdd(&p[2 * lane + 1], sy);
        atomicAdd(&p[128 + 2 * lane + 0], qx);
        atomicAdd(&p[128 + 2 * lane + 1], qy);
    }
}

// ---------------- BN finalize: fold 64 partials -> per-channel scale/shift ----------------
__global__ void bn_finalize(const float* __restrict__ part, const float* __restrict__ gamma,
                            const float* __restrict__ beta, float* __restrict__ ss, int n) {
    int c = threadIdx.x;  // 128
    float S = 0.f, Q = 0.f;
    for (int k = 0; k < 64; ++k) {
        S += part[(size_t)k * 256 + c];
        Q += part[(size_t)k * 256 + 128 + c];
    }
    float invN = 1.f / (float)n;
    float mu = S * invN;
    float var = Q * invN - mu * mu;
    float g = gamma[c] * rsqrtf(var + 1e-5f);
    ss[c] = g;
    ss[128 + c] = beta[c] - mu * g;
}

// ---------------- fused BN-normalize + ReLU + residual (bf16 in, fp32 out) ----------------
__global__ void final_kernel(const unsigned short* __restrict__ out2b,
                             const unsigned short* __restrict__ residb,
                             const float* __restrict__ ss, float* __restrict__ out, int n) {
    int i = blockIdx.x * blockDim.x + threadIdx.x;  // over n*32 groups of 4 ch
    if (i >= n * 32) return;
    int c0 = (i & 31) * 4;
    uint2 v = ((const uint2*)out2b)[i];
    uint2 r = ((const uint2*)residb)[i];
    float2 v01 = bf2f2(v.x), v23 = bf2f2(v.y);
    float2 r01 = bf2f2(r.x), r23 = bf2f2(r.y);
    float4 o;
    o.x = fmaxf(v01.x * ss[c0 + 0] + ss[128 + c0 + 0], 0.f) + r01.x;
    o.y = fmaxf(v01.y * ss[c0 + 1] + ss[128 + c0 + 1], 0.f) + r01.y;
    o.z = fmaxf(v23.x * ss[c0 + 2] + ss[128 + c0 + 2], 0.f) + r23.x;
    o.w = fmaxf(v23.y * ss[c0 + 3] + ss[128 + c0 + 3], 0.f) + r23.y;
    ((float4*)out)[i] = o;
}

extern "C" void kernel_launch(void* const* d_in, const int* in_sizes, int n_in,
                              void* d_out, int out_size, void* d_ws, size_t ws_size,
                              hipStream_t stream) {
    const float* x     = (const float*)d_in[0];
    const int*   ei    = (const int*)d_in[1];
    const float* W1    = (const float*)d_in[2];
    const float* asrc1 = (const float*)d_in[3];
    const float* adst1 = (const float*)d_in[4];
    const float* b1    = (const float*)d_in[5];
    const float* W2    = (const float*)d_in[6];
    const float* asrc2 = (const float*)d_in[7];
    const float* adst2 = (const float*)d_in[8];
    const float* b2    = (const float*)d_in[9];
    const float* gamma = (const float*)d_in[10];
    const float* beta  = (const float*)d_in[11];
    const float* Wres  = (const float*)d_in[12];
    const float* bres  = (const float*)d_in[13];

    const int n = in_sizes[0] / 128;  // 50000
    const int E = in_sizes[1] / 2;    // 800000

    char* ws = (char*)d_ws;
    size_t off = 0;
    auto alloc = [&](size_t bytes) {
        void* p = ws + off;
        off = (off + bytes + 255) & ~(size_t)255;
        return p;
    };
    float* as1  = (float*)alloc((size_t)n * 3 * 4);
    float* ad1  = (float*)alloc((size_t)n * 3 * 4);
    float* as2  = (float*)alloc((size_t)n * 4);
    float* ad2  = (float*)alloc((size_t)n * 4);
    float* part = (float*)alloc(64 * 256 * 4);
    float* ss   = (float*)alloc(256 * 4);
    unsigned short* xb     = (unsigned short*)alloc((size_t)n * 128 * 2);
    unsigned short* h1b    = (unsigned short*)alloc((size_t)n * 96 * 2);
    unsigned short* h2b    = (unsigned short*)alloc((size_t)n * 128 * 2);
    unsigned short* out1b  = (unsigned short*)alloc((size_t)n * 96 * 2);
    unsigned short* out2b  = (unsigned short*)alloc((size_t)n * 128 * 2);
    unsigned short* residb = (unsigned short*)alloc((size_t)n * 128 * 2);
    unsigned short* w1p    = (unsigned short*)alloc(128 * 96 * 2);
    unsigned short* w2p    = (unsigned short*)alloc(96 * 128 * 2);
    unsigned short* wresp  = (unsigned short*)alloc(128 * 128 * 2);
    int* deg  = (int*)alloc((size_t)n * 4);
    int* offs = (int*)alloc((size_t)(n + 1) * 4);
    int* ctr  = (int*)alloc((size_t)(n + 1) * 4);
    int* bsum = (int*)alloc(256 * 4);
    int* csr  = (int*)alloc((size_t)E * 4);

    hipMemsetAsync(deg, 0, (size_t)n * 4, stream);
    hipMemsetAsync(part, 0, 64 * 256 * 4, stream);

    const int* srcIdx = ei;
    const int* dstIdx = ei + E;
    const int nb = (n + 255) / 256;

    // fused prep: x->bf16 + 3 weight packs
    const int nxb = (n * 32 + 255) / 256;
    prep_kernel<<<nxb + 160, 256, 0, stream>>>(x, xb, n * 32, W1, w1p, W2, w2p, Wres, wresp);

    // CSR
    hist_kernel<<<2048, 256, 0, stream>>>(dstIdx, E, deg);
    scan_part<<<nb, 256, 0, stream>>>(deg, offs, bsum, n);
    scan_bsum<<<1, 256, 0, stream>>>(bsum, nb);
    scan_add<<<nb, 256, 0, stream>>>(offs, ctr, bsum, n);
    scatter_kernel<<<2048, 256, 0, stream>>>(srcIdx, dstIdx, E, ctr, csr);

    const int mt = (n + 15) / 16;          // 3125 row tiles
    const int gblk = (mt + 3) / 4;

    mfma_gemm<128, 96, 3><<<gblk, 256, 0, stream>>>(xb, w1p, nullptr, nullptr, h1b,
                                                    asrc1, adst1, as1, ad1, n);
    mfma_gemm<128, 128, 0><<<gblk, 256, 0, stream>>>(xb, wresp, bres, nullptr, residb,
                                                     nullptr, nullptr, nullptr, nullptr, n);
    gat1_agg<<<(n + 3) / 4, 256, 0, stream>>>(h1b, as1, ad1, offs, csr, b1, out1b, n);
    mfma_gemm<96, 128, 1><<<gblk, 256, 0, stream>>>(out1b, w2p, nullptr, nullptr, h2b,
                                                    asrc2, adst2, as2, ad2, n);
    gat2_agg<<<(n + 3) / 4, 256, 0, stream>>>(h2b, as2, ad2, offs, csr, b2, out2b, part, n);
    bn_finalize<<<1, 128, 0, stream>>>(part, gamma, beta, ss, n);
    final_kernel<<<(n * 32 + 255) / 256, 256, 0, stream>>>(out2b, residb, ss, (float*)d_out, n);
}

// Round 8
// 234.786 us; speedup vs baseline: 2.6756x; 1.1181x over previous
//
#include <hip/hip_runtime.h>

#define NEG 0.2f
#define NEG_INF (-1e30f)

typedef __attribute__((ext_vector_type(8))) short bf16x8;
typedef __attribute__((ext_vector_type(4))) float f32x4;

__device__ __forceinline__ float leaky(float e) { return e > 0.f ? e : NEG * e; }

__device__ __forceinline__ unsigned short f2bf(float f) {
    unsigned int u = __float_as_uint(f);
    unsigned int r = u + 0x7fffu + ((u >> 16) & 1u);
    return (unsigned short)(r >> 16);
}
__device__ __forceinline__ float2 bf2f2(unsigned int u) {
    float2 r;
    r.x = __uint_as_float(u << 16);
    r.y = __uint_as_float(u & 0xffff0000u);
    return r;
}

// ---------------- fused prep: hist + x->bf16 + weight packing ----------------
__device__ __forceinline__ void pack_w(const float* __restrict__ W,
                                       unsigned short* __restrict__ Bp, int K, int N, int idx) {
    int i = idx & 7;
    int rest = idx >> 3;
    int lane = rest & 63;
    rest >>= 6;
    int KT = K / 32;
    int kt = rest % KT;
    int ct = rest / KT;
    int m = lane & 15, kb = lane >> 4;
    int k = kt * 32 + kb * 8 + i, col = ct * 16 + m;
    Bp[idx] = f2bf(W[(size_t)k * N + col]);
}

__global__ __launch_bounds__(256) void prep_kernel(const float* __restrict__ x,
                                                   unsigned short* __restrict__ xb, int n4,
                                                   const float* __restrict__ W1,
                                                   unsigned short* __restrict__ w1p,
                                                   const float* __restrict__ W2,
                                                   unsigned short* __restrict__ w2p,
                                                   const float* __restrict__ Wres,
                                                   unsigned short* __restrict__ wresp,
                                                   const int* __restrict__ dst, int E,
                                                   int* __restrict__ deg, int histBlks) {
    int b = blockIdx.x;
    if (b < histBlks) {
        for (int e = b * 256 + threadIdx.x; e < E; e += histBlks * 256)
            atomicAdd(&deg[dst[e]], 1);
        return;
    }
    b -= histBlks;
    int nxb = (n4 + 255) / 256;
    if (b < nxb) {
        int i = b * 256 + threadIdx.x;
        if (i < n4) {
            float4 v = ((const float4*)x)[i];
            ushort4 o;
            o.x = f2bf(v.x); o.y = f2bf(v.y); o.z = f2bf(v.z); o.w = f2bf(v.w);
            ((ushort4*)xb)[i] = o;
        }
        return;
    }
    b -= nxb;
    if (b < 48) { pack_w(W1, w1p, 128, 96, b * 256 + threadIdx.x); return; }
    b -= 48;
    if (b < 48) { pack_w(W2, w2p, 96, 128, b * 256 + threadIdx.x); return; }
    b -= 48;
    if (b < 64) { pack_w(Wres, wresp, 128, 128, b * 256 + threadIdx.x); }
}

// ---------------- scan chain ----------------
__global__ void scan_part(const int* __restrict__ deg, int* __restrict__ offs,
                          int* __restrict__ bsum, int n) {
    __shared__ int buf[256];
    int i = blockIdx.x * 256 + threadIdx.x;
    int v = (i < n) ? deg[i] : 0;
    buf[threadIdx.x] = v;
    __syncthreads();
    for (int s = 1; s < 256; s <<= 1) {
        int t = (threadIdx.x >= s) ? buf[threadIdx.x - s] : 0;
        __syncthreads();
        buf[threadIdx.x] += t;
        __syncthreads();
    }
    if (i < n) offs[i + 1] = buf[threadIdx.x];
    if (threadIdx.x == 255) bsum[blockIdx.x] = buf[255];
}

__global__ void scan_bsum(int* __restrict__ bsum, int nb) {
    __shared__ int buf[256];
    int v = (threadIdx.x < nb) ? bsum[threadIdx.x] : 0;
    buf[threadIdx.x] = v;
    __syncthreads();
    for (int s = 1; s < 256; s <<= 1) {
        int t = (threadIdx.x >= s) ? buf[threadIdx.x - s] : 0;
        __syncthreads();
        buf[threadIdx.x] += t;
        __syncthreads();
    }
    if (threadIdx.x < nb) bsum[threadIdx.x] = buf[threadIdx.x] - v;  // exclusive
}

__global__ void scan_add(int* __restrict__ offs, int* __restrict__ ctr,
                         const int* __restrict__ bsum, int n) {
    int i = blockIdx.x * 256 + threadIdx.x;
    if (i < n) {
        int v = offs[i + 1] + bsum[blockIdx.x];
        offs[i + 1] = v;
        if (i + 1 < n) ctr[i + 1] = v;
    }
    if (i == 0) { offs[0] = 0; ctr[0] = 0; }
}

// ---------------- MFMA GEMM body: one wave per 16-row tile, all col-tiles ----------------
template <int K, int N, int HEADS>
__device__ __forceinline__ void gemm_body(int w, const unsigned short* __restrict__ A,
                                          const unsigned short* __restrict__ Bp,
                                          const float* __restrict__ bias,
                                          unsigned short* __restrict__ outB,
                                          const float* __restrict__ asrc,
                                          const float* __restrict__ adst,
                                          float* __restrict__ a_s,
                                          float* __restrict__ a_d, int M) {
    constexpr int KT = K / 32, CT = N / 16;
    int row0 = w * 16;
    if (row0 >= M) return;
    int lane = threadIdx.x & 63;
    int m = lane & 15, kb = lane >> 4;
    const unsigned short* arow = A + (size_t)(row0 + m) * K + kb * 8;

    f32x4 acc[CT];
#pragma unroll
    for (int ct = 0; ct < CT; ++ct) acc[ct] = (f32x4){0.f, 0.f, 0.f, 0.f};

#pragma unroll
    for (int kt = 0; kt < KT; ++kt) {
        bf16x8 a = *(const bf16x8*)(arow + kt * 32);
#pragma unroll
        for (int ct = 0; ct < CT; ++ct) {
            bf16x8 b = *(const bf16x8*)(Bp + ((size_t)(ct * KT + kt) * 64 + lane) * 8);
            acc[ct] = __builtin_amdgcn_mfma_f32_16x16x32_bf16(a, b, acc[ct], 0, 0, 0);
        }
    }

#pragma unroll
    for (int r = 0; r < 4; ++r) {
        int row = row0 + kb * 4 + r;
#pragma unroll
        for (int ct = 0; ct < CT; ++ct) {
            int col = ct * 16 + m;
            float v = acc[ct][r] + (bias ? bias[col] : 0.f);
            outB[(size_t)row * N + col] = f2bf(v);
        }
    }

    if (HEADS > 0) {
        float asv[CT], adv[CT];
#pragma unroll
        for (int ct = 0; ct < CT; ++ct) {
            int col = ct * 16 + m;
            asv[ct] = asrc[col];
            adv[ct] = adst[col];
        }
        constexpr int TPH = CT / (HEADS > 0 ? HEADS : 1);
#pragma unroll
        for (int r = 0; r < 4; ++r) {
            int row = row0 + kb * 4 + r;
#pragma unroll
            for (int h = 0; h < HEADS; ++h) {
                float s = 0.f, d = 0.f;
#pragma unroll
                for (int t = 0; t < TPH; ++t) {
                    int ct = h * TPH + t;
                    s += acc[ct][r] * asv[ct];
                    d += acc[ct][r] * adv[ct];
                }
#pragma unroll
                for (int off = 1; off <= 8; off <<= 1) {
                    s += __shfl_xor(s, off);
                    d += __shfl_xor(d, off);
                }
                if (m == 0) {
                    a_s[(size_t)row * HEADS + h] = s;
                    a_d[(size_t)row * HEADS + h] = d;
                }
            }
        }
    }
}

// ---------------- phase2: scatter + gemm1 + gemm_res fused (independent, block-split) ----------------
__global__ __launch_bounds__(256) void phase2_kernel(
    const int* __restrict__ src, const int* __restrict__ dst, int E,
    int* __restrict__ ctr, int* __restrict__ csr,
    const unsigned short* __restrict__ xb,
    const unsigned short* __restrict__ w1p, unsigned short* __restrict__ h1b,
    const float* __restrict__ asrc1, const float* __restrict__ adst1,
    float* __restrict__ as1, float* __restrict__ ad1,
    const unsigned short* __restrict__ wresp, const float* __restrict__ bres,
    unsigned short* __restrict__ residb, int n, int scatBlks, int g1Blks) {
    int b = blockIdx.x;
    if (b < scatBlks) {
        for (int e = b * 256 + threadIdx.x; e < E; e += scatBlks * 256) {
            int p = atomicAdd(&ctr[dst[e]], 1);
            csr[p] = src[e];
        }
        return;
    }
    b -= scatBlks;
    if (b < g1Blks) {
        gemm_body<128, 96, 3>(b * 4 + (threadIdx.x >> 6), xb, w1p, nullptr, h1b,
                              asrc1, adst1, as1, ad1, n);
        return;
    }
    b -= g1Blks;
    gemm_body<128, 128, 0>(b * 4 + (threadIdx.x >> 6), xb, wresp, bres, residb,
                           nullptr, nullptr, nullptr, nullptr, n);
}

// gemm2 standalone wrapper
__global__ __launch_bounds__(256) void gemm2_kernel(const unsigned short* __restrict__ A,
                                                    const unsigned short* __restrict__ Bp,
                                                    unsigned short* __restrict__ outB,
                                                    const float* __restrict__ asrc,
                                                    const float* __restrict__ adst,
                                                    float* __restrict__ a_s,
                                                    float* __restrict__ a_d, int M) {
    gemm_body<96, 128, 1>(blockIdx.x * 4 + (threadIdx.x >> 6), A, Bp, nullptr, outB,
                          asrc, adst, a_s, a_d, M);
}

// ---------------- GAT aggregation: split LDS scratch, 4-wide gather ILP ----------------
__global__ __launch_bounds__(256) void gat1_agg(const unsigned short* __restrict__ h1b,
                                                const float* __restrict__ a_s,
                                                const float* __restrict__ a_d,
                                                const int* __restrict__ offs,
                                                const int* __restrict__ csr,
                                                const float* __restrict__ b1,
                                                unsigned short* __restrict__ out1b, int n) {
    __shared__ int ssrc[4][64];
    __shared__ float se[4][3][64];
    int wid = threadIdx.x >> 6;
    int node = blockIdx.x * 4 + wid;
    if (node >= n) return;
    int lane = threadIdx.x & 63;
    int head = lane >> 4; if (head > 2) head = 2;
    int beg = offs[node], end = offs[node + 1];
    int deg = end - beg;
    float ad0 = a_d[node * 3 + 0], ad1 = a_d[node * 3 + 1], ad2 = a_d[node * 3 + 2];
    float es0 = leaky(a_s[node * 3 + 0] + ad0);
    float es1 = leaky(a_s[node * 3 + 1] + ad1);
    float es2 = leaky(a_s[node * 3 + 2] + ad2);
    float2 hv0 = make_float2(0.f, 0.f);
    if (lane < 48) hv0 = bf2f2(*(const unsigned int*)&h1b[(size_t)node * 96 + 2 * lane]);

    float den;
    float2 acc;

    if (deg <= 64) {
        int s = 0;
        float l0 = NEG_INF, l1 = NEG_INF, l2 = NEG_INF;
        if (lane < deg) {
            s = csr[beg + lane];
            l0 = leaky(a_s[s * 3 + 0] + ad0);
            l1 = leaky(a_s[s * 3 + 1] + ad1);
            l2 = leaky(a_s[s * 3 + 2] + ad2);
        }
        float m0 = l0, m1 = l1, m2 = l2;
#pragma unroll
        for (int sh = 32; sh >= 1; sh >>= 1) {
            m0 = fmaxf(m0, __shfl_xor(m0, sh));
            m1 = fmaxf(m1, __shfl_xor(m1, sh));
            m2 = fmaxf(m2, __shfl_xor(m2, sh));
        }
        m0 = fmaxf(m0, es0); m1 = fmaxf(m1, es1); m2 = fmaxf(m2, es2);
        float e0 = 0.f, e1 = 0.f, e2 = 0.f;
        if (lane < deg) {
            e0 = __expf(l0 - m0); e1 = __expf(l1 - m1); e2 = __expf(l2 - m2);
        }
        ssrc[wid][lane] = s;
        se[wid][0][lane] = e0; se[wid][1][lane] = e1; se[wid][2][lane] = e2;
        float w0 = __expf(es0 - m0), w1 = __expf(es1 - m1), w2 = __expf(es2 - m2);
        den = (head == 0) ? w0 : ((head == 1) ? w1 : w2);
        float wSelf = (lane < 16) ? w0 : ((lane < 32) ? w1 : w2);
        acc.x = wSelf * hv0.x; acc.y = wSelf * hv0.y;

        int jj = 0;
        for (; jj + 3 < deg; jj += 4) {
            int sA = ssrc[wid][jj], sB = ssrc[wid][jj + 1];
            int sC = ssrc[wid][jj + 2], sD = ssrc[wid][jj + 3];
            float wA = se[wid][head][jj], wB = se[wid][head][jj + 1];
            float wC = se[wid][head][jj + 2], wD = se[wid][head][jj + 3];
            den += (wA + wB) + (wC + wD);
            if (lane < 48) {
                unsigned pa = *(const unsigned*)&h1b[(size_t)sA * 96 + 2 * lane];
                unsigned pb = *(const unsigned*)&h1b[(size_t)sB * 96 + 2 * lane];
                unsigned pc = *(const unsigned*)&h1b[(size_t)sC * 96 + 2 * lane];
                unsigned pd = *(const unsigned*)&h1b[(size_t)sD * 96 + 2 * lane];
                float2 ha = bf2f2(pa), hb = bf2f2(pb), hc = bf2f2(pc), hd = bf2f2(pd);
                acc.x += wA * ha.x + wB * hb.x + wC * hc.x + wD * hd.x;
                acc.y += wA * ha.y + wB * hb.y + wC * hc.y + wD * hd.y;
            }
        }
        for (; jj < deg; ++jj) {
            int sA = ssrc[wid][jj];
            float wA = se[wid][head][jj];
            den += wA;
            if (lane < 48) {
                float2 ha = bf2f2(*(const unsigned*)&h1b[(size_t)sA * 96 + 2 * lane]);
                acc.x += wA * ha.x; acc.y += wA * ha.y;
            }
        }
    } else {
        float m0 = es0, m1 = es1, m2 = es2;
        for (int j = beg + lane; j < end; j += 64) {
            int s = csr[j];
            m0 = fmaxf(m0, leaky(a_s[s * 3 + 0] + ad0));
            m1 = fmaxf(m1, leaky(a_s[s * 3 + 1] + ad1));
            m2 = fmaxf(m2, leaky(a_s[s * 3 + 2] + ad2));
        }
#pragma unroll
        for (int sh = 32; sh >= 1; sh >>= 1) {
            m0 = fmaxf(m0, __shfl_xor(m0, sh));
            m1 = fmaxf(m1, __shfl_xor(m1, sh));
            m2 = fmaxf(m2, __shfl_xor(m2, sh));
        }
        float w0 = __expf(es0 - m0), w1 = __expf(es1 - m1), w2 = __expf(es2 - m2);
        den = (head == 0) ? w0 : ((head == 1) ? w1 : w2);
        float wSelf = (lane < 16) ? w0 : ((lane < 32) ? w1 : w2);
        acc.x = wSelf * hv0.x; acc.y = wSelf * hv0.y;
        for (int t0 = beg; t0 < end; t0 += 64) {
            int cnt = min(64, end - t0);
            int s = 0;
            float e0 = 0.f, e1 = 0.f, e2 = 0.f;
            if (lane < cnt) {
                s = csr[t0 + lane];
                e0 = __expf(leaky(a_s[s * 3 + 0] + ad0) - m0);
                e1 = __expf(leaky(a_s[s * 3 + 1] + ad1) - m1);
                e2 = __expf(leaky(a_s[s * 3 + 2] + ad2) - m2);
            }
            ssrc[wid][lane] = s;
            se[wid][0][lane] = e0; se[wid][1][lane] = e1; se[wid][2][lane] = e2;
            int jj = 0;
            for (; jj + 3 < cnt; jj += 4) {
                int sA = ssrc[wid][jj], sB = ssrc[wid][jj + 1];
                int sC = ssrc[wid][jj + 2], sD = ssrc[wid][jj + 3];
                float wA = se[wid][head][jj], wB = se[wid][head][jj + 1];
                float wC = se[wid][head][jj + 2], wD = se[wid][head][jj + 3];
                den += (wA + wB) + (wC + wD);
                if (lane < 48) {
                    unsigned pa = *(const unsigned*)&h1b[(size_t)sA * 96 + 2 * lane];
                    unsigned pb = *(const unsigned*)&h1b[(size_t)sB * 96 + 2 * lane];
                    unsigned pc = *(const unsigned*)&h1b[(size_t)sC * 96 + 2 * lane];
                    unsigned pd = *(const unsigned*)&h1b[(size_t)sD * 96 + 2 * lane];
                    float2 ha = bf2f2(pa), hb = bf2f2(pb), hc = bf2f2(pc), hd = bf2f2(pd);
                    acc.x += wA * ha.x + wB * hb.x + wC * hc.x + wD * hd.x;
                    acc.y += wA * ha.y + wB * hb.y + wC * hc.y + wD * hd.y;
                }
            }
            for (; jj < cnt; ++jj) {
                int sA = ssrc[wid][jj];
                float wA = se[wid][head][jj];
                den += wA;
                if (lane < 48) {
                    float2 ha = bf2f2(*(const unsigned*)&h1b[(size_t)sA * 96 + 2 * lane]);
                    acc.x += wA * ha.x; acc.y += wA * ha.y;
                }
            }
        }
    }

    if (lane < 48) {
        float inv = 1.f / (den + 1e-16f);
        ushort2 o;
        o.x = f2bf(acc.x * inv + b1[2 * lane]);
        o.y = f2bf(acc.y * inv + b1[2 * lane + 1]);
        *(ushort2*)&out1b[(size_t)node * 96 + 2 * lane] = o;
    }
}

// gat2: 128 ch, 1 head; writes bf16 out2 AND accumulates BN partial sums.
__global__ __launch_bounds__(256) void gat2_agg(const unsigned short* __restrict__ h2b,
                                                const float* __restrict__ a_s,
                                                const float* __restrict__ a_d,
                                                const int* __restrict__ offs,
                                                const int* __restrict__ csr,
                                                const float* __restrict__ b2,
                                                unsigned short* __restrict__ out2b,
                                                float* __restrict__ part, int n) {
    __shared__ int ssrc[4][64];
    __shared__ float se[4][64];
    __shared__ float4 red[4][64];
    int wid = threadIdx.x >> 6;
    int node = blockIdx.x * 4 + wid;
    int lane = threadIdx.x & 63;
    float2 o = make_float2(0.f, 0.f);

    if (node < n) {
        int beg = offs[node], end = offs[node + 1];
        int deg = end - beg;
        float ad = a_d[node];
        float es = leaky(a_s[node] + ad);
        float2 hv0 = bf2f2(*(const unsigned int*)&h2b[(size_t)node * 128 + 2 * lane]);
        float den;
        float2 acc;

        if (deg <= 64) {
            int s = 0;
            float l = NEG_INF;
            if (lane < deg) {
                s = csr[beg + lane];
                l = leaky(a_s[s] + ad);
            }
            float m = l;
#pragma unroll
            for (int sh = 32; sh >= 1; sh >>= 1) m = fmaxf(m, __shfl_xor(m, sh));
            m = fmaxf(m, es);
            float e = (lane < deg) ? __expf(l - m) : 0.f;
            ssrc[wid][lane] = s;
            se[wid][lane] = e;
            float wSelf = __expf(es - m);
            den = wSelf;
            acc.x = wSelf * hv0.x; acc.y = wSelf * hv0.y;

            int jj = 0;
            for (; jj + 3 < deg; jj += 4) {
                int sA = ssrc[wid][jj], sB = ssrc[wid][jj + 1];
                int sC = ssrc[wid][jj + 2], sD = ssrc[wid][jj + 3];
                float wA = se[wid][jj], wB = se[wid][jj + 1];
                float wC = se[wid][jj + 2], wD = se[wid][jj + 3];
                den += (wA + wB) + (wC + wD);
                unsigned pa = *(const unsigned*)&h2b[(size_t)sA * 128 + 2 * lane];
                unsigned pb = *(const unsigned*)&h2b[(size_t)sB * 128 + 2 * lane];
                unsigned pc = *(const unsigned*)&h2b[(size_t)sC * 128 + 2 * lane];
                unsigned pd = *(const unsigned*)&h2b[(size_t)sD * 128 + 2 * lane];
                float2 ha = bf2f2(pa), hb = bf2f2(pb), hc = bf2f2(pc), hd = bf2f2(pd);
                acc.x += wA * ha.x + wB * hb.x + wC * hc.x + wD * hd.x;
                acc.y += wA * ha.y + wB * hb.y + wC * hc.y + wD * hd.y;
            }
            for (; jj < deg; ++jj) {
                int sA = ssrc[wid][jj];
                float wA = se[wid][jj];
                den += wA;
                float2 ha = bf2f2(*(const unsigned*)&h2b[(size_t)sA * 128 + 2 * lane]);
                acc.x += wA * ha.x; acc.y += wA * ha.y;
            }
        } else {
            float m = es;
            for (int j = beg + lane; j < end; j += 64) {
                int s = csr[j];
                m = fmaxf(m, leaky(a_s[s] + ad));
            }
#pragma unroll
            for (int sh = 32; sh >= 1; sh >>= 1) m = fmaxf(m, __shfl_xor(m, sh));
            float wSelf = __expf(es - m);
            den = wSelf;
            acc.x = wSelf * hv0.x; acc.y = wSelf * hv0.y;
            for (int t0 = beg; t0 < end; t0 += 64) {
                int cnt = min(64, end - t0);
                int s = 0;
                float e = 0.f;
                if (lane < cnt) {
                    s = csr[t0 + lane];
                    e = __expf(leaky(a_s[s] + ad) - m);
                }
                ssrc[wid][lane] = s;
                se[wid][lane] = e;
                int jj = 0;
                for (; jj + 3 < cnt; jj += 4) {
                    int sA = ssrc[wid][jj], sB = ssrc[wid][jj + 1];
                    int sC = ssrc[wid][jj + 2], sD = ssrc[wid][jj + 3];
                    float wA = se[wid][jj], wB = se[wid][jj + 1];
                    float wC = se[wid][jj + 2], wD = se[wid][jj + 3];
                    den += (wA + wB) + (wC + wD);
                    unsigned pa = *(const unsigned*)&h2b[(size_t)sA * 128 + 2 * lane];
                    unsigned pb = *(const unsigned*)&h2b[(size_t)sB * 128 + 2 * lane];
                    unsigned pc = *(const unsigned*)&h2b[(size_t)sC * 128 + 2 * lane];
                    unsigned pd = *(const unsigned*)&h2b[(size_t)sD * 128 + 2 * lane];
                    float2 ha = bf2f2(pa), hb = bf2f2(pb), hc = bf2f2(pc), hd = bf2f2(pd);
                    acc.x += wA * ha.x + wB * hb.x + wC * hc.x + wD * hd.x;
                    acc.y += wA * ha.y + wB * hb.y + wC * hc.y + wD * hd.y;
                }
                for (; jj < cnt; ++jj) {
                    int sA = ssrc[wid][jj];
                    float wA = se[wid][jj];
                    den += wA;
                    float2 ha = bf2f2(*(const unsigned*)&h2b[(size_t)sA * 128 + 2 * lane]);
                    acc.x += wA * ha.x; acc.y += wA * ha.y;
                }
            }
        }

        float inv = 1.f / (den + 1e-16f);
        o.x = acc.x * inv + b2[2 * lane];
        o.y = acc.y * inv + b2[2 * lane + 1];
        ushort2 ob;
        ob.x = f2bf(o.x); ob.y = f2bf(o.y);
        *(ushort2*)&out2b[(size_t)node * 128 + 2 * lane] = ob;
    }

    // ---- block-level BN partial reduction ----
    red[wid][lane] = make_float4(o.x, o.y, o.x * o.x, o.y * o.y);
    __syncthreads();
    if (wid == 0) {
        float4 a = red[0][lane], b = red[1][lane], c = red[2][lane], d = red[3][lane];
        float sx = a.x + b.x + c.x + d.x;
        float sy = a.y + b.y + c.y + d.y;
        float qx = a.z + b.z + c.z + d.z;
        float qy = a.w + b.w + c.w + d.w;
        float* p = part + (size_t)(blockIdx.x & 63) * 256;
        atomicAdd(&p[2 * lane + 0], sx);
        atomicAdd(&p[2 * lane + 1], sy);
        atomicAdd(&p[128 + 2 * lane + 0], qx);
        atomicAdd(&p[128 + 2 * lane + 1], qy);
    }
}

// ---------------- BN finalize ----------------
__global__ void bn_finalize(const float* __restrict__ part, const float* __restrict__ gamma,
                            const float* __restrict__ beta, float* __restrict__ ss, int n) {
    int c = threadIdx.x;  // 128
    float S = 0.f, Q = 0.f;
    for (int k = 0; k < 64; ++k) {
        S += part[(size_t)k * 256 + c];
        Q += part[(size_t)k * 256 + 128 + c];
    }
    float invN = 1.f / (float)n;
    float mu = S * invN;
    float var = Q * invN - mu * mu;
    float g = gamma[c] * rsqrtf(var + 1e-5f);
    ss[c] = g;
    ss[128 + c] = beta[c] - mu * g;
}

// ---------------- fused BN-normalize + ReLU + residual ----------------
__global__ void final_kernel(const unsigned short* __restrict__ out2b,
                             const unsigned short* __restrict__ residb,
                             const float* __restrict__ ss, float* __restrict__ out, int n) {
    int i = blockIdx.x * blockDim.x + threadIdx.x;  // over n*32 groups of 4 ch
    if (i >= n * 32) return;
    int c0 = (i & 31) * 4;
    uint2 v = ((const uint2*)out2b)[i];
    uint2 r = ((const uint2*)residb)[i];
    float2 v01 = bf2f2(v.x), v23 = bf2f2(v.y);
    float2 r01 = bf2f2(r.x), r23 = bf2f2(r.y);
    float4 o;
    o.x = fmaxf(v01.x * ss[c0 + 0] + ss[128 + c0 + 0], 0.f) + r01.x;
    o.y = fmaxf(v01.y * ss[c0 + 1] + ss[128 + c0 + 1], 0.f) + r01.y;
    o.z = fmaxf(v23.x * ss[c0 + 2] + ss[128 + c0 + 2], 0.f) + r23.x;
    o.w = fmaxf(v23.y * ss[c0 + 3] + ss[128 + c0 + 3], 0.f) + r23.y;
    ((float4*)out)[i] = o;
}

extern "C" void kernel_launch(void* const* d_in, const int* in_sizes, int n_in,
                              void* d_out, int out_size, void* d_ws, size_t ws_size,
                              hipStream_t stream) {
    const float* x     = (const float*)d_in[0];
    const int*   ei    = (const int*)d_in[1];
    const float* W1    = (const float*)d_in[2];
    const float* asrc1 = (const float*)d_in[3];
    const float* adst1 = (const float*)d_in[4];
    const float* b1    = (const float*)d_in[5];
    const float* W2    = (const float*)d_in[6];
    const float* asrc2 = (const float*)d_in[7];
    const float* adst2 = (const float*)d_in[8];
    const float* b2    = (const float*)d_in[9];
    const float* gamma = (const float*)d_in[10];
    const float* beta  = (const float*)d_in[11];
    const float* Wres  = (const float*)d_in[12];
    const float* bres  = (const float*)d_in[13];

    const int n = in_sizes[0] / 128;  // 50000
    const int E = in_sizes[1] / 2;    // 800000

    char* ws = (char*)d_ws;
    size_t off = 0;
    auto alloc = [&](size_t bytes) {
        void* p = ws + off;
        off = (off + bytes + 255) & ~(size_t)255;
        return p;
    };
    float* as1  = (float*)alloc((size_t)n * 3 * 4);
    float* ad1  = (float*)alloc((size_t)n * 3 * 4);
    float* as2  = (float*)alloc((size_t)n * 4);
    float* ad2  = (float*)alloc((size_t)n * 4);
    float* part = (float*)alloc(64 * 256 * 4);
    float* ss   = (float*)alloc(256 * 4);
    unsigned short* xb     = (unsigned short*)alloc((size_t)n * 128 * 2);
    unsigned short* h1b    = (unsigned short*)alloc((size_t)n * 96 * 2);
    unsigned short* h2b    = (unsigned short*)alloc((size_t)n * 128 * 2);
    unsigned short* out1b  = (unsigned short*)alloc((size_t)n * 96 * 2);
    unsigned short* out2b  = (unsigned short*)alloc((size_t)n * 128 * 2);
    unsigned short* residb = (unsigned short*)alloc((size_t)n * 128 * 2);
    unsigned short* w1p    = (unsigned short*)alloc(128 * 96 * 2);
    unsigned short* w2p    = (unsigned short*)alloc(96 * 128 * 2);
    unsigned short* wresp  = (unsigned short*)alloc(128 * 128 * 2);
    int* deg  = (int*)alloc((size_t)n * 4);
    int* offs = (int*)alloc((size_t)(n + 1) * 4);
    int* ctr  = (int*)alloc((size_t)(n + 1) * 4);
    int* bsum = (int*)alloc(256 * 4);
    int* csr  = (int*)alloc((size_t)E * 4);

    hipMemsetAsync(deg, 0, (size_t)n * 4, stream);
    hipMemsetAsync(part, 0, 64 * 256 * 4, stream);

    const int* srcIdx = ei;
    const int* dstIdx = ei + E;
    const int nb = (n + 255) / 256;

    // fused prep: hist + x->bf16 + 3 weight packs
    const int histBlks = 512;
    const int nxb = (n * 32 + 255) / 256;
    prep_kernel<<<histBlks + nxb + 160, 256, 0, stream>>>(x, xb, n * 32, W1, w1p, W2, w2p,
                                                          Wres, wresp, dstIdx, E, deg, histBlks);

    scan_part<<<nb, 256, 0, stream>>>(deg, offs, bsum, n);
    scan_bsum<<<1, 256, 0, stream>>>(bsum, nb);
    scan_add<<<nb, 256, 0, stream>>>(offs, ctr, bsum, n);

    const int mt = (n + 15) / 16;   // 3125 row tiles
    const int gblk = (mt + 3) / 4;  // 782
    const int scatBlks = 1024;

    // phase2: scatter + gemm1(+att1) + gemm_res, fused for overlap
    phase2_kernel<<<scatBlks + 2 * gblk, 256, 0, stream>>>(
        srcIdx, dstIdx, E, ctr, csr, xb, w1p, h1b, asrc1, adst1, as1, ad1,
        wresp, bres, residb, n, scatBlks, gblk);

    gat1_agg<<<(n + 3) / 4, 256, 0, stream>>>(h1b, as1, ad1, offs, csr, b1, out1b, n);
    gemm2_kernel<<<gblk, 256, 0, stream>>>(out1b, w2p, h2b, asrc2, adst2, as2, ad2, n);
    gat2_agg<<<(n + 3) / 4, 256, 0, stream>>>(h2b, as2, ad2, offs, csr, b2, out2b, part, n);
    bn_finalize<<<1, 128, 0, stream>>>(part, gamma, beta, ss, n);
    final_kernel<<<(n * 32 + 255) / 256, 256, 0, stream>>>(out2b, residb, ss, (float*)d_out, n);
}

// Round 9
// 219.356 us; speedup vs baseline: 2.8638x; 1.0703x over previous
//
#include <hip/hip_runtime.h>

#define NEG 0.2f
#define NEG_INF (-1e30f)

typedef __attribute__((ext_vector_type(8))) short bf16x8;
typedef __attribute__((ext_vector_type(4))) float f32x4;

__device__ __forceinline__ float leaky(float e) { return e > 0.f ? e : NEG * e; }

__device__ __forceinline__ unsigned short f2bf(float f) {
    unsigned int u = __float_as_uint(f);
    unsigned int r = u + 0x7fffu + ((u >> 16) & 1u);
    return (unsigned short)(r >> 16);
}
__device__ __forceinline__ float2 bf2f2(unsigned int u) {
    float2 r;
    r.x = __uint_as_float(u << 16);
    r.y = __uint_as_float(u & 0xffff0000u);
    return r;
}

// ---------------- fused prep: hist + x->bf16 + weight packing ----------------
__device__ __forceinline__ void pack_w(const float* __restrict__ W,
                                       unsigned short* __restrict__ Bp, int K, int N, int idx) {
    int i = idx & 7;
    int rest = idx >> 3;
    int lane = rest & 63;
    rest >>= 6;
    int KT = K / 32;
    int kt = rest % KT;
    int ct = rest / KT;
    int m = lane & 15, kb = lane >> 4;
    int k = kt * 32 + kb * 8 + i, col = ct * 16 + m;
    Bp[idx] = f2bf(W[(size_t)k * N + col]);
}

__global__ __launch_bounds__(256) void prep_kernel(const float* __restrict__ x,
                                                   unsigned short* __restrict__ xb, int n4,
                                                   const float* __restrict__ W1,
                                                   unsigned short* __restrict__ w1p,
                                                   const float* __restrict__ W2,
                                                   unsigned short* __restrict__ w2p,
                                                   const float* __restrict__ Wres,
                                                   unsigned short* __restrict__ wresp,
                                                   const int* __restrict__ dst, int E,
                                                   int* __restrict__ deg, int histBlks) {
    int b = blockIdx.x;
    if (b < histBlks) {
        for (int e = b * 256 + threadIdx.x; e < E; e += histBlks * 256)
            atomicAdd(&deg[dst[e]], 1);
        return;
    }
    b -= histBlks;
    int nxb = (n4 + 255) / 256;
    if (b < nxb) {
        int i = b * 256 + threadIdx.x;
        if (i < n4) {
            float4 v = ((const float4*)x)[i];
            ushort4 o;
            o.x = f2bf(v.x); o.y = f2bf(v.y); o.z = f2bf(v.z); o.w = f2bf(v.w);
            ((ushort4*)xb)[i] = o;
        }
        return;
    }
    b -= nxb;
    if (b < 48) { pack_w(W1, w1p, 128, 96, b * 256 + threadIdx.x); return; }
    b -= 48;
    if (b < 48) { pack_w(W2, w2p, 96, 128, b * 256 + threadIdx.x); return; }
    b -= 48;
    if (b < 64) { pack_w(Wres, wresp, 128, 128, b * 256 + threadIdx.x); }
}

// ---------------- scan chain ----------------
__global__ void scan_part(const int* __restrict__ deg, int* __restrict__ offs,
                          int* __restrict__ bsum, int n) {
    __shared__ int buf[256];
    int i = blockIdx.x * 256 + threadIdx.x;
    int v = (i < n) ? deg[i] : 0;
    buf[threadIdx.x] = v;
    __syncthreads();
    for (int s = 1; s < 256; s <<= 1) {
        int t = (threadIdx.x >= s) ? buf[threadIdx.x - s] : 0;
        __syncthreads();
        buf[threadIdx.x] += t;
        __syncthreads();
    }
    if (i < n) offs[i + 1] = buf[threadIdx.x];
    if (threadIdx.x == 255) bsum[blockIdx.x] = buf[255];
}

__global__ void scan_bsum(int* __restrict__ bsum, int nb) {
    __shared__ int buf[256];
    int v = (threadIdx.x < nb) ? bsum[threadIdx.x] : 0;
    buf[threadIdx.x] = v;
    __syncthreads();
    for (int s = 1; s < 256; s <<= 1) {
        int t = (threadIdx.x >= s) ? buf[threadIdx.x - s] : 0;
        __syncthreads();
        buf[threadIdx.x] += t;
        __syncthreads();
    }
    if (threadIdx.x < nb) bsum[threadIdx.x] = buf[threadIdx.x] - v;  // exclusive
}

// also seeds per-node ctr and per-bucket (32-node) pairBase/bcur
__global__ void scan_add(int* __restrict__ offs, int* __restrict__ ctr,
                         const int* __restrict__ bsum, int n,
                         int* __restrict__ pairBase, int* __restrict__ bcur) {
    int i = blockIdx.x * 256 + threadIdx.x;
    if (i < n) {
        int v = offs[i + 1] + bsum[blockIdx.x];
        offs[i + 1] = v;
        if (i + 1 < n) ctr[i + 1] = v;
        if (((i + 1) & 31) == 0) {
            int b = (i + 1) >> 5;
            pairBase[b] = v;
            bcur[b] = v;
        }
    }
    if (i == 0) { offs[0] = 0; ctr[0] = 0; pairBase[0] = 0; bcur[0] = 0; }
}

// ---------------- binned edge pass A: LDS-staged bucket append ----------------
__global__ __launch_bounds__(256) void bin_kernel(const int* __restrict__ src,
                                                  const int* __restrict__ dst, int E,
                                                  int* __restrict__ bcur,
                                                  int2* __restrict__ pairBuf, int nb) {
    __shared__ int2 stage[4096];
    __shared__ int hist[1600];
    __shared__ int base[1600];
    for (int c0 = blockIdx.x * 4096; c0 < E; c0 += gridDim.x * 4096) {
        int cnt = min(4096, E - c0);
        for (int b = threadIdx.x; b < nb; b += 256) hist[b] = 0;
        __syncthreads();
        for (int i = threadIdx.x; i < cnt; i += 256) {
            int s = src[c0 + i], d = dst[c0 + i];
            stage[i] = make_int2(s, d);
            atomicAdd(&hist[d >> 5], 1);
        }
        __syncthreads();
        for (int b = threadIdx.x; b < nb; b += 256) {
            int h = hist[b];
            if (h) base[b] = atomicAdd(&bcur[b], h);
            hist[b] = 0;
        }
        __syncthreads();
        for (int i = threadIdx.x; i < cnt; i += 256) {
            int2 p = stage[i];
            int b = p.y >> 5;
            int off = atomicAdd(&hist[b], 1);
            pairBuf[base[b] + off] = p;
        }
        __syncthreads();
    }
}

// ---------------- MFMA GEMM body: one wave per 16-row tile, all col-tiles ----------------
template <int K, int N, int HEADS>
__device__ __forceinline__ void gemm_body(int w, const unsigned short* __restrict__ A,
                                          const unsigned short* __restrict__ Bp,
                                          const float* __restrict__ bias,
                                          unsigned short* __restrict__ outB,
                                          const float* __restrict__ asrc,
                                          const float* __restrict__ adst,
                                          float* __restrict__ a_s,
                                          float* __restrict__ a_d, int M) {
    constexpr int KT = K / 32, CT = N / 16;
    int row0 = w * 16;
    if (row0 >= M) return;
    int lane = threadIdx.x & 63;
    int m = lane & 15, kb = lane >> 4;
    const unsigned short* arow = A + (size_t)(row0 + m) * K + kb * 8;

    f32x4 acc[CT];
#pragma unroll
    for (int ct = 0; ct < CT; ++ct) acc[ct] = (f32x4){0.f, 0.f, 0.f, 0.f};

#pragma unroll
    for (int kt = 0; kt < KT; ++kt) {
        bf16x8 a = *(const bf16x8*)(arow + kt * 32);
#pragma unroll
        for (int ct = 0; ct < CT; ++ct) {
            bf16x8 b = *(const bf16x8*)(Bp + ((size_t)(ct * KT + kt) * 64 + lane) * 8);
            acc[ct] = __builtin_amdgcn_mfma_f32_16x16x32_bf16(a, b, acc[ct], 0, 0, 0);
        }
    }

#pragma unroll
    for (int r = 0; r < 4; ++r) {
        int row = row0 + kb * 4 + r;
#pragma unroll
        for (int ct = 0; ct < CT; ++ct) {
            int col = ct * 16 + m;
            float v = acc[ct][r] + (bias ? bias[col] : 0.f);
            outB[(size_t)row * N + col] = f2bf(v);
        }
    }

    if (HEADS > 0) {
        float asv[CT], adv[CT];
#pragma unroll
        for (int ct = 0; ct < CT; ++ct) {
            int col = ct * 16 + m;
            asv[ct] = asrc[col];
            adv[ct] = adst[col];
        }
        constexpr int TPH = CT / (HEADS > 0 ? HEADS : 1);
#pragma unroll
        for (int r = 0; r < 4; ++r) {
            int row = row0 + kb * 4 + r;
#pragma unroll
            for (int h = 0; h < HEADS; ++h) {
                float s = 0.f, d = 0.f;
#pragma unroll
                for (int t = 0; t < TPH; ++t) {
                    int ct = h * TPH + t;
                    s += acc[ct][r] * asv[ct];
                    d += acc[ct][r] * adv[ct];
                }
#pragma unroll
                for (int off = 1; off <= 8; off <<= 1) {
                    s += __shfl_xor(s, off);
                    d += __shfl_xor(d, off);
                }
                if (m == 0) {
                    a_s[(size_t)row * HEADS + h] = s;
                    a_d[(size_t)row * HEADS + h] = d;
                }
            }
        }
    }
}

// ---------------- phase2: passB (bucket scatter) + gemm1 + gemm_res fused ----------------
__global__ __launch_bounds__(256) void phase2_kernel(
    const int2* __restrict__ pairBuf, const int* __restrict__ pairBase,
    const int* __restrict__ bcur, int* __restrict__ ctr, int* __restrict__ csr, int nb,
    const unsigned short* __restrict__ xb,
    const unsigned short* __restrict__ w1p, unsigned short* __restrict__ h1b,
    const float* __restrict__ asrc1, const float* __restrict__ adst1,
    float* __restrict__ as1, float* __restrict__ ad1,
    const unsigned short* __restrict__ wresp, const float* __restrict__ bres,
    unsigned short* __restrict__ residb, int n, int passBlks, int g1Blks) {
    int b = blockIdx.x;
    int lane = threadIdx.x & 63;
    if (b < passBlks) {
        int wgid = b * 4 + (threadIdx.x >> 6);
        for (int bk = wgid; bk < nb; bk += passBlks * 4) {
            int lo = pairBase[bk], hi = bcur[bk];
            for (int i = lo + lane; i < hi; i += 64) {
                int2 p = pairBuf[i];
                int pos = atomicAdd(&ctr[p.y], 1);
                csr[pos] = p.x;
            }
        }
        return;
    }
    b -= passBlks;
    if (b < g1Blks) {
        gemm_body<128, 96, 3>(b * 4 + (threadIdx.x >> 6), xb, w1p, nullptr, h1b,
                              asrc1, adst1, as1, ad1, n);
        return;
    }
    b -= g1Blks;
    gemm_body<128, 128, 0>(b * 4 + (threadIdx.x >> 6), xb, wresp, bres, residb,
                           nullptr, nullptr, nullptr, nullptr, n);
}

// gemm2 standalone wrapper
__global__ __launch_bounds__(256) void gemm2_kernel(const unsigned short* __restrict__ A,
                                                    const unsigned short* __restrict__ Bp,
                                                    unsigned short* __restrict__ outB,
                                                    const float* __restrict__ asrc,
                                                    const float* __restrict__ adst,
                                                    float* __restrict__ a_s,
                                                    float* __restrict__ a_d, int M) {
    gemm_body<96, 128, 1>(blockIdx.x * 4 + (threadIdx.x >> 6), A, Bp, nullptr, outB,
                          asrc, adst, a_s, a_d, M);
}

// ---------------- GAT aggregation: split LDS scratch, 4-wide gather ILP ----------------
__global__ __launch_bounds__(256) void gat1_agg(const unsigned short* __restrict__ h1b,
                                                const float* __restrict__ a_s,
                                                const float* __restrict__ a_d,
                                                const int* __restrict__ offs,
                                                const int* __restrict__ csr,
                                                const float* __restrict__ b1,
                                                unsigned short* __restrict__ out1b, int n) {
    __shared__ int ssrc[4][64];
    __shared__ float se[4][3][64];
    int wid = threadIdx.x >> 6;
    int node = blockIdx.x * 4 + wid;
    if (node >= n) return;
    int lane = threadIdx.x & 63;
    int head = lane >> 4; if (head > 2) head = 2;
    int beg = offs[node], end = offs[node + 1];
    int deg = end - beg;
    float ad0 = a_d[node * 3 + 0], ad1 = a_d[node * 3 + 1], ad2 = a_d[node * 3 + 2];
    float es0 = leaky(a_s[node * 3 + 0] + ad0);
    float es1 = leaky(a_s[node * 3 + 1] + ad1);
    float es2 = leaky(a_s[node * 3 + 2] + ad2);
    float2 hv0 = make_float2(0.f, 0.f);
    if (lane < 48) hv0 = bf2f2(*(const unsigned int*)&h1b[(size_t)node * 96 + 2 * lane]);

    float den;
    float2 acc;

    if (deg <= 64) {
        int s = 0;
        float l0 = NEG_INF, l1 = NEG_INF, l2 = NEG_INF;
        if (lane < deg) {
            s = csr[beg + lane];
            l0 = leaky(a_s[s * 3 + 0] + ad0);
            l1 = leaky(a_s[s * 3 + 1] + ad1);
            l2 = leaky(a_s[s * 3 + 2] + ad2);
        }
        float m0 = l0, m1 = l1, m2 = l2;
#pragma unroll
        for (int sh = 32; sh >= 1; sh >>= 1) {
            m0 = fmaxf(m0, __shfl_xor(m0, sh));
            m1 = fmaxf(m1, __shfl_xor(m1, sh));
            m2 = fmaxf(m2, __shfl_xor(m2, sh));
        }
        m0 = fmaxf(m0, es0); m1 = fmaxf(m1, es1); m2 = fmaxf(m2, es2);
        float e0 = 0.f, e1 = 0.f, e2 = 0.f;
        if (lane < deg) {
            e0 = __expf(l0 - m0); e1 = __expf(l1 - m1); e2 = __expf(l2 - m2);
        }
        ssrc[wid][lane] = s;
        se[wid][0][lane] = e0; se[wid][1][lane] = e1; se[wid][2][lane] = e2;
        float w0 = __expf(es0 - m0), w1 = __expf(es1 - m1), w2 = __expf(es2 - m2);
        den = (head == 0) ? w0 : ((head == 1) ? w1 : w2);
        float wSelf = (lane < 16) ? w0 : ((lane < 32) ? w1 : w2);
        acc.x = wSelf * hv0.x; acc.y = wSelf * hv0.y;

        int jj = 0;
        for (; jj + 3 < deg; jj += 4) {
            int sA = ssrc[wid][jj], sB = ssrc[wid][jj + 1];
            int sC = ssrc[wid][jj + 2], sD = ssrc[wid][jj + 3];
            float wA = se[wid][head][jj], wB = se[wid][head][jj + 1];
            float wC = se[wid][head][jj + 2], wD = se[wid][head][jj + 3];
            den += (wA + wB) + (wC + wD);
            if (lane < 48) {
                unsigned pa = *(const unsigned*)&h1b[(size_t)sA * 96 + 2 * lane];
                unsigned pb = *(const unsigned*)&h1b[(size_t)sB * 96 + 2 * lane];
                unsigned pc = *(const unsigned*)&h1b[(size_t)sC * 96 + 2 * lane];
                unsigned pd = *(const unsigned*)&h1b[(size_t)sD * 96 + 2 * lane];
                float2 ha = bf2f2(pa), hb = bf2f2(pb), hc = bf2f2(pc), hd = bf2f2(pd);
                acc.x += wA * ha.x + wB * hb.x + wC * hc.x + wD * hd.x;
                acc.y += wA * ha.y + wB * hb.y + wC * hc.y + wD * hd.y;
            }
        }
        for (; jj < deg; ++jj) {
            int sA = ssrc[wid][jj];
            float wA = se[wid][head][jj];
            den += wA;
            if (lane < 48) {
                float2 ha = bf2f2(*(const unsigned*)&h1b[(size_t)sA * 96 + 2 * lane]);
                acc.x += wA * ha.x; acc.y += wA * ha.y;
            }
        }
    } else {
        float m0 = es0, m1 = es1, m2 = es2;
        for (int j = beg + lane; j < end; j += 64) {
            int s = csr[j];
            m0 = fmaxf(m0, leaky(a_s[s * 3 + 0] + ad0));
            m1 = fmaxf(m1, leaky(a_s[s * 3 + 1] + ad1));
            m2 = fmaxf(m2, leaky(a_s[s * 3 + 2] + ad2));
        }
#pragma unroll
        for (int sh = 32; sh >= 1; sh >>= 1) {
            m0 = fmaxf(m0, __shfl_xor(m0, sh));
            m1 = fmaxf(m1, __shfl_xor(m1, sh));
            m2 = fmaxf(m2, __shfl_xor(m2, sh));
        }
        float w0 = __expf(es0 - m0), w1 = __expf(es1 - m1), w2 = __expf(es2 - m2);
        den = (head == 0) ? w0 : ((head == 1) ? w1 : w2);
        float wSelf = (lane < 16) ? w0 : ((lane < 32) ? w1 : w2);
        acc.x = wSelf * hv0.x; acc.y = wSelf * hv0.y;
        for (int t0 = beg; t0 < end; t0 += 64) {
            int cnt = min(64, end - t0);
            int s = 0;
            float e0 = 0.f, e1 = 0.f, e2 = 0.f;
            if (lane < cnt) {
                s = csr[t0 + lane];
                e0 = __expf(leaky(a_s[s * 3 + 0] + ad0) - m0);
                e1 = __expf(leaky(a_s[s * 3 + 1] + ad1) - m1);
                e2 = __expf(leaky(a_s[s * 3 + 2] + ad2) - m2);
            }
            ssrc[wid][lane] = s;
            se[wid][0][lane] = e0; se[wid][1][lane] = e1; se[wid][2][lane] = e2;
            int jj = 0;
            for (; jj + 3 < cnt; jj += 4) {
                int sA = ssrc[wid][jj], sB = ssrc[wid][jj + 1];
                int sC = ssrc[wid][jj + 2], sD = ssrc[wid][jj + 3];
                float wA = se[wid][head][jj], wB = se[wid][head][jj + 1];
                float wC = se[wid][head][jj + 2], wD = se[wid][head][jj + 3];
                den += (wA + wB) + (wC + wD);
                if (lane < 48) {
                    unsigned pa = *(const unsigned*)&h1b[(size_t)sA * 96 + 2 * lane];
                    unsigned pb = *(const unsigned*)&h1b[(size_t)sB * 96 + 2 * lane];
                    unsigned pc = *(const unsigned*)&h1b[(size_t)sC * 96 + 2 * lane];
                    unsigned pd = *(const unsigned*)&h1b[(size_t)sD * 96 + 2 * lane];
                    float2 ha = bf2f2(pa), hb = bf2f2(pb), hc = bf2f2(pc), hd = bf2f2(pd);
                    acc.x += wA * ha.x + wB * hb.x + wC * hc.x + wD * hd.x;
                    acc.y += wA * ha.y + wB * hb.y + wC * hc.y + wD * hd.y;
                }
            }
            for (; jj < cnt; ++jj) {
                int sA = ssrc[wid][jj];
                float wA = se[wid][head][jj];
                den += wA;
                if (lane < 48) {
                    float2 ha = bf2f2(*(const unsigned*)&h1b[(size_t)sA * 96 + 2 * lane]);
                    acc.x += wA * ha.x; acc.y += wA * ha.y;
                }
            }
        }
    }

    if (lane < 48) {
        float inv = 1.f / (den + 1e-16f);
        ushort2 o;
        o.x = f2bf(acc.x * inv + b1[2 * lane]);
        o.y = f2bf(acc.y * inv + b1[2 * lane + 1]);
        *(ushort2*)&out1b[(size_t)node * 96 + 2 * lane] = o;
    }
}

// gat2: 128 ch, 1 head; writes bf16 out2 AND accumulates BN partial sums.
__global__ __launch_bounds__(256) void gat2_agg(const unsigned short* __restrict__ h2b,
                                                const float* __restrict__ a_s,
                                                const float* __restrict__ a_d,
                                                const int* __restrict__ offs,
                                                const int* __restrict__ csr,
                                                const float* __restrict__ b2,
                                                unsigned short* __restrict__ out2b,
                                                float* __restrict__ part, int n) {
    __shared__ int ssrc[4][64];
    __shared__ float se[4][64];
    __shared__ float4 red[4][64];
    int wid = threadIdx.x >> 6;
    int node = blockIdx.x * 4 + wid;
    int lane = threadIdx.x & 63;
    float2 o = make_float2(0.f, 0.f);

    if (node < n) {
        int beg = offs[node], end = offs[node + 1];
        int deg = end - beg;
        float ad = a_d[node];
        float es = leaky(a_s[node] + ad);
        float2 hv0 = bf2f2(*(const unsigned int*)&h2b[(size_t)node * 128 + 2 * lane]);
        float den;
        float2 acc;

        if (deg <= 64) {
            int s = 0;
            float l = NEG_INF;
            if (lane < deg) {
                s = csr[beg + lane];
                l = leaky(a_s[s] + ad);
            }
            float m = l;
#pragma unroll
            for (int sh = 32; sh >= 1; sh >>= 1) m = fmaxf(m, __shfl_xor(m, sh));
            m = fmaxf(m, es);
            float e = (lane < deg) ? __expf(l - m) : 0.f;
            ssrc[wid][lane] = s;
            se[wid][lane] = e;
            float wSelf = __expf(es - m);
            den = wSelf;
            acc.x = wSelf * hv0.x; acc.y = wSelf * hv0.y;

            int jj = 0;
            for (; jj + 3 < deg; jj += 4) {
                int sA = ssrc[wid][jj], sB = ssrc[wid][jj + 1];
                int sC = ssrc[wid][jj + 2], sD = ssrc[wid][jj + 3];
                float wA = se[wid][jj], wB = se[wid][jj + 1];
                float wC = se[wid][jj + 2], wD = se[wid][jj + 3];
                den += (wA + wB) + (wC + wD);
                unsigned pa = *(const unsigned*)&h2b[(size_t)sA * 128 + 2 * lane];
                unsigned pb = *(const unsigned*)&h2b[(size_t)sB * 128 + 2 * lane];
                unsigned pc = *(const unsigned*)&h2b[(size_t)sC * 128 + 2 * lane];
                unsigned pd = *(const unsigned*)&h2b[(size_t)sD * 128 + 2 * lane];
                float2 ha = bf2f2(pa), hb = bf2f2(pb), hc = bf2f2(pc), hd = bf2f2(pd);
                acc.x += wA * ha.x + wB * hb.x + wC * hc.x + wD * hd.x;
                acc.y += wA * ha.y + wB * hb.y + wC * hc.y + wD * hd.y;
            }
            for (; jj < deg; ++jj) {
                int sA = ssrc[wid][jj];
                float wA = se[wid][jj];
                den += wA;
                float2 ha = bf2f2(*(const unsigned*)&h2b[(size_t)sA * 128 + 2 * lane]);
                acc.x += wA * ha.x; acc.y += wA * ha.y;
            }
        } else {
            float m = es;
            for (int j = beg + lane; j < end; j += 64) {
                int s = csr[j];
                m = fmaxf(m, leaky(a_s[s] + ad));
            }
#pragma unroll
            for (int sh = 32; sh >= 1; sh >>= 1) m = fmaxf(m, __shfl_xor(m, sh));
            float wSelf = __expf(es - m);
            den = wSelf;
            acc.x = wSelf * hv0.x; acc.y = wSelf * hv0.y;
            for (int t0 = beg; t0 < end; t0 += 64) {
                int cnt = min(64, end - t0);
                int s = 0;
                float e = 0.f;
                if (lane < cnt) {
                    s = csr[t0 + lane];
                    e = __expf(leaky(a_s[s] + ad) - m);
                }
                ssrc[wid][lane] = s;
                se[wid][lane] = e;
                int jj = 0;
                for (; jj + 3 < cnt; jj += 4) {
                    int sA = ssrc[wid][jj], sB = ssrc[wid][jj + 1];
                    int sC = ssrc[wid][jj + 2], sD = ssrc[wid][jj + 3];
                    float wA = se[wid][jj], wB = se[wid][jj + 1];
                    float wC = se[wid][jj + 2], wD = se[wid][jj + 3];
                    den += (wA + wB) + (wC + wD);
                    unsigned pa = *(const unsigned*)&h2b[(size_t)sA * 128 + 2 * lane];
                    unsigned pb = *(const unsigned*)&h2b[(size_t)sB * 128 + 2 * lane];
                    unsigned pc = *(const unsigned*)&h2b[(size_t)sC * 128 + 2 * lane];
                    unsigned pd = *(const unsigned*)&h2b[(size_t)sD * 128 + 2 * lane];
                    float2 ha = bf2f2(pa), hb = bf2f2(pb), hc = bf2f2(pc), hd = bf2f2(pd);
                    acc.x += wA * ha.x + wB * hb.x + wC * hc.x + wD * hd.x;
                    acc.y += wA * ha.y + wB * hb.y + wC * hc.y + wD * hd.y;
                }
                for (; jj < cnt; ++jj) {
                    int sA = ssrc[wid][jj];
                    float wA = se[wid][jj];
                    den += wA;
                    float2 ha = bf2f2(*(const unsigned*)&h2b[(size_t)sA * 128 + 2 * lane]);
                    acc.x += wA * ha.x; acc.y += wA * ha.y;
                }
            }
        }

        float inv = 1.f / (den + 1e-16f);
        o.x = acc.x * inv + b2[2 * lane];
        o.y = acc.y * inv + b2[2 * lane + 1];
        ushort2 ob;
        ob.x = f2bf(o.x); ob.y = f2bf(o.y);
        *(ushort2*)&out2b[(size_t)node * 128 + 2 * lane] = ob;
    }

    // ---- block-level BN partial reduction ----
    red[wid][lane] = make_float4(o.x, o.y, o.x * o.x, o.y * o.y);
    __syncthreads();
    if (wid == 0) {
        float4 a = red[0][lane], b = red[1][lane], c = red[2][lane], d = red[3][lane];
        float sx = a.x + b.x + c.x + d.x;
        float sy = a.y + b.y + c.y + d.y;
        float qx = a.z + b.z + c.z + d.z;
        float qy = a.w + b.w + c.w + d.w;
        float* p = part + (size_t)(blockIdx.x & 63) * 256;
        atomicAdd(&p[2 * lane + 0], sx);
        atomicAdd(&p[2 * lane + 1], sy);
        atomicAdd(&p[128 + 2 * lane + 0], qx);
        atomicAdd(&p[128 + 2 * lane + 1], qy);
    }
}

// ---------------- BN finalize ----------------
__global__ void bn_finalize(const float* __restrict__ part, const float* __restrict__ gamma,
                            const float* __restrict__ beta, float* __restrict__ ss, int n) {
    int c = threadIdx.x;  // 128
    float S = 0.f, Q = 0.f;
    for (int k = 0; k < 64; ++k) {
        S += part[(size_t)k * 256 + c];
        Q += part[(size_t)k * 256 + 128 + c];
    }
    float invN = 1.f / (float)n;
    float mu = S * invN;
    float var = Q * invN - mu * mu;
    float g = gamma[c] * rsqrtf(var + 1e-5f);
    ss[c] = g;
    ss[128 + c] = beta[c] - mu * g;
}

// ---------------- fused BN-normalize + ReLU + residual ----------------
__global__ void final_kernel(const unsigned short* __restrict__ out2b,
                             const unsigned short* __restrict__ residb,
                             const float* __restrict__ ss, float* __restrict__ out, int n) {
    int i = blockIdx.x * blockDim.x + threadIdx.x;  // over n*32 groups of 4 ch
    if (i >= n * 32) return;
    int c0 = (i & 31) * 4;
    uint2 v = ((const uint2*)out2b)[i];
    uint2 r = ((const uint2*)residb)[i];
    float2 v01 = bf2f2(v.x), v23 = bf2f2(v.y);
    float2 r01 = bf2f2(r.x), r23 = bf2f2(r.y);
    float4 o;
    o.x = fmaxf(v01.x * ss[c0 + 0] + ss[128 + c0 + 0], 0.f) + r01.x;
    o.y = fmaxf(v01.y * ss[c0 + 1] + ss[128 + c0 + 1], 0.f) + r01.y;
    o.z = fmaxf(v23.x * ss[c0 + 2] + ss[128 + c0 + 2], 0.f) + r23.x;
    o.w = fmaxf(v23.y * ss[c0 + 3] + ss[128 + c0 + 3], 0.f) + r23.y;
    ((float4*)out)[i] = o;
}

extern "C" void kernel_launch(void* const* d_in, const int* in_sizes, int n_in,
                              void* d_out, int out_size, void* d_ws, size_t ws_size,
                              hipStream_t stream) {
    const float* x     = (const float*)d_in[0];
    const int*   ei    = (const int*)d_in[1];
    const float* W1    = (const float*)d_in[2];
    const float* asrc1 = (const float*)d_in[3];
    const float* adst1 = (const float*)d_in[4];
    const float* b1    = (const float*)d_in[5];
    const float* W2    = (const float*)d_in[6];
    const float* asrc2 = (const float*)d_in[7];
    const float* adst2 = (const float*)d_in[8];
    const float* b2    = (const float*)d_in[9];
    const float* gamma = (const float*)d_in[10];
    const float* beta  = (const float*)d_in[11];
    const float* Wres  = (const float*)d_in[12];
    const float* bres  = (const float*)d_in[13];

    const int n = in_sizes[0] / 128;  // 50000
    const int E = in_sizes[1] / 2;    // 800000

    char* ws = (char*)d_ws;
    size_t off = 0;
    auto alloc = [&](size_t bytes) {
        void* p = ws + off;
        off = (off + bytes + 255) & ~(size_t)255;
        return p;
    };
    float* as1  = (float*)alloc((size_t)n * 3 * 4);
    float* ad1  = (float*)alloc((size_t)n * 3 * 4);
    float* as2  = (float*)alloc((size_t)n * 4);
    float* ad2  = (float*)alloc((size_t)n * 4);
    float* part = (float*)alloc(64 * 256 * 4);
    float* ss   = (float*)alloc(256 * 4);
    unsigned short* xb     = (unsigned short*)alloc((size_t)n * 128 * 2);
    unsigned short* h1b    = (unsigned short*)alloc((size_t)n * 96 * 2);
    unsigned short* h2b    = (unsigned short*)alloc((size_t)n * 128 * 2);
    unsigned short* out1b  = (unsigned short*)alloc((size_t)n * 96 * 2);
    unsigned short* out2b  = (unsigned short*)alloc((size_t)n * 128 * 2);
    unsigned short* residb = (unsigned short*)alloc((size_t)n * 128 * 2);
    unsigned short* w1p    = (unsigned short*)alloc(128 * 96 * 2);
    unsigned short* w2p    = (unsigned short*)alloc(96 * 128 * 2);
    unsigned short* wresp  = (unsigned short*)alloc(128 * 128 * 2);
    int* deg      = (int*)alloc((size_t)n * 4);
    int* offs     = (int*)alloc((size_t)(n + 1) * 4);
    int* ctr      = (int*)alloc((size_t)(n + 1) * 4);
    int* bsum     = (int*)alloc(256 * 4);
    int* pairBase = (int*)alloc(1600 * 4);
    int* bcur     = (int*)alloc(1600 * 4);
    int2* pairBuf = (int2*)alloc((size_t)E * 8);
    int* csr      = (int*)alloc((size_t)E * 4);

    hipMemsetAsync(deg, 0, (size_t)n * 4, stream);
    hipMemsetAsync(part, 0, 64 * 256 * 4, stream);

    const int* srcIdx = ei;
    const int* dstIdx = ei + E;
    const int nb = (n + 255) / 256;
    const int NB = (n + 31) / 32;  // 1563 buckets

    // fused prep: hist + x->bf16 + 3 weight packs
    const int histBlks = 512;
    const int nxb = (n * 32 + 255) / 256;
    prep_kernel<<<histBlks + nxb + 160, 256, 0, stream>>>(x, xb, n * 32, W1, w1p, W2, w2p,
                                                          Wres, wresp, dstIdx, E, deg, histBlks);

    scan_part<<<nb, 256, 0, stream>>>(deg, offs, bsum, n);
    scan_bsum<<<1, 256, 0, stream>>>(bsum, nb);
    scan_add<<<nb, 256, 0, stream>>>(offs, ctr, bsum, n, pairBase, bcur);

    // pass A: bin edges into 32-node buckets (L2-local appends)
    bin_kernel<<<(E + 4095) / 4096, 256, 0, stream>>>(srcIdx, dstIdx, E, bcur, pairBuf, NB);

    const int mt = (n + 15) / 16;   // 3125 row tiles
    const int gblk = (mt + 3) / 4;  // 782
    const int passBlks = 391;       // 1564 waves >= NB buckets

    // phase2: passB (bucket->csr scatter) + gemm1(+att1) + gemm_res, fused for overlap
    phase2_kernel<<<passBlks + 2 * gblk, 256, 0, stream>>>(
        pairBuf, pairBase, bcur, ctr, csr, NB, xb, w1p, h1b, asrc1, adst1, as1, ad1,
        wresp, bres, residb, n, passBlks, gblk);

    gat1_agg<<<(n + 3) / 4, 256, 0, stream>>>(h1b, as1, ad1, offs, csr, b1, out1b, n);
    gemm2_kernel<<<gblk, 256, 0, stream>>>(out1b, w2p, h2b, asrc2, adst2, as2, ad2, n);
    gat2_agg<<<(n + 3) / 4, 256, 0, stream>>>(h2b, as2, ad2, offs, csr, b2, out2b, part, n);
    bn_finalize<<<1, 128, 0, stream>>>(part, gamma, beta, ss, n);
    final_kernel<<<(n * 32 + 255) / 256, 256, 0, stream>>>(out2b, residb, ss, (float*)d_out, n);
}

// Round 10
// 195.499 us; speedup vs baseline: 3.2132x; 1.1220x over previous
//
#include <hip/hip_runtime.h>

#define NEG 0.2f
#define NEG_INF (-1e30f)

typedef __attribute__((ext_vector_type(8))) short bf16x8;
typedef __attribute__((ext_vector_type(4))) float f32x4;

__device__ __forceinline__ float leaky(float e) { return e > 0.f ? e : NEG * e; }

__device__ __forceinline__ unsigned short f2bf(float f) {
    unsigned int u = __float_as_uint(f);
    unsigned int r = u + 0x7fffu + ((u >> 16) & 1u);
    return (unsigned short)(r >> 16);
}
__device__ __forceinline__ float2 bf2f2(unsigned int u) {
    float2 r;
    r.x = __uint_as_float(u << 16);
    r.y = __uint_as_float(u & 0xffff0000u);
    return r;
}

// ---------------- fused prep: hist + x->bf16 + weight packing ----------------
__device__ __forceinline__ void pack_w(const float* __restrict__ W,
                                       unsigned short* __restrict__ Bp, int K, int N, int idx) {
    int i = idx & 7;
    int rest = idx >> 3;
    int lane = rest & 63;
    rest >>= 6;
    int KT = K / 32;
    int kt = rest % KT;
    int ct = rest / KT;
    int m = lane & 15, kb = lane >> 4;
    int k = kt * 32 + kb * 8 + i, col = ct * 16 + m;
    Bp[idx] = f2bf(W[(size_t)k * N + col]);
}

__global__ __launch_bounds__(256) void prep_kernel(const float* __restrict__ x,
                                                   unsigned short* __restrict__ xb, int n4,
                                                   const float* __restrict__ W1,
                                                   unsigned short* __restrict__ w1p,
                                                   const float* __restrict__ W2,
                                                   unsigned short* __restrict__ w2p,
                                                   const float* __restrict__ Wres,
                                                   unsigned short* __restrict__ wresp,
                                                   const int* __restrict__ dst, int E,
                                                   int* __restrict__ deg, int histBlks) {
    int b = blockIdx.x;
    if (b < histBlks) {
        for (int e = b * 256 + threadIdx.x; e < E; e += histBlks * 256)
            atomicAdd(&deg[dst[e]], 1);
        return;
    }
    b -= histBlks;
    int nxb = (n4 + 255) / 256;
    if (b < nxb) {
        int i = b * 256 + threadIdx.x;
        if (i < n4) {
            float4 v = ((const float4*)x)[i];
            ushort4 o;
            o.x = f2bf(v.x); o.y = f2bf(v.y); o.z = f2bf(v.z); o.w = f2bf(v.w);
            ((ushort4*)xb)[i] = o;
        }
        return;
    }
    b -= nxb;
    if (b < 48) { pack_w(W1, w1p, 128, 96, b * 256 + threadIdx.x); return; }
    b -= 48;
    if (b < 48) { pack_w(W2, w2p, 96, 128, b * 256 + threadIdx.x); return; }
    b -= 48;
    if (b < 64) { pack_w(Wres, wresp, 128, 128, b * 256 + threadIdx.x); }
}

// ---------------- scan chain ----------------
__global__ void scan_part(const int* __restrict__ deg, int* __restrict__ offs,
                          int* __restrict__ bsum, int n) {
    __shared__ int buf[256];
    int i = blockIdx.x * 256 + threadIdx.x;
    int v = (i < n) ? deg[i] : 0;
    buf[threadIdx.x] = v;
    __syncthreads();
    for (int s = 1; s < 256; s <<= 1) {
        int t = (threadIdx.x >= s) ? buf[threadIdx.x - s] : 0;
        __syncthreads();
        buf[threadIdx.x] += t;
        __syncthreads();
    }
    if (i < n) offs[i + 1] = buf[threadIdx.x];
    if (threadIdx.x == 255) bsum[blockIdx.x] = buf[255];
}

__global__ void scan_bsum(int* __restrict__ bsum, int nb) {
    __shared__ int buf[256];
    int v = (threadIdx.x < nb) ? bsum[threadIdx.x] : 0;
    buf[threadIdx.x] = v;
    __syncthreads();
    for (int s = 1; s < 256; s <<= 1) {
        int t = (threadIdx.x >= s) ? buf[threadIdx.x - s] : 0;
        __syncthreads();
        buf[threadIdx.x] += t;
        __syncthreads();
    }
    if (threadIdx.x < nb) bsum[threadIdx.x] = buf[threadIdx.x] - v;  // exclusive
}

// seeds per-bucket (32-node) pairBase/bcur
__global__ void scan_add(int* __restrict__ offs, const int* __restrict__ bsum, int n,
                         int* __restrict__ pairBase, int* __restrict__ bcur) {
    int i = blockIdx.x * 256 + threadIdx.x;
    if (i < n) {
        int v = offs[i + 1] + bsum[blockIdx.x];
        offs[i + 1] = v;
        if (((i + 1) & 31) == 0) {
            int b = (i + 1) >> 5;
            pairBase[b] = v;
            bcur[b] = v;
        }
    }
    if (i == 0) { offs[0] = 0; pairBase[0] = 0; bcur[0] = 0; }
}

// ---------------- binned edge pass A: LDS-staged bucket append ----------------
__global__ __launch_bounds__(256) void bin_kernel(const int* __restrict__ src,
                                                  const int* __restrict__ dst, int E,
                                                  int* __restrict__ bcur,
                                                  int2* __restrict__ pairBuf, int nb) {
    __shared__ int2 stage[4096];
    __shared__ int hist[1600];
    __shared__ int base[1600];
    for (int c0 = blockIdx.x * 4096; c0 < E; c0 += gridDim.x * 4096) {
        int cnt = min(4096, E - c0);
        for (int b = threadIdx.x; b < nb; b += 256) hist[b] = 0;
        __syncthreads();
        for (int i = threadIdx.x; i < cnt; i += 256) {
            int s = src[c0 + i], d = dst[c0 + i];
            stage[i] = make_int2(s, d);
            atomicAdd(&hist[d >> 5], 1);
        }
        __syncthreads();
        for (int b = threadIdx.x; b < nb; b += 256) {
            int h = hist[b];
            if (h) base[b] = atomicAdd(&bcur[b], h);
            hist[b] = 0;
        }
        __syncthreads();
        for (int i = threadIdx.x; i < cnt; i += 256) {
            int2 p = stage[i];
            int b = p.y >> 5;
            int off = atomicAdd(&hist[b], 1);
            pairBuf[base[b] + off] = p;
        }
        __syncthreads();
    }
}

// ---------------- MFMA GEMM body: one wave per 16-row tile, all col-tiles ----------------
template <int K, int N, int HEADS>
__device__ __forceinline__ void gemm_body(int w, const unsigned short* __restrict__ A,
                                          const unsigned short* __restrict__ Bp,
                                          const float* __restrict__ bias,
                                          unsigned short* __restrict__ outB,
                                          const float* __restrict__ asrc,
                                          const float* __restrict__ adst,
                                          float* __restrict__ a_s,
                                          float* __restrict__ a_d, int M) {
    constexpr int KT = K / 32, CT = N / 16;
    int row0 = w * 16;
    if (row0 >= M) return;
    int lane = threadIdx.x & 63;
    int m = lane & 15, kb = lane >> 4;
    const unsigned short* arow = A + (size_t)(row0 + m) * K + kb * 8;

    f32x4 acc[CT];
#pragma unroll
    for (int ct = 0; ct < CT; ++ct) acc[ct] = (f32x4){0.f, 0.f, 0.f, 0.f};

#pragma unroll
    for (int kt = 0; kt < KT; ++kt) {
        bf16x8 a = *(const bf16x8*)(arow + kt * 32);
#pragma unroll
        for (int ct = 0; ct < CT; ++ct) {
            bf16x8 b = *(const bf16x8*)(Bp + ((size_t)(ct * KT + kt) * 64 + lane) * 8);
            acc[ct] = __builtin_amdgcn_mfma_f32_16x16x32_bf16(a, b, acc[ct], 0, 0, 0);
        }
    }

#pragma unroll
    for (int r = 0; r < 4; ++r) {
        int row = row0 + kb * 4 + r;
#pragma unroll
        for (int ct = 0; ct < CT; ++ct) {
            int col = ct * 16 + m;
            float v = acc[ct][r] + (bias ? bias[col] : 0.f);
            outB[(size_t)row * N + col] = f2bf(v);
        }
    }

    if (HEADS > 0) {
        float asv[CT], adv[CT];
#pragma unroll
        for (int ct = 0; ct < CT; ++ct) {
            int col = ct * 16 + m;
            asv[ct] = asrc[col];
            adv[ct] = adst[col];
        }
        constexpr int TPH = CT / (HEADS > 0 ? HEADS : 1);
#pragma unroll
        for (int r = 0; r < 4; ++r) {
            int row = row0 + kb * 4 + r;
#pragma unroll
            for (int h = 0; h < HEADS; ++h) {
                float s = 0.f, d = 0.f;
#pragma unroll
                for (int t = 0; t < TPH; ++t) {
                    int ct = h * TPH + t;
                    s += acc[ct][r] * asv[ct];
                    d += acc[ct][r] * adv[ct];
                }
#pragma unroll
                for (int off = 1; off <= 8; off <<= 1) {
                    s += __shfl_xor(s, off);
                    d += __shfl_xor(d, off);
                }
                if (m == 0) {
                    a_s[(size_t)row * HEADS + h] = s;
                    a_d[(size_t)row * HEADS + h] = d;
                }
            }
        }
    }
}

// ---------------- phase2: passB (LDS-counter bucket scatter) + gemm1 + gemm_res ----------------
__global__ __launch_bounds__(256) void phase2_kernel(
    const int2* __restrict__ pairBuf, const int* __restrict__ pairBase,
    const int* __restrict__ bcur, const int* __restrict__ offs,
    int* __restrict__ csr, int nb,
    const unsigned short* __restrict__ xb,
    const unsigned short* __restrict__ w1p, unsigned short* __restrict__ h1b,
    const float* __restrict__ asrc1, const float* __restrict__ adst1,
    float* __restrict__ as1, float* __restrict__ ad1,
    const unsigned short* __restrict__ wresp, const float* __restrict__ bres,
    unsigned short* __restrict__ residb, int n, int passBlks, int g1Blks) {
    int b = blockIdx.x;
    int lane = threadIdx.x & 63;
    int wid = threadIdx.x >> 6;
    if (b < passBlks) {
        __shared__ int cnt[4][32];
        int bk = b * 4 + wid;  // one bucket per wave (passBlks*4 >= nb)
        if (bk < nb) {
            int node0 = bk * 32;
            if (lane < 32) cnt[wid][lane] = (node0 + lane < n) ? offs[node0 + lane] : 0;
            int lo = pairBase[bk], hi = bcur[bk];
            for (int i = lo + lane; i < hi; i += 64) {
                int2 p = pairBuf[i];
                int pos = atomicAdd(&cnt[wid][p.y & 31], 1);  // LDS atomic
                csr[pos] = p.x;
            }
        }
        return;
    }
    b -= passBlks;
    if (b < g1Blks) {
        gemm_body<128, 96, 3>(b * 4 + wid, xb, w1p, nullptr, h1b,
                              asrc1, adst1, as1, ad1, n);
        return;
    }
    b -= g1Blks;
    gemm_body<128, 128, 0>(b * 4 + wid, xb, wresp, bres, residb,
                           nullptr, nullptr, nullptr, nullptr, n);
}

// gemm2 standalone wrapper
__global__ __launch_bounds__(256) void gemm2_kernel(const unsigned short* __restrict__ A,
                                                    const unsigned short* __restrict__ Bp,
                                                    unsigned short* __restrict__ outB,
                                                    const float* __restrict__ asrc,
                                                    const float* __restrict__ adst,
                                                    float* __restrict__ a_s,
                                                    float* __restrict__ a_d, int M) {
    gemm_body<96, 128, 1>(blockIdx.x * 4 + (threadIdx.x >> 6), A, Bp, nullptr, outB,
                          asrc, adst, a_s, a_d, M);
}

// ---------------- GAT aggregation: split LDS scratch, 4-wide gather ILP ----------------
__global__ __launch_bounds__(256) void gat1_agg(const unsigned short* __restrict__ h1b,
                                                const float* __restrict__ a_s,
                                                const float* __restrict__ a_d,
                                                const int* __restrict__ offs,
                                                const int* __restrict__ csr,
                                                const float* __restrict__ b1,
                                                unsigned short* __restrict__ out1b, int n) {
    __shared__ int ssrc[4][64];
    __shared__ float se[4][3][64];
    int wid = threadIdx.x >> 6;
    int node = blockIdx.x * 4 + wid;
    if (node >= n) return;
    int lane = threadIdx.x & 63;
    int head = lane >> 4; if (head > 2) head = 2;
    int beg = offs[node], end = offs[node + 1];
    int deg = end - beg;
    float ad0 = a_d[node * 3 + 0], ad1 = a_d[node * 3 + 1], ad2 = a_d[node * 3 + 2];
    float es0 = leaky(a_s[node * 3 + 0] + ad0);
    float es1 = leaky(a_s[node * 3 + 1] + ad1);
    float es2 = leaky(a_s[node * 3 + 2] + ad2);
    float2 hv0 = make_float2(0.f, 0.f);
    if (lane < 48) hv0 = bf2f2(*(const unsigned int*)&h1b[(size_t)node * 96 + 2 * lane]);

    float den;
    float2 acc;

    if (deg <= 64) {
        int s = 0;
        float l0 = NEG_INF, l1 = NEG_INF, l2 = NEG_INF;
        if (lane < deg) {
            s = csr[beg + lane];
            l0 = leaky(a_s[s * 3 + 0] + ad0);
            l1 = leaky(a_s[s * 3 + 1] + ad1);
            l2 = leaky(a_s[s * 3 + 2] + ad2);
        }
        float m0 = l0, m1 = l1, m2 = l2;
#pragma unroll
        for (int sh = 32; sh >= 1; sh >>= 1) {
            m0 = fmaxf(m0, __shfl_xor(m0, sh));
            m1 = fmaxf(m1, __shfl_xor(m1, sh));
            m2 = fmaxf(m2, __shfl_xor(m2, sh));
        }
        m0 = fmaxf(m0, es0); m1 = fmaxf(m1, es1); m2 = fmaxf(m2, es2);
        float e0 = 0.f, e1 = 0.f, e2 = 0.f;
        if (lane < deg) {
            e0 = __expf(l0 - m0); e1 = __expf(l1 - m1); e2 = __expf(l2 - m2);
        }
        ssrc[wid][lane] = s;
        se[wid][0][lane] = e0; se[wid][1][lane] = e1; se[wid][2][lane] = e2;
        float w0 = __expf(es0 - m0), w1 = __expf(es1 - m1), w2 = __expf(es2 - m2);
        den = (head == 0) ? w0 : ((head == 1) ? w1 : w2);
        float wSelf = (lane < 16) ? w0 : ((lane < 32) ? w1 : w2);
        acc.x = wSelf * hv0.x; acc.y = wSelf * hv0.y;

        int jj = 0;
        for (; jj + 3 < deg; jj += 4) {
            int sA = ssrc[wid][jj], sB = ssrc[wid][jj + 1];
            int sC = ssrc[wid][jj + 2], sD = ssrc[wid][jj + 3];
            float wA = se[wid][head][jj], wB = se[wid][head][jj + 1];
            float wC = se[wid][head][jj + 2], wD = se[wid][head][jj + 3];
            den += (wA + wB) + (wC + wD);
            if (lane < 48) {
                unsigned pa = *(const unsigned*)&h1b[(size_t)sA * 96 + 2 * lane];
                unsigned pb = *(const unsigned*)&h1b[(size_t)sB * 96 + 2 * lane];
                unsigned pc = *(const unsigned*)&h1b[(size_t)sC * 96 + 2 * lane];
                unsigned pd = *(const unsigned*)&h1b[(size_t)sD * 96 + 2 * lane];
                float2 ha = bf2f2(pa), hb = bf2f2(pb), hc = bf2f2(pc), hd = bf2f2(pd);
                acc.x += wA * ha.x + wB * hb.x + wC * hc.x + wD * hd.x;
                acc.y += wA * ha.y + wB * hb.y + wC * hc.y + wD * hd.y;
            }
        }
        for (; jj < deg; ++jj) {
            int sA = ssrc[wid][jj];
            float wA = se[wid][head][jj];
            den += wA;
            if (lane < 48) {
                float2 ha = bf2f2(*(const unsigned*)&h1b[(size_t)sA * 96 + 2 * lane]);
                acc.x += wA * ha.x; acc.y += wA * ha.y;
            }
        }
    } else {
        float m0 = es0, m1 = es1, m2 = es2;
        for (int j = beg + lane; j < end; j += 64) {
            int s = csr[j];
            m0 = fmaxf(m0, leaky(a_s[s * 3 + 0] + ad0));
            m1 = fmaxf(m1, leaky(a_s[s * 3 + 1] + ad1));
            m2 = fmaxf(m2, leaky(a_s[s * 3 + 2] + ad2));
        }
#pragma unroll
        for (int sh = 32; sh >= 1; sh >>= 1) {
            m0 = fmaxf(m0, __shfl_xor(m0, sh));
            m1 = fmaxf(m1, __shfl_xor(m1, sh));
            m2 = fmaxf(m2, __shfl_xor(m2, sh));
        }
        float w0 = __expf(es0 - m0), w1 = __expf(es1 - m1), w2 = __expf(es2 - m2);
        den = (head == 0) ? w0 : ((head == 1) ? w1 : w2);
        float wSelf = (lane < 16) ? w0 : ((lane < 32) ? w1 : w2);
        acc.x = wSelf * hv0.x; acc.y = wSelf * hv0.y;
        for (int t0 = beg; t0 < end; t0 += 64) {
            int cnt = min(64, end - t0);
            int s = 0;
            float e0 = 0.f, e1 = 0.f, e2 = 0.f;
            if (lane < cnt) {
                s = csr[t0 + lane];
                e0 = __expf(leaky(a_s[s * 3 + 0] + ad0) - m0);
                e1 = __expf(leaky(a_s[s * 3 + 1] + ad1) - m1);
                e2 = __expf(leaky(a_s[s * 3 + 2] + ad2) - m2);
            }
            ssrc[wid][lane] = s;
            se[wid][0][lane] = e0; se[wid][1][lane] = e1; se[wid][2][lane] = e2;
            int jj = 0;
            for (; jj + 3 < cnt; jj += 4) {
                int sA = ssrc[wid][jj], sB = ssrc[wid][jj + 1];
                int sC = ssrc[wid][jj + 2], sD = ssrc[wid][jj + 3];
                float wA = se[wid][head][jj], wB = se[wid][head][jj + 1];
                float wC = se[wid][head][jj + 2], wD = se[wid][head][jj + 3];
                den += (wA + wB) + (wC + wD);
                if (lane < 48) {
                    unsigned pa = *(const unsigned*)&h1b[(size_t)sA * 96 + 2 * lane];
                    unsigned pb = *(const unsigned*)&h1b[(size_t)sB * 96 + 2 * lane];
                    unsigned pc = *(const unsigned*)&h1b[(size_t)sC * 96 + 2 * lane];
                    unsigned pd = *(const unsigned*)&h1b[(size_t)sD * 96 + 2 * lane];
                    float2 ha = bf2f2(pa), hb = bf2f2(pb), hc = bf2f2(pc), hd = bf2f2(pd);
                    acc.x += wA * ha.x + wB * hb.x + wC * hc.x + wD * hd.x;
                    acc.y += wA * ha.y + wB * hb.y + wC * hc.y + wD * hd.y;
                }
            }
            for (; jj < cnt; ++jj) {
                int sA = ssrc[wid][jj];
                float wA = se[wid][head][jj];
                den += wA;
                if (lane < 48) {
                    float2 ha = bf2f2(*(const unsigned*)&h1b[(size_t)sA * 96 + 2 * lane]);
                    acc.x += wA * ha.x; acc.y += wA * ha.y;
                }
            }
        }
    }

    if (lane < 48) {
        float inv = 1.f / (den + 1e-16f);
        ushort2 o;
        o.x = f2bf(acc.x * inv + b1[2 * lane]);
        o.y = f2bf(acc.y * inv + b1[2 * lane + 1]);
        *(ushort2*)&out1b[(size_t)node * 96 + 2 * lane] = o;
    }
}

// gat2: 128 ch, 1 head; writes bf16 out2 AND accumulates BN partial sums.
__global__ __launch_bounds__(256) void gat2_agg(const unsigned short* __restrict__ h2b,
                                                const float* __restrict__ a_s,
                                                const float* __restrict__ a_d,
                                                const int* __restrict__ offs,
                                                const int* __restrict__ csr,
                                                const float* __restrict__ b2,
                                                unsigned short* __restrict__ out2b,
                                                float* __restrict__ part, int n) {
    __shared__ int ssrc[4][64];
    __shared__ float se[4][64];
    __shared__ float4 red[4][64];
    int wid = threadIdx.x >> 6;
    int node = blockIdx.x * 4 + wid;
    int lane = threadIdx.x & 63;
    float2 o = make_float2(0.f, 0.f);

    if (node < n) {
        int beg = offs[node], end = offs[node + 1];
        int deg = end - beg;
        float ad = a_d[node];
        float es = leaky(a_s[node] + ad);
        float2 hv0 = bf2f2(*(const unsigned int*)&h2b[(size_t)node * 128 + 2 * lane]);
        float den;
        float2 acc;

        if (deg <= 64) {
            int s = 0;
            float l = NEG_INF;
            if (lane < deg) {
                s = csr[beg + lane];
                l = leaky(a_s[s] + ad);
            }
            float m = l;
#pragma unroll
            for (int sh = 32; sh >= 1; sh >>= 1) m = fmaxf(m, __shfl_xor(m, sh));
            m = fmaxf(m, es);
            float e = (lane < deg) ? __expf(l - m) : 0.f;
            ssrc[wid][lane] = s;
            se[wid][lane] = e;
            float wSelf = __expf(es - m);
            den = wSelf;
            acc.x = wSelf * hv0.x; acc.y = wSelf * hv0.y;

            int jj = 0;
            for (; jj + 3 < deg; jj += 4) {
                int sA = ssrc[wid][jj], sB = ssrc[wid][jj + 1];
                int sC = ssrc[wid][jj + 2], sD = ssrc[wid][jj + 3];
                float wA = se[wid][jj], wB = se[wid][jj + 1];
                float wC = se[wid][jj + 2], wD = se[wid][jj + 3];
                den += (wA + wB) + (wC + wD);
                unsigned pa = *(const unsigned*)&h2b[(size_t)sA * 128 + 2 * lane];
                unsigned pb = *(const unsigned*)&h2b[(size_t)sB * 128 + 2 * lane];
                unsigned pc = *(const unsigned*)&h2b[(size_t)sC * 128 + 2 * lane];
                unsigned pd = *(const unsigned*)&h2b[(size_t)sD * 128 + 2 * lane];
                float2 ha = bf2f2(pa), hb = bf2f2(pb), hc = bf2f2(pc), hd = bf2f2(pd);
                acc.x += wA * ha.x + wB * hb.x + wC * hc.x + wD * hd.x;
                acc.y += wA * ha.y + wB * hb.y + wC * hc.y + wD * hd.y;
            }
            for (; jj < deg; ++jj) {
                int sA = ssrc[wid][jj];
                float wA = se[wid][jj];
                den += wA;
                float2 ha = bf2f2(*(const unsigned*)&h2b[(size_t)sA * 128 + 2 * lane]);
                acc.x += wA * ha.x; acc.y += wA * ha.y;
            }
        } else {
            float m = es;
            for (int j = beg + lane; j < end; j += 64) {
                int s = csr[j];
                m = fmaxf(m, leaky(a_s[s] + ad));
            }
#pragma unroll
            for (int sh = 32; sh >= 1; sh >>= 1) m = fmaxf(m, __shfl_xor(m, sh));
            float wSelf = __expf(es - m);
            den = wSelf;
            acc.x = wSelf * hv0.x; acc.y = wSelf * hv0.y;
            for (int t0 = beg; t0 < end; t0 += 64) {
                int cnt = min(64, end - t0);
                int s = 0;
                float e = 0.f;
                if (lane < cnt) {
                    s = csr[t0 + lane];
                    e = __expf(leaky(a_s[s] + ad) - m);
                }
                ssrc[wid][lane] = s;
                se[wid][lane] = e;
                int jj = 0;
                for (; jj + 3 < cnt; jj += 4) {
                    int sA = ssrc[wid][jj], sB = ssrc[wid][jj + 1];
                    int sC = ssrc[wid][jj + 2], sD = ssrc[wid][jj + 3];
                    float wA = se[wid][jj], wB = se[wid][jj + 1];
                    float wC = se[wid][jj + 2], wD = se[wid][jj + 3];
                    den += (wA + wB) + (wC + wD);
                    unsigned pa = *(const unsigned*)&h2b[(size_t)sA * 128 + 2 * lane];
                    unsigned pb = *(const unsigned*)&h2b[(size_t)sB * 128 + 2 * lane];
                    unsigned pc = *(const unsigned*)&h2b[(size_t)sC * 128 + 2 * lane];
                    unsigned pd = *(const unsigned*)&h2b[(size_t)sD * 128 + 2 * lane];
                    float2 ha = bf2f2(pa), hb = bf2f2(pb), hc = bf2f2(pc), hd = bf2f2(pd);
                    acc.x += wA * ha.x + wB * hb.x + wC * hc.x + wD * hd.x;
                    acc.y += wA * ha.y + wB * hb.y + wC * hc.y + wD * hd.y;
                }
                for (; jj < cnt; ++jj) {
                    int sA = ssrc[wid][jj];
                    float wA = se[wid][jj];
                    den += wA;
                    float2 ha = bf2f2(*(const unsigned*)&h2b[(size_t)sA * 128 + 2 * lane]);
                    acc.x += wA * ha.x; acc.y += wA * ha.y;
                }
            }
        }

        float inv = 1.f / (den + 1e-16f);
        o.x = acc.x * inv + b2[2 * lane];
        o.y = acc.y * inv + b2[2 * lane + 1];
        ushort2 ob;
        ob.x = f2bf(o.x); ob.y = f2bf(o.y);
        *(ushort2*)&out2b[(size_t)node * 128 + 2 * lane] = ob;
    }

    // ---- block-level BN partial reduction ----
    red[wid][lane] = make_float4(o.x, o.y, o.x * o.x, o.y * o.y);
    __syncthreads();
    if (wid == 0) {
        float4 a = red[0][lane], b = red[1][lane], c = red[2][lane], d = red[3][lane];
        float sx = a.x + b.x + c.x + d.x;
        float sy = a.y + b.y + c.y + d.y;
        float qx = a.z + b.z + c.z + d.z;
        float qy = a.w + b.w + c.w + d.w;
        float* p = part + (size_t)(blockIdx.x & 63) * 256;
        atomicAdd(&p[2 * lane + 0], sx);
        atomicAdd(&p[2 * lane + 1], sy);
        atomicAdd(&p[128 + 2 * lane + 0], qx);
        atomicAdd(&p[128 + 2 * lane + 1], qy);
    }
}

// ---------------- BN finalize ----------------
__global__ void bn_finalize(const float* __restrict__ part, const float* __restrict__ gamma,
                            const float* __restrict__ beta, float* __restrict__ ss, int n) {
    int c = threadIdx.x;  // 128
    float S = 0.f, Q = 0.f;
    for (int k = 0; k < 64; ++k) {
        S += part[(size_t)k * 256 + c];
        Q += part[(size_t)k * 256 + 128 + c];
    }
    float invN = 1.f / (float)n;
    float mu = S * invN;
    float var = Q * invN - mu * mu;
    float g = gamma[c] * rsqrtf(var + 1e-5f);
    ss[c] = g;
    ss[128 + c] = beta[c] - mu * g;
}

// ---------------- fused BN-normalize + ReLU + residual ----------------
__global__ void final_kernel(const unsigned short* __restrict__ out2b,
                             const unsigned short* __restrict__ residb,
                             const float* __restrict__ ss, float* __restrict__ out, int n) {
    int i = blockIdx.x * blockDim.x + threadIdx.x;  // over n*32 groups of 4 ch
    if (i >= n * 32) return;
    int c0 = (i & 31) * 4;
    uint2 v = ((const uint2*)out2b)[i];
    uint2 r = ((const uint2*)residb)[i];
    float2 v01 = bf2f2(v.x), v23 = bf2f2(v.y);
    float2 r01 = bf2f2(r.x), r23 = bf2f2(r.y);
    float4 o;
    o.x = fmaxf(v01.x * ss[c0 + 0] + ss[128 + c0 + 0], 0.f) + r01.x;
    o.y = fmaxf(v01.y * ss[c0 + 1] + ss[128 + c0 + 1], 0.f) + r01.y;
    o.z = fmaxf(v23.x * ss[c0 + 2] + ss[128 + c0 + 2], 0.f) + r23.x;
    o.w = fmaxf(v23.y * ss[c0 + 3] + ss[128 + c0 + 3], 0.f) + r23.y;
    ((float4*)out)[i] = o;
}

extern "C" void kernel_launch(void* const* d_in, const int* in_sizes, int n_in,
                              void* d_out, int out_size, void* d_ws, size_t ws_size,
                              hipStream_t stream) {
    const float* x     = (const float*)d_in[0];
    const int*   ei    = (const int*)d_in[1];
    const float* W1    = (const float*)d_in[2];
    const float* asrc1 = (const float*)d_in[3];
    const float* adst1 = (const float*)d_in[4];
    const float* b1    = (const float*)d_in[5];
    const float* W2    = (const float*)d_in[6];
    const float* asrc2 = (const float*)d_in[7];
    const float* adst2 = (const float*)d_in[8];
    const float* b2    = (const float*)d_in[9];
    const float* gamma = (const float*)d_in[10];
    const float* beta  = (const float*)d_in[11];
    const float* Wres  = (const float*)d_in[12];
    const float* bres  = (const float*)d_in[13];

    const int n = in_sizes[0] / 128;  // 50000
    const int E = in_sizes[1] / 2;    // 800000

    char* ws = (char*)d_ws;
    size_t off = 0;
    auto alloc = [&](size_t bytes) {
        void* p = ws + off;
        off = (off + bytes + 255) & ~(size_t)255;
        return p;
    };
    float* as1  = (float*)alloc((size_t)n * 3 * 4);
    float* ad1  = (float*)alloc((size_t)n * 3 * 4);
    float* as2  = (float*)alloc((size_t)n * 4);
    float* ad2  = (float*)alloc((size_t)n * 4);
    float* part = (float*)alloc(64 * 256 * 4);
    float* ss   = (float*)alloc(256 * 4);
    unsigned short* xb     = (unsigned short*)alloc((size_t)n * 128 * 2);
    unsigned short* h1b    = (unsigned short*)alloc((size_t)n * 96 * 2);
    unsigned short* h2b    = (unsigned short*)alloc((size_t)n * 128 * 2);
    unsigned short* out1b  = (unsigned short*)alloc((size_t)n * 96 * 2);
    unsigned short* out2b  = (unsigned short*)alloc((size_t)n * 128 * 2);
    unsigned short* residb = (unsigned short*)alloc((size_t)n * 128 * 2);
    unsigned short* w1p    = (unsigned short*)alloc(128 * 96 * 2);
    unsigned short* w2p    = (unsigned short*)alloc(96 * 128 * 2);
    unsigned short* wresp  = (unsigned short*)alloc(128 * 128 * 2);
    int* deg      = (int*)alloc((size_t)n * 4);
    int* offs     = (int*)alloc((size_t)(n + 1) * 4);
    int* bsum     = (int*)alloc(256 * 4);
    int* pairBase = (int*)alloc(1600 * 4);
    int* bcur     = (int*)alloc(1600 * 4);
    int2* pairBuf = (int2*)alloc((size_t)E * 8);
    int* csr      = (int*)alloc((size_t)E * 4);

    hipMemsetAsync(deg, 0, (size_t)n * 4, stream);
    hipMemsetAsync(part, 0, 64 * 256 * 4, stream);

    const int* srcIdx = ei;
    const int* dstIdx = ei + E;
    const int nb = (n + 255) / 256;
    const int NB = (n + 31) / 32;  // 1563 buckets

    // fused prep: hist + x->bf16 + 3 weight packs
    const int histBlks = 512;
    const int nxb = (n * 32 + 255) / 256;
    prep_kernel<<<histBlks + nxb + 160, 256, 0, stream>>>(x, xb, n * 32, W1, w1p, W2, w2p,
                                                          Wres, wresp, dstIdx, E, deg, histBlks);

    scan_part<<<nb, 256, 0, stream>>>(deg, offs, bsum, n);
    scan_bsum<<<1, 256, 0, stream>>>(bsum, nb);
    scan_add<<<nb, 256, 0, stream>>>(offs, bsum, n, pairBase, bcur);

    // pass A: bin edges into 32-node buckets (L2-local appends)
    bin_kernel<<<(E + 4095) / 4096, 256, 0, stream>>>(srcIdx, dstIdx, E, bcur, pairBuf, NB);

    const int mt = (n + 15) / 16;   // 3125 row tiles
    const int gblk = (mt + 3) / 4;  // 782
    const int passBlks = 391;       // 1564 waves >= NB buckets

    // phase2: passB (bucket->csr scatter, LDS counters) + gemm1(+att1) + gemm_res
    phase2_kernel<<<passBlks + 2 * gblk, 256, 0, stream>>>(
        pairBuf, pairBase, bcur, offs, csr, NB, xb, w1p, h1b, asrc1, adst1, as1, ad1,
        wresp, bres, residb, n, passBlks, gblk);

    gat1_agg<<<(n + 3) / 4, 256, 0, stream>>>(h1b, as1, ad1, offs, csr, b1, out1b, n);
    gemm2_kernel<<<gblk, 256, 0, stream>>>(out1b, w2p, h2b, asrc2, adst2, as2, ad2, n);
    gat2_agg<<<(n + 3) / 4, 256, 0, stream>>>(h2b, as2, ad2, offs, csr, b2, out2b, part, n);
    bn_finalize<<<1, 128, 0, stream>>>(part, gamma, beta, ss, n);
    final_kernel<<<(n * 32 + 255) / 256, 256, 0, stream>>>(out2b, residb, ss, (float*)d_out, n);
}

// Round 11
// 191.397 us; speedup vs baseline: 3.2821x; 1.0214x over previous
//
#include <hip/hip_runtime.h>

#define NEG 0.2f
#define NEG_INF (-1e30f)

typedef __attribute__((ext_vector_type(8))) short bf16x8;
typedef __attribute__((ext_vector_type(4))) float f32x4;

__device__ __forceinline__ float leaky(float e) { return e > 0.f ? e : NEG * e; }

__device__ __forceinline__ unsigned short f2bf(float f) {
    unsigned int u = __float_as_uint(f);
    unsigned int r = u + 0x7fffu + ((u >> 16) & 1u);
    return (unsigned short)(r >> 16);
}
__device__ __forceinline__ float2 bf2f2(unsigned int u) {
    float2 r;
    r.x = __uint_as_float(u << 16);
    r.y = __uint_as_float(u & 0xffff0000u);
    return r;
}

// ---------------- fused prep: hist + x->bf16 + weight packing ----------------
__device__ __forceinline__ void pack_w(const float* __restrict__ W,
                                       unsigned short* __restrict__ Bp, int K, int N, int idx) {
    int i = idx & 7;
    int rest = idx >> 3;
    int lane = rest & 63;
    rest >>= 6;
    int KT = K / 32;
    int kt = rest % KT;
    int ct = rest / KT;
    int m = lane & 15, kb = lane >> 4;
    int k = kt * 32 + kb * 8 + i, col = ct * 16 + m;
    Bp[idx] = f2bf(W[(size_t)k * N + col]);
}

__global__ __launch_bounds__(256) void prep_kernel(const float* __restrict__ x,
                                                   unsigned short* __restrict__ xb, int n4,
                                                   const float* __restrict__ W1,
                                                   unsigned short* __restrict__ w1p,
                                                   const float* __restrict__ W2,
                                                   unsigned short* __restrict__ w2p,
                                                   const float* __restrict__ Wres,
                                                   unsigned short* __restrict__ wresp,
                                                   const int* __restrict__ dst, int E,
                                                   int* __restrict__ deg, int histBlks) {
    int b = blockIdx.x;
    if (b < histBlks) {
        for (int e = b * 256 + threadIdx.x; e < E; e += histBlks * 256)
            atomicAdd(&deg[dst[e]], 1);
        return;
    }
    b -= histBlks;
    int nxb = (n4 + 255) / 256;
    if (b < nxb) {
        int i = b * 256 + threadIdx.x;
        if (i < n4) {
            float4 v = ((const float4*)x)[i];
            ushort4 o;
            o.x = f2bf(v.x); o.y = f2bf(v.y); o.z = f2bf(v.z); o.w = f2bf(v.w);
            ((ushort4*)xb)[i] = o;
        }
        return;
    }
    b -= nxb;
    if (b < 48) { pack_w(W1, w1p, 128, 96, b * 256 + threadIdx.x); return; }
    b -= 48;
    if (b < 48) { pack_w(W2, w2p, 96, 128, b * 256 + threadIdx.x); return; }
    b -= 48;
    if (b < 64) { pack_w(Wres, wresp, 128, 128, b * 256 + threadIdx.x); }
}

// ---------------- scan chain ----------------
__global__ void scan_part(const int* __restrict__ deg, int* __restrict__ offs,
                          int* __restrict__ bsum, int n) {
    __shared__ int buf[256];
    int i = blockIdx.x * 256 + threadIdx.x;
    int v = (i < n) ? deg[i] : 0;
    buf[threadIdx.x] = v;
    __syncthreads();
    for (int s = 1; s < 256; s <<= 1) {
        int t = (threadIdx.x >= s) ? buf[threadIdx.x - s] : 0;
        __syncthreads();
        buf[threadIdx.x] += t;
        __syncthreads();
    }
    if (i < n) offs[i + 1] = buf[threadIdx.x];
    if (threadIdx.x == 255) bsum[blockIdx.x] = buf[255];
}

__global__ void scan_bsum(int* __restrict__ bsum, int nb) {
    __shared__ int buf[256];
    int v = (threadIdx.x < nb) ? bsum[threadIdx.x] : 0;
    buf[threadIdx.x] = v;
    __syncthreads();
    for (int s = 1; s < 256; s <<= 1) {
        int t = (threadIdx.x >= s) ? buf[threadIdx.x - s] : 0;
        __syncthreads();
        buf[threadIdx.x] += t;
        __syncthreads();
    }
    if (threadIdx.x < nb) bsum[threadIdx.x] = buf[threadIdx.x] - v;  // exclusive
}

// seeds per-bucket (32-node) pairBase/bcur
__global__ void scan_add(int* __restrict__ offs, const int* __restrict__ bsum, int n,
                         int* __restrict__ pairBase, int* __restrict__ bcur) {
    int i = blockIdx.x * 256 + threadIdx.x;
    if (i < n) {
        int v = offs[i + 1] + bsum[blockIdx.x];
        offs[i + 1] = v;
        if (((i + 1) & 31) == 0) {
            int b = (i + 1) >> 5;
            pairBase[b] = v;
            bcur[b] = v;
        }
    }
    if (i == 0) { offs[0] = 0; pairBase[0] = 0; bcur[0] = 0; }
}

// ---------------- binned edge pass A: LDS-staged bucket append ----------------
__global__ __launch_bounds__(256) void bin_kernel(const int* __restrict__ src,
                                                  const int* __restrict__ dst, int E,
                                                  int* __restrict__ bcur,
                                                  int2* __restrict__ pairBuf, int nb) {
    __shared__ int2 stage[4096];
    __shared__ int hist[1600];
    __shared__ int base[1600];
    for (int c0 = blockIdx.x * 4096; c0 < E; c0 += gridDim.x * 4096) {
        int cnt = min(4096, E - c0);
        for (int b = threadIdx.x; b < nb; b += 256) hist[b] = 0;
        __syncthreads();
        for (int i = threadIdx.x; i < cnt; i += 256) {
            int s = src[c0 + i], d = dst[c0 + i];
            stage[i] = make_int2(s, d);
            atomicAdd(&hist[d >> 5], 1);
        }
        __syncthreads();
        for (int b = threadIdx.x; b < nb; b += 256) {
            int h = hist[b];
            if (h) base[b] = atomicAdd(&bcur[b], h);
            hist[b] = 0;
        }
        __syncthreads();
        for (int i = threadIdx.x; i < cnt; i += 256) {
            int2 p = stage[i];
            int b = p.y >> 5;
            int off = atomicAdd(&hist[b], 1);
            pairBuf[base[b] + off] = p;
        }
        __syncthreads();
    }
}

// ---------------- MFMA GEMM body: one wave per 16-row tile, all col-tiles ----------------
template <int K, int N, int HEADS>
__device__ __forceinline__ void gemm_body(int w, const unsigned short* __restrict__ A,
                                          const unsigned short* __restrict__ Bp,
                                          const float* __restrict__ bias,
                                          unsigned short* __restrict__ outB,
                                          const float* __restrict__ asrc,
                                          const float* __restrict__ adst,
                                          float* __restrict__ a_s,
                                          float* __restrict__ a_d, int M) {
    constexpr int KT = K / 32, CT = N / 16;
    int row0 = w * 16;
    if (row0 >= M) return;
    int lane = threadIdx.x & 63;
    int m = lane & 15, kb = lane >> 4;
    const unsigned short* arow = A + (size_t)(row0 + m) * K + kb * 8;

    f32x4 acc[CT];
#pragma unroll
    for (int ct = 0; ct < CT; ++ct) acc[ct] = (f32x4){0.f, 0.f, 0.f, 0.f};

#pragma unroll
    for (int kt = 0; kt < KT; ++kt) {
        bf16x8 a = *(const bf16x8*)(arow + kt * 32);
#pragma unroll
        for (int ct = 0; ct < CT; ++ct) {
            bf16x8 b = *(const bf16x8*)(Bp + ((size_t)(ct * KT + kt) * 64 + lane) * 8);
            acc[ct] = __builtin_amdgcn_mfma_f32_16x16x32_bf16(a, b, acc[ct], 0, 0, 0);
        }
    }

#pragma unroll
    for (int r = 0; r < 4; ++r) {
        int row = row0 + kb * 4 + r;
#pragma unroll
        for (int ct = 0; ct < CT; ++ct) {
            int col = ct * 16 + m;
            float v = acc[ct][r] + (bias ? bias[col] : 0.f);
            outB[(size_t)row * N + col] = f2bf(v);
        }
    }

    if (HEADS > 0) {
        float asv[CT], adv[CT];
#pragma unroll
        for (int ct = 0; ct < CT; ++ct) {
            int col = ct * 16 + m;
            asv[ct] = asrc[col];
            adv[ct] = adst[col];
        }
        constexpr int TPH = CT / (HEADS > 0 ? HEADS : 1);
#pragma unroll
        for (int r = 0; r < 4; ++r) {
            int row = row0 + kb * 4 + r;
#pragma unroll
            for (int h = 0; h < HEADS; ++h) {
                float s = 0.f, d = 0.f;
#pragma unroll
                for (int t = 0; t < TPH; ++t) {
                    int ct = h * TPH + t;
                    s += acc[ct][r] * asv[ct];
                    d += acc[ct][r] * adv[ct];
                }
#pragma unroll
                for (int off = 1; off <= 8; off <<= 1) {
                    s += __shfl_xor(s, off);
                    d += __shfl_xor(d, off);
                }
                if (m == 0) {
                    a_s[(size_t)row * HEADS + h] = s;
                    a_d[(size_t)row * HEADS + h] = d;
                }
            }
        }
    }
}

// ---------------- phase2: passB (LDS-counter bucket scatter) + gemm1 + gemm_res ----------------
__global__ __launch_bounds__(256) void phase2_kernel(
    const int2* __restrict__ pairBuf, const int* __restrict__ pairBase,
    const int* __restrict__ bcur, const int* __restrict__ offs,
    int* __restrict__ csr, int nb,
    const unsigned short* __restrict__ xb,
    const unsigned short* __restrict__ w1p, unsigned short* __restrict__ h1b,
    const float* __restrict__ asrc1, const float* __restrict__ adst1,
    float* __restrict__ as1, float* __restrict__ ad1,
    const unsigned short* __restrict__ wresp, const float* __restrict__ bres,
    unsigned short* __restrict__ residb, int n, int passBlks, int g1Blks) {
    int b = blockIdx.x;
    int lane = threadIdx.x & 63;
    int wid = threadIdx.x >> 6;
    if (b < passBlks) {
        __shared__ int cnt[4][32];
        int bk = b * 4 + wid;  // one bucket per wave
        if (bk < nb) {
            int node0 = bk * 32;
            if (lane < 32) cnt[wid][lane] = (node0 + lane < n) ? offs[node0 + lane] : 0;
            int lo = pairBase[bk], hi = bcur[bk];
            for (int i = lo + lane; i < hi; i += 64) {
                int2 p = pairBuf[i];
                int pos = atomicAdd(&cnt[wid][p.y & 31], 1);  // LDS atomic
                csr[pos] = p.x;
            }
        }
        return;
    }
    b -= passBlks;
    if (b < g1Blks) {
        gemm_body<128, 96, 3>(b * 4 + wid, xb, w1p, nullptr, h1b,
                              asrc1, adst1, as1, ad1, n);
        return;
    }
    b -= g1Blks;
    gemm_body<128, 128, 0>(b * 4 + wid, xb, wresp, bres, residb,
                           nullptr, nullptr, nullptr, nullptr, n);
}

// gemm2 standalone wrapper
__global__ __launch_bounds__(256) void gemm2_kernel(const unsigned short* __restrict__ A,
                                                    const unsigned short* __restrict__ Bp,
                                                    unsigned short* __restrict__ outB,
                                                    const float* __restrict__ asrc,
                                                    const float* __restrict__ adst,
                                                    float* __restrict__ a_s,
                                                    float* __restrict__ a_d, int M) {
    gemm_body<96, 128, 1>(blockIdx.x * 4 + (threadIdx.x >> 6), A, Bp, nullptr, outB,
                          asrc, adst, a_s, a_d, M);
}

// ---------------- GAT aggregation: 8-wide gather MLP ----------------
__global__ __launch_bounds__(256) void gat1_agg(const unsigned short* __restrict__ h1b,
                                                const float* __restrict__ a_s,
                                                const float* __restrict__ a_d,
                                                const int* __restrict__ offs,
                                                const int* __restrict__ csr,
                                                const float* __restrict__ b1,
                                                unsigned short* __restrict__ out1b, int n) {
    __shared__ int ssrc[4][64];
    __shared__ float se[4][3][64];
    int wid = threadIdx.x >> 6;
    int node = blockIdx.x * 4 + wid;
    if (node >= n) return;
    int lane = threadIdx.x & 63;
    int head = lane >> 4; if (head > 2) head = 2;
    int beg = offs[node], end = offs[node + 1];
    int deg = end - beg;
    float ad0 = a_d[node * 3 + 0], ad1 = a_d[node * 3 + 1], ad2 = a_d[node * 3 + 2];
    float es0 = leaky(a_s[node * 3 + 0] + ad0);
    float es1 = leaky(a_s[node * 3 + 1] + ad1);
    float es2 = leaky(a_s[node * 3 + 2] + ad2);
    float2 hv0 = make_float2(0.f, 0.f);
    if (lane < 48) hv0 = bf2f2(*(const unsigned int*)&h1b[(size_t)node * 96 + 2 * lane]);

    float den;
    float2 acc;

    if (deg <= 64) {
        int s = 0;
        float l0 = NEG_INF, l1 = NEG_INF, l2 = NEG_INF;
        if (lane < deg) {
            s = csr[beg + lane];
            l0 = leaky(a_s[s * 3 + 0] + ad0);
            l1 = leaky(a_s[s * 3 + 1] + ad1);
            l2 = leaky(a_s[s * 3 + 2] + ad2);
        }
        float m0 = l0, m1 = l1, m2 = l2;
#pragma unroll
        for (int sh = 32; sh >= 1; sh >>= 1) {
            m0 = fmaxf(m0, __shfl_xor(m0, sh));
            m1 = fmaxf(m1, __shfl_xor(m1, sh));
            m2 = fmaxf(m2, __shfl_xor(m2, sh));
        }
        m0 = fmaxf(m0, es0); m1 = fmaxf(m1, es1); m2 = fmaxf(m2, es2);
        float e0 = 0.f, e1 = 0.f, e2 = 0.f;
        if (lane < deg) {
            e0 = __expf(l0 - m0); e1 = __expf(l1 - m1); e2 = __expf(l2 - m2);
        }
        ssrc[wid][lane] = s;
        se[wid][0][lane] = e0; se[wid][1][lane] = e1; se[wid][2][lane] = e2;
        float w0 = __expf(es0 - m0), w1 = __expf(es1 - m1), w2 = __expf(es2 - m2);
        den = (head == 0) ? w0 : ((head == 1) ? w1 : w2);
        float wSelf = (lane < 16) ? w0 : ((lane < 32) ? w1 : w2);
        acc.x = wSelf * hv0.x; acc.y = wSelf * hv0.y;

        int jj = 0;
        for (; jj + 7 < deg; jj += 8) {
            int sA[8]; float wA[8]; unsigned ph[8];
#pragma unroll
            for (int q = 0; q < 8; ++q) {
                sA[q] = ssrc[wid][jj + q];
                wA[q] = se[wid][head][jj + q];
            }
#pragma unroll
            for (int q = 0; q < 8; ++q)
                ph[q] = (lane < 48) ? *(const unsigned*)&h1b[(size_t)sA[q] * 96 + 2 * lane] : 0u;
            float dsum = 0.f;
#pragma unroll
            for (int q = 0; q < 8; ++q) {
                dsum += wA[q];
                if (lane < 48) {
                    float2 h = bf2f2(ph[q]);
                    acc.x += wA[q] * h.x; acc.y += wA[q] * h.y;
                }
            }
            den += dsum;
        }
        for (; jj + 3 < deg; jj += 4) {
            int sA[4]; float wA[4]; unsigned ph[4];
#pragma unroll
            for (int q = 0; q < 4; ++q) {
                sA[q] = ssrc[wid][jj + q];
                wA[q] = se[wid][head][jj + q];
            }
#pragma unroll
            for (int q = 0; q < 4; ++q)
                ph[q] = (lane < 48) ? *(const unsigned*)&h1b[(size_t)sA[q] * 96 + 2 * lane] : 0u;
            float dsum = 0.f;
#pragma unroll
            for (int q = 0; q < 4; ++q) {
                dsum += wA[q];
                if (lane < 48) {
                    float2 h = bf2f2(ph[q]);
                    acc.x += wA[q] * h.x; acc.y += wA[q] * h.y;
                }
            }
            den += dsum;
        }
        for (; jj < deg; ++jj) {
            int sA = ssrc[wid][jj];
            float wA = se[wid][head][jj];
            den += wA;
            if (lane < 48) {
                float2 ha = bf2f2(*(const unsigned*)&h1b[(size_t)sA * 96 + 2 * lane]);
                acc.x += wA * ha.x; acc.y += wA * ha.y;
            }
        }
    } else {
        float m0 = es0, m1 = es1, m2 = es2;
        for (int j = beg + lane; j < end; j += 64) {
            int s = csr[j];
            m0 = fmaxf(m0, leaky(a_s[s * 3 + 0] + ad0));
            m1 = fmaxf(m1, leaky(a_s[s * 3 + 1] + ad1));
            m2 = fmaxf(m2, leaky(a_s[s * 3 + 2] + ad2));
        }
#pragma unroll
        for (int sh = 32; sh >= 1; sh >>= 1) {
            m0 = fmaxf(m0, __shfl_xor(m0, sh));
            m1 = fmaxf(m1, __shfl_xor(m1, sh));
            m2 = fmaxf(m2, __shfl_xor(m2, sh));
        }
        float w0 = __expf(es0 - m0), w1 = __expf(es1 - m1), w2 = __expf(es2 - m2);
        den = (head == 0) ? w0 : ((head == 1) ? w1 : w2);
        float wSelf = (lane < 16) ? w0 : ((lane < 32) ? w1 : w2);
        acc.x = wSelf * hv0.x; acc.y = wSelf * hv0.y;
        for (int t0 = beg; t0 < end; t0 += 64) {
            int cnt = min(64, end - t0);
            int s = 0;
            float e0 = 0.f, e1 = 0.f, e2 = 0.f;
            if (lane < cnt) {
                s = csr[t0 + lane];
                e0 = __expf(leaky(a_s[s * 3 + 0] + ad0) - m0);
                e1 = __expf(leaky(a_s[s * 3 + 1] + ad1) - m1);
                e2 = __expf(leaky(a_s[s * 3 + 2] + ad2) - m2);
            }
            ssrc[wid][lane] = s;
            se[wid][0][lane] = e0; se[wid][1][lane] = e1; se[wid][2][lane] = e2;
            int jj = 0;
            for (; jj + 7 < cnt; jj += 8) {
                int sA[8]; float wA[8]; unsigned ph[8];
#pragma unroll
                for (int q = 0; q < 8; ++q) {
                    sA[q] = ssrc[wid][jj + q];
                    wA[q] = se[wid][head][jj + q];
                }
#pragma unroll
                for (int q = 0; q < 8; ++q)
                    ph[q] = (lane < 48) ? *(const unsigned*)&h1b[(size_t)sA[q] * 96 + 2 * lane] : 0u;
                float dsum = 0.f;
#pragma unroll
                for (int q = 0; q < 8; ++q) {
                    dsum += wA[q];
                    if (lane < 48) {
                        float2 h = bf2f2(ph[q]);
                        acc.x += wA[q] * h.x; acc.y += wA[q] * h.y;
                    }
                }
                den += dsum;
            }
            for (; jj < cnt; ++jj) {
                int sA = ssrc[wid][jj];
                float wA = se[wid][head][jj];
                den += wA;
                if (lane < 48) {
                    float2 ha = bf2f2(*(const unsigned*)&h1b[(size_t)sA * 96 + 2 * lane]);
                    acc.x += wA * ha.x; acc.y += wA * ha.y;
                }
            }
        }
    }

    if (lane < 48) {
        float inv = 1.f / (den + 1e-16f);
        ushort2 o;
        o.x = f2bf(acc.x * inv + b1[2 * lane]);
        o.y = f2bf(acc.y * inv + b1[2 * lane + 1]);
        *(ushort2*)&out1b[(size_t)node * 96 + 2 * lane] = o;
    }
}

// gat2: 128 ch, 1 head; writes bf16 out2 AND accumulates BN partial sums.
__global__ __launch_bounds__(256) void gat2_agg(const unsigned short* __restrict__ h2b,
                                                const float* __restrict__ a_s,
                                                const float* __restrict__ a_d,
                                                const int* __restrict__ offs,
                                                const int* __restrict__ csr,
                                                const float* __restrict__ b2,
                                                unsigned short* __restrict__ out2b,
                                                float* __restrict__ part, int n) {
    __shared__ int ssrc[4][64];
    __shared__ float se[4][64];
    __shared__ float4 red[4][64];
    int wid = threadIdx.x >> 6;
    int node = blockIdx.x * 4 + wid;
    int lane = threadIdx.x & 63;
    float2 o = make_float2(0.f, 0.f);

    if (node < n) {
        int beg = offs[node], end = offs[node + 1];
        int deg = end - beg;
        float ad = a_d[node];
        float es = leaky(a_s[node] + ad);
        float2 hv0 = bf2f2(*(const unsigned int*)&h2b[(size_t)node * 128 + 2 * lane]);
        float den;
        float2 acc;

        if (deg <= 64) {
            int s = 0;
            float l = NEG_INF;
            if (lane < deg) {
                s = csr[beg + lane];
                l = leaky(a_s[s] + ad);
            }
            float m = l;
#pragma unroll
            for (int sh = 32; sh >= 1; sh >>= 1) m = fmaxf(m, __shfl_xor(m, sh));
            m = fmaxf(m, es);
            float e = (lane < deg) ? __expf(l - m) : 0.f;
            ssrc[wid][lane] = s;
            se[wid][lane] = e;
            float wSelf = __expf(es - m);
            den = wSelf;
            acc.x = wSelf * hv0.x; acc.y = wSelf * hv0.y;

            int jj = 0;
            for (; jj + 7 < deg; jj += 8) {
                int sA[8]; float wA[8]; unsigned ph[8];
#pragma unroll
                for (int q = 0; q < 8; ++q) {
                    sA[q] = ssrc[wid][jj + q];
                    wA[q] = se[wid][jj + q];
                }
#pragma unroll
                for (int q = 0; q < 8; ++q)
                    ph[q] = *(const unsigned*)&h2b[(size_t)sA[q] * 128 + 2 * lane];
                float dsum = 0.f;
#pragma unroll
                for (int q = 0; q < 8; ++q) {
                    dsum += wA[q];
                    float2 h = bf2f2(ph[q]);
                    acc.x += wA[q] * h.x; acc.y += wA[q] * h.y;
                }
                den += dsum;
            }
            for (; jj + 3 < deg; jj += 4) {
                int sA[4]; float wA[4]; unsigned ph[4];
#pragma unroll
                for (int q = 0; q < 4; ++q) {
                    sA[q] = ssrc[wid][jj + q];
                    wA[q] = se[wid][jj + q];
                }
#pragma unroll
                for (int q = 0; q < 4; ++q)
                    ph[q] = *(const unsigned*)&h2b[(size_t)sA[q] * 128 + 2 * lane];
                float dsum = 0.f;
#pragma unroll
                for (int q = 0; q < 4; ++q) {
                    dsum += wA[q];
                    float2 h = bf2f2(ph[q]);
                    acc.x += wA[q] * h.x; acc.y += wA[q] * h.y;
                }
                den += dsum;
            }
            for (; jj < deg; ++jj) {
                int sA = ssrc[wid][jj];
                float wA = se[wid][jj];
                den += wA;
                float2 ha = bf2f2(*(const unsigned*)&h2b[(size_t)sA * 128 + 2 * lane]);
                acc.x += wA * ha.x; acc.y += wA * ha.y;
            }
        } else {
            float m = es;
            for (int j = beg + lane; j < end; j += 64) {
                int s = csr[j];
                m = fmaxf(m, leaky(a_s[s] + ad));
            }
#pragma unroll
            for (int sh = 32; sh >= 1; sh >>= 1) m = fmaxf(m, __shfl_xor(m, sh));
            float wSelf = __expf(es - m);
            den = wSelf;
            acc.x = wSelf * hv0.x; acc.y = wSelf * hv0.y;
            for (int t0 = beg; t0 < end; t0 += 64) {
                int cnt = min(64, end - t0);
                int s = 0;
                float e = 0.f;
                if (lane < cnt) {
                    s = csr[t0 + lane];
                    e = __expf(leaky(a_s[s] + ad) - m);
                }
                ssrc[wid][lane] = s;
                se[wid][lane] = e;
                int jj = 0;
                for (; jj + 7 < cnt; jj += 8) {
                    int sA[8]; float wA[8]; unsigned ph[8];
#pragma unroll
                    for (int q = 0; q < 8; ++q) {
                        sA[q] = ssrc[wid][jj + q];
                        wA[q] = se[wid][jj + q];
                    }
#pragma unroll
                    for (int q = 0; q < 8; ++q)
                        ph[q] = *(const unsigned*)&h2b[(size_t)sA[q] * 128 + 2 * lane];
                    float dsum = 0.f;
#pragma unroll
                    for (int q = 0; q < 8; ++q) {
                        dsum += wA[q];
                        float2 h = bf2f2(ph[q]);
                        acc.x += wA[q] * h.x; acc.y += wA[q] * h.y;
                    }
                    den += dsum;
                }
                for (; jj < cnt; ++jj) {
                    int sA = ssrc[wid][jj];
                    float wA = se[wid][jj];
                    den += wA;
                    float2 ha = bf2f2(*(const unsigned*)&h2b[(size_t)sA * 128 + 2 * lane]);
                    acc.x += wA * ha.x; acc.y += wA * ha.y;
                }
            }
        }

        float inv = 1.f / (den + 1e-16f);
        o.x = acc.x * inv + b2[2 * lane];
        o.y = acc.y * inv + b2[2 * lane + 1];
        ushort2 ob;
        ob.x = f2bf(o.x); ob.y = f2bf(o.y);
        *(ushort2*)&out2b[(size_t)node * 128 + 2 * lane] = ob;
    }

    // ---- block-level BN partial reduction ----
    red[wid][lane] = make_float4(o.x, o.y, o.x * o.x, o.y * o.y);
    __syncthreads();
    if (wid == 0) {
        float4 a = red[0][lane], b = red[1][lane], c = red[2][lane], d = red[3][lane];
        float sx = a.x + b.x + c.x + d.x;
        float sy = a.y + b.y + c.y + d.y;
        float qx = a.z + b.z + c.z + d.z;
        float qy = a.w + b.w + c.w + d.w;
        float* p = part + (size_t)(blockIdx.x & 63) * 256;
        atomicAdd(&p[2 * lane + 0], sx);
        atomicAdd(&p[2 * lane + 1], sy);
        atomicAdd(&p[128 + 2 * lane + 0], qx);
        atomicAdd(&p[128 + 2 * lane + 1], qy);
    }
}

// ---------------- BN finalize ----------------
__global__ void bn_finalize(const float* __restrict__ part, const float* __restrict__ gamma,
                            const float* __restrict__ beta, float* __restrict__ ss, int n) {
    int c = threadIdx.x;  // 128
    float S = 0.f, Q = 0.f;
    for (int k = 0; k < 64; ++k) {
        S += part[(size_t)k * 256 + c];
        Q += part[(size_t)k * 256 + 128 + c];
    }
    float invN = 1.f / (float)n;
    float mu = S * invN;
    float var = Q * invN - mu * mu;
    float g = gamma[c] * rsqrtf(var + 1e-5f);
    ss[c] = g;
    ss[128 + c] = beta[c] - mu * g;
}

// ---------------- fused BN-normalize + ReLU + residual ----------------
__global__ void final_kernel(const unsigned short* __restrict__ out2b,
                             const unsigned short* __restrict__ residb,
                             const float* __restrict__ ss, float* __restrict__ out, int n) {
    int i = blockIdx.x * blockDim.x + threadIdx.x;  // over n*32 groups of 4 ch
    if (i >= n * 32) return;
    int c0 = (i & 31) * 4;
    uint2 v = ((const uint2*)out2b)[i];
    uint2 r = ((const uint2*)residb)[i];
    float2 v01 = bf2f2(v.x), v23 = bf2f2(v.y);
    float2 r01 = bf2f2(r.x), r23 = bf2f2(r.y);
    float4 o;
    o.x = fmaxf(v01.x * ss[c0 + 0] + ss[128 + c0 + 0], 0.f) + r01.x;
    o.y = fmaxf(v01.y * ss[c0 + 1] + ss[128 + c0 + 1], 0.f) + r01.y;
    o.z = fmaxf(v23.x * ss[c0 + 2] + ss[128 + c0 + 2], 0.f) + r23.x;
    o.w = fmaxf(v23.y * ss[c0 + 3] + ss[128 + c0 + 3], 0.f) + r23.y;
    ((float4*)out)[i] = o;
}

extern "C" void kernel_launch(void* const* d_in, const int* in_sizes, int n_in,
                              void* d_out, int out_size, void* d_ws, size_t ws_size,
                              hipStream_t stream) {
    const float* x     = (const float*)d_in[0];
    const int*   ei    = (const int*)d_in[1];
    const float* W1    = (const float*)d_in[2];
    const float* asrc1 = (const float*)d_in[3];
    const float* adst1 = (const float*)d_in[4];
    const float* b1    = (const float*)d_in[5];
    const float* W2    = (const float*)d_in[6];
    const float* asrc2 = (const float*)d_in[7];
    const float* adst2 = (const float*)d_in[8];
    const float* b2    = (const float*)d_in[9];
    const float* gamma = (const float*)d_in[10];
    const float* beta  = (const float*)d_in[11];
    const float* Wres  = (const float*)d_in[12];
    const float* bres  = (const float*)d_in[13];

    const int n = in_sizes[0] / 128;  // 50000
    const int E = in_sizes[1] / 2;    // 800000

    char* ws = (char*)d_ws;
    size_t off = 0;
    auto alloc = [&](size_t bytes) {
        void* p = ws + off;
        off = (off + bytes + 255) & ~(size_t)255;
        return p;
    };
    float* as1  = (float*)alloc((size_t)n * 3 * 4);
    float* ad1  = (float*)alloc((size_t)n * 3 * 4);
    float* as2  = (float*)alloc((size_t)n * 4);
    float* ad2  = (float*)alloc((size_t)n * 4);
    float* part = (float*)alloc(64 * 256 * 4);
    float* ss   = (float*)alloc(256 * 4);
    unsigned short* xb     = (unsigned short*)alloc((size_t)n * 128 * 2);
    unsigned short* h1b    = (unsigned short*)alloc((size_t)n * 96 * 2);
    unsigned short* h2b    = (unsigned short*)alloc((size_t)n * 128 * 2);
    unsigned short* out1b  = (unsigned short*)alloc((size_t)n * 96 * 2);
    unsigned short* out2b  = (unsigned short*)alloc((size_t)n * 128 * 2);
    unsigned short* residb = (unsigned short*)alloc((size_t)n * 128 * 2);
    unsigned short* w1p    = (unsigned short*)alloc(128 * 96 * 2);
    unsigned short* w2p    = (unsigned short*)alloc(96 * 128 * 2);
    unsigned short* wresp  = (unsigned short*)alloc(128 * 128 * 2);
    int* deg      = (int*)alloc((size_t)n * 4);
    int* offs     = (int*)alloc((size_t)(n + 1) * 4);
    int* bsum     = (int*)alloc(256 * 4);
    int* pairBase = (int*)alloc(1600 * 4);
    int* bcur     = (int*)alloc(1600 * 4);
    int2* pairBuf = (int2*)alloc((size_t)E * 8);
    int* csr      = (int*)alloc((size_t)E * 4);

    hipMemsetAsync(deg, 0, (size_t)n * 4, stream);
    hipMemsetAsync(part, 0, 64 * 256 * 4, stream);

    const int* srcIdx = ei;
    const int* dstIdx = ei + E;
    const int nb = (n + 255) / 256;
    const int NB = (n + 31) / 32;  // 1563 buckets

    // fused prep: hist + x->bf16 + 3 weight packs
    const int histBlks = 512;
    const int nxb = (n * 32 + 255) / 256;
    prep_kernel<<<histBlks + nxb + 160, 256, 0, stream>>>(x, xb, n * 32, W1, w1p, W2, w2p,
                                                          Wres, wresp, dstIdx, E, deg, histBlks);

    scan_part<<<nb, 256, 0, stream>>>(deg, offs, bsum, n);
    scan_bsum<<<1, 256, 0, stream>>>(bsum, nb);
    scan_add<<<nb, 256, 0, stream>>>(offs, bsum, n, pairBase, bcur);

    // pass A: bin edges into 32-node buckets (L2-local appends)
    bin_kernel<<<(E + 4095) / 4096, 256, 0, stream>>>(srcIdx, dstIdx, E, bcur, pairBuf, NB);

    const int mt = (n + 15) / 16;   // 3125 row tiles
    const int gblk = (mt + 3) / 4;  // 782
    const int passBlks = 391;       // 1564 waves >= NB buckets

    // phase2: passB (bucket->csr scatter, LDS counters) + gemm1(+att1) + gemm_res
    phase2_kernel<<<passBlks + 2 * gblk, 256, 0, stream>>>(
        pairBuf, pairBase, bcur, offs, csr, NB, xb, w1p, h1b, asrc1, adst1, as1, ad1,
        wresp, bres, residb, n, passBlks, gblk);

    gat1_agg<<<(n + 3) / 4, 256, 0, stream>>>(h1b, as1, ad1, offs, csr, b1, out1b, n);
    gemm2_kernel<<<gblk, 256, 0, stream>>>(out1b, w2p, h2b, asrc2, adst2, as2, ad2, n);
    gat2_agg<<<(n + 3) / 4, 256, 0, stream>>>(h2b, as2, ad2, offs, csr, b2, out2b, part, n);
    bn_finalize<<<1, 128, 0, stream>>>(part, gamma, beta, ss, n);
    final_kernel<<<(n * 32 + 255) / 256, 256, 0, stream>>>(out2b, residb, ss, (float*)d_out, n);
}

// Round 12
// 164.914 us; speedup vs baseline: 3.8092x; 1.1606x over previous
//
#include <hip/hip_runtime.h>

#define NEG 0.2f
#define NEG_INF (-1e30f)

typedef __attribute__((ext_vector_type(8))) short bf16x8;
typedef __attribute__((ext_vector_type(4))) float f32x4;

__device__ __forceinline__ float leaky(float e) { return e > 0.f ? e : NEG * e; }

__device__ __forceinline__ unsigned short f2bf(float f) {
    unsigned int u = __float_as_uint(f);
    unsigned int r = u + 0x7fffu + ((u >> 16) & 1u);
    return (unsigned short)(r >> 16);
}
__device__ __forceinline__ float2 bf2f2(unsigned int u) {
    float2 r;
    r.x = __uint_as_float(u << 16);
    r.y = __uint_as_float(u & 0xffff0000u);
    return r;
}

// ---------------- fused prep: bucket-hist + x->bf16 + weight packing ----------------
__device__ __forceinline__ void pack_w(const float* __restrict__ W,
                                       unsigned short* __restrict__ Bp, int K, int N, int idx) {
    int i = idx & 7;
    int rest = idx >> 3;
    int lane = rest & 63;
    rest >>= 6;
    int KT = K / 32;
    int kt = rest % KT;
    int ct = rest / KT;
    int m = lane & 15, kb = lane >> 4;
    int k = kt * 32 + kb * 8 + i, col = ct * 16 + m;
    Bp[idx] = f2bf(W[(size_t)k * N + col]);
}

__global__ __launch_bounds__(256) void prep_kernel(const float* __restrict__ x,
                                                   unsigned short* __restrict__ xb, int n4,
                                                   const float* __restrict__ W1,
                                                   unsigned short* __restrict__ w1p,
                                                   const float* __restrict__ W2,
                                                   unsigned short* __restrict__ w2p,
                                                   const float* __restrict__ Wres,
                                                   unsigned short* __restrict__ wresp,
                                                   const int* __restrict__ dst, int E,
                                                   int* __restrict__ bucketCnt, int nbk,
                                                   int binBlks) {
    int b = blockIdx.x;
    if (b < binBlks) {
        // bucket-level histogram: one 4096-edge chunk per block, LDS-aggregated
        __shared__ int hist[1600];
        for (int k = threadIdx.x; k < nbk; k += 256) hist[k] = 0;
        __syncthreads();
        int c0 = b * 4096;
        int cnt = min(4096, E - c0);
        for (int i = threadIdx.x; i < cnt; i += 256)
            atomicAdd(&hist[dst[c0 + i] >> 5], 1);
        __syncthreads();
        for (int k = threadIdx.x; k < nbk; k += 256) {
            int h = hist[k];
            if (h) atomicAdd(&bucketCnt[k], h);
        }
        return;
    }
    b -= binBlks;
    int nxb = (n4 + 255) / 256;
    if (b < nxb) {
        int i = b * 256 + threadIdx.x;
        if (i < n4) {
            float4 v = ((const float4*)x)[i];
            ushort4 o;
            o.x = f2bf(v.x); o.y = f2bf(v.y); o.z = f2bf(v.z); o.w = f2bf(v.w);
            ((ushort4*)xb)[i] = o;
        }
        return;
    }
    b -= nxb;
    if (b < 48) { pack_w(W1, w1p, 128, 96, b * 256 + threadIdx.x); return; }
    b -= 48;
    if (b < 48) { pack_w(W2, w2p, 96, 128, b * 256 + threadIdx.x); return; }
    b -= 48;
    if (b < 64) { pack_w(Wres, wresp, 128, 128, b * 256 + threadIdx.x); }
}

// ---------------- bucket scan (1563 elements, one block) ----------------
__global__ __launch_bounds__(1024) void scan_buckets(const int* __restrict__ bc,
                                                     int* __restrict__ pairBase,
                                                     int* __restrict__ bcur,
                                                     int* __restrict__ offs, int nbk, int n) {
    __shared__ int buf[1024];
    __shared__ int carry;
    int tid = threadIdx.x;
    if (tid == 0) carry = 0;
    __syncthreads();
    for (int base = 0; base < nbk; base += 1024) {
        int v = (base + tid < nbk) ? bc[base + tid] : 0;
        buf[tid] = v;
        __syncthreads();
        for (int s = 1; s < 1024; s <<= 1) {
            int t = (tid >= s) ? buf[tid - s] : 0;
            __syncthreads();
            buf[tid] += t;
            __syncthreads();
        }
        int incl = buf[tid];
        int tot = buf[1023];
        int c = carry;
        if (base + tid < nbk) {
            int ex = c + incl - v;  // exclusive prefix
            pairBase[base + tid] = ex;
            bcur[base + tid] = ex;
        }
        __syncthreads();
        if (tid == 0) carry = c + tot;
        __syncthreads();
    }
    if (tid == 0) {
        pairBase[nbk] = carry;
        offs[n] = carry;  // = E
    }
}

// ---------------- binned edge pass: LDS-staged bucket append ----------------
__global__ __launch_bounds__(256) void bin_kernel(const int* __restrict__ src,
                                                  const int* __restrict__ dst, int E,
                                                  int* __restrict__ bcur,
                                                  int2* __restrict__ pairBuf, int nb) {
    __shared__ int2 stage[4096];
    __shared__ int hist[1600];
    __shared__ int base[1600];
    for (int c0 = blockIdx.x * 4096; c0 < E; c0 += gridDim.x * 4096) {
        int cnt = min(4096, E - c0);
        for (int b = threadIdx.x; b < nb; b += 256) hist[b] = 0;
        __syncthreads();
        for (int i = threadIdx.x; i < cnt; i += 256) {
            int s = src[c0 + i], d = dst[c0 + i];
            stage[i] = make_int2(s, d);
            atomicAdd(&hist[d >> 5], 1);
        }
        __syncthreads();
        for (int b = threadIdx.x; b < nb; b += 256) {
            int h = hist[b];
            if (h) base[b] = atomicAdd(&bcur[b], h);
            hist[b] = 0;
        }
        __syncthreads();
        for (int i = threadIdx.x; i < cnt; i += 256) {
            int2 p = stage[i];
            int b = p.y >> 5;
            int off = atomicAdd(&hist[b], 1);
            pairBuf[base[b] + off] = p;
        }
        __syncthreads();
    }
}

// ---------------- MFMA GEMM body: one wave per 16-row tile, all col-tiles ----------------
template <int K, int N, int HEADS>
__device__ __forceinline__ void gemm_body(int w, const unsigned short* __restrict__ A,
                                          const unsigned short* __restrict__ Bp,
                                          const float* __restrict__ bias,
                                          unsigned short* __restrict__ outB,
                                          const float* __restrict__ asrc,
                                          const float* __restrict__ adst,
                                          float* __restrict__ a_s,
                                          float* __restrict__ a_d, int M) {
    constexpr int KT = K / 32, CT = N / 16;
    int row0 = w * 16;
    if (row0 >= M) return;
    int lane = threadIdx.x & 63;
    int m = lane & 15, kb = lane >> 4;
    const unsigned short* arow = A + (size_t)(row0 + m) * K + kb * 8;

    f32x4 acc[CT];
#pragma unroll
    for (int ct = 0; ct < CT; ++ct) acc[ct] = (f32x4){0.f, 0.f, 0.f, 0.f};

#pragma unroll
    for (int kt = 0; kt < KT; ++kt) {
        bf16x8 a = *(const bf16x8*)(arow + kt * 32);
#pragma unroll
        for (int ct = 0; ct < CT; ++ct) {
            bf16x8 b = *(const bf16x8*)(Bp + ((size_t)(ct * KT + kt) * 64 + lane) * 8);
            acc[ct] = __builtin_amdgcn_mfma_f32_16x16x32_bf16(a, b, acc[ct], 0, 0, 0);
        }
    }

#pragma unroll
    for (int r = 0; r < 4; ++r) {
        int row = row0 + kb * 4 + r;
#pragma unroll
        for (int ct = 0; ct < CT; ++ct) {
            int col = ct * 16 + m;
            float v = acc[ct][r] + (bias ? bias[col] : 0.f);
            outB[(size_t)row * N + col] = f2bf(v);
        }
    }

    if (HEADS > 0) {
        float asv[CT], adv[CT];
#pragma unroll
        for (int ct = 0; ct < CT; ++ct) {
            int col = ct * 16 + m;
            asv[ct] = asrc[col];
            adv[ct] = adst[col];
        }
        constexpr int TPH = CT / (HEADS > 0 ? HEADS : 1);
#pragma unroll
        for (int r = 0; r < 4; ++r) {
            int row = row0 + kb * 4 + r;
#pragma unroll
            for (int h = 0; h < HEADS; ++h) {
                float s = 0.f, d = 0.f;
#pragma unroll
                for (int t = 0; t < TPH; ++t) {
                    int ct = h * TPH + t;
                    s += acc[ct][r] * asv[ct];
                    d += acc[ct][r] * adv[ct];
                }
#pragma unroll
                for (int off = 1; off <= 8; off <<= 1) {
                    s += __shfl_xor(s, off);
                    d += __shfl_xor(d, off);
                }
                if (m == 0) {
                    a_s[(size_t)row * HEADS + h] = s;
                    a_d[(size_t)row * HEADS + h] = d;
                }
            }
        }
    }
}

// ---------------- phase2: passB (degree-count + offs + scatter) + gemm1 + gemm_res ----------------
__global__ __launch_bounds__(256) void phase2_kernel(
    const int2* __restrict__ pairBuf, const int* __restrict__ pairBase,
    const int* __restrict__ bcur, int* __restrict__ offs,
    int* __restrict__ csr, int nb,
    const unsigned short* __restrict__ xb,
    const unsigned short* __restrict__ w1p, unsigned short* __restrict__ h1b,
    const float* __restrict__ asrc1, const float* __restrict__ adst1,
    float* __restrict__ as1, float* __restrict__ ad1,
    const unsigned short* __restrict__ wresp, const float* __restrict__ bres,
    unsigned short* __restrict__ residb, int n, int passBlks, int g1Blks) {
    int b = blockIdx.x;
    int lane = threadIdx.x & 63;
    int wid = threadIdx.x >> 6;
    if (b < passBlks) {
        __shared__ int cnt[4][32];
        int bk = b * 4 + wid;  // one bucket per wave
        if (bk < nb) {
            int node0 = bk * 32;
            int lo = pairBase[bk], hi = bcur[bk];
            if (lane < 32) cnt[wid][lane] = 0;
            // pass 1: per-node degree count (LDS atomics, intra-wave)
            for (int i = lo + lane; i < hi; i += 64)
                atomicAdd(&cnt[wid][pairBuf[i].y & 31], 1);
            // 32-lane inclusive prefix scan of counts
            int myc = (lane < 32) ? cnt[wid][lane] : 0;
            int c = myc;
#pragma unroll
            for (int s = 1; s < 32; s <<= 1) {
                int t = __shfl_up(c, s);
                if (lane >= s && lane < 32) c += t;
            }
            int basePos = lo + c - myc;  // exclusive
            if (lane < 32) {
                if (node0 + lane < n) offs[node0 + lane] = basePos;
                cnt[wid][lane] = basePos;
            }
            // pass 2: scatter
            for (int i = lo + lane; i < hi; i += 64) {
                int2 p = pairBuf[i];
                int pos = atomicAdd(&cnt[wid][p.y & 31], 1);
                csr[pos] = p.x;
            }
        }
        return;
    }
    b -= passBlks;
    if (b < g1Blks) {
        gemm_body<128, 96, 3>(b * 4 + wid, xb, w1p, nullptr, h1b,
                              asrc1, adst1, as1, ad1, n);
        return;
    }
    b -= g1Blks;
    gemm_body<128, 128, 0>(b * 4 + wid, xb, wresp, bres, residb,
                           nullptr, nullptr, nullptr, nullptr, n);
}

// gemm2 standalone wrapper
__global__ __launch_bounds__(256) void gemm2_kernel(const unsigned short* __restrict__ A,
                                                    const unsigned short* __restrict__ Bp,
                                                    unsigned short* __restrict__ outB,
                                                    const float* __restrict__ asrc,
                                                    const float* __restrict__ adst,
                                                    float* __restrict__ a_s,
                                                    float* __restrict__ a_d, int M) {
    gemm_body<96, 128, 1>(blockIdx.x * 4 + (threadIdx.x >> 6), A, Bp, nullptr, outB,
                          asrc, adst, a_s, a_d, M);
}

// ---------------- GAT aggregation: 8-wide gather MLP ----------------
__global__ __launch_bounds__(256) void gat1_agg(const unsigned short* __restrict__ h1b,
                                                const float* __restrict__ a_s,
                                                const float* __restrict__ a_d,
                                                const int* __restrict__ offs,
                                                const int* __restrict__ csr,
                                                const float* __restrict__ b1,
                                                unsigned short* __restrict__ out1b, int n) {
    __shared__ int ssrc[4][64];
    __shared__ float se[4][3][64];
    int wid = threadIdx.x >> 6;
    int node = blockIdx.x * 4 + wid;
    if (node >= n) return;
    int lane = threadIdx.x & 63;
    int head = lane >> 4; if (head > 2) head = 2;
    int beg = offs[node], end = offs[node + 1];
    int deg = end - beg;
    float ad0 = a_d[node * 3 + 0], ad1 = a_d[node * 3 + 1], ad2 = a_d[node * 3 + 2];
    float es0 = leaky(a_s[node * 3 + 0] + ad0);
    float es1 = leaky(a_s[node * 3 + 1] + ad1);
    float es2 = leaky(a_s[node * 3 + 2] + ad2);
    float2 hv0 = make_float2(0.f, 0.f);
    if (lane < 48) hv0 = bf2f2(*(const unsigned int*)&h1b[(size_t)node * 96 + 2 * lane]);

    float den;
    float2 acc;

    if (deg <= 64) {
        int s = 0;
        float l0 = NEG_INF, l1 = NEG_INF, l2 = NEG_INF;
        if (lane < deg) {
            s = csr[beg + lane];
            l0 = leaky(a_s[s * 3 + 0] + ad0);
            l1 = leaky(a_s[s * 3 + 1] + ad1);
            l2 = leaky(a_s[s * 3 + 2] + ad2);
        }
        float m0 = l0, m1 = l1, m2 = l2;
#pragma unroll
        for (int sh = 32; sh >= 1; sh >>= 1) {
            m0 = fmaxf(m0, __shfl_xor(m0, sh));
            m1 = fmaxf(m1, __shfl_xor(m1, sh));
            m2 = fmaxf(m2, __shfl_xor(m2, sh));
        }
        m0 = fmaxf(m0, es0); m1 = fmaxf(m1, es1); m2 = fmaxf(m2, es2);
        float e0 = 0.f, e1 = 0.f, e2 = 0.f;
        if (lane < deg) {
            e0 = __expf(l0 - m0); e1 = __expf(l1 - m1); e2 = __expf(l2 - m2);
        }
        ssrc[wid][lane] = s;
        se[wid][0][lane] = e0; se[wid][1][lane] = e1; se[wid][2][lane] = e2;
        float w0 = __expf(es0 - m0), w1 = __expf(es1 - m1), w2 = __expf(es2 - m2);
        den = (head == 0) ? w0 : ((head == 1) ? w1 : w2);
        float wSelf = (lane < 16) ? w0 : ((lane < 32) ? w1 : w2);
        acc.x = wSelf * hv0.x; acc.y = wSelf * hv0.y;

        int jj = 0;
        for (; jj + 7 < deg; jj += 8) {
            int sA[8]; float wA[8]; unsigned ph[8];
#pragma unroll
            for (int q = 0; q < 8; ++q) {
                sA[q] = ssrc[wid][jj + q];
                wA[q] = se[wid][head][jj + q];
            }
#pragma unroll
            for (int q = 0; q < 8; ++q)
                ph[q] = (lane < 48) ? *(const unsigned*)&h1b[(size_t)sA[q] * 96 + 2 * lane] : 0u;
            float dsum = 0.f;
#pragma unroll
            for (int q = 0; q < 8; ++q) {
                dsum += wA[q];
                if (lane < 48) {
                    float2 h = bf2f2(ph[q]);
                    acc.x += wA[q] * h.x; acc.y += wA[q] * h.y;
                }
            }
            den += dsum;
        }
        for (; jj + 3 < deg; jj += 4) {
            int sA[4]; float wA[4]; unsigned ph[4];
#pragma unroll
            for (int q = 0; q < 4; ++q) {
                sA[q] = ssrc[wid][jj + q];
                wA[q] = se[wid][head][jj + q];
            }
#pragma unroll
            for (int q = 0; q < 4; ++q)
                ph[q] = (lane < 48) ? *(const unsigned*)&h1b[(size_t)sA[q] * 96 + 2 * lane] : 0u;
            float dsum = 0.f;
#pragma unroll
            for (int q = 0; q < 4; ++q) {
                dsum += wA[q];
                if (lane < 48) {
                    float2 h = bf2f2(ph[q]);
                    acc.x += wA[q] * h.x; acc.y += wA[q] * h.y;
                }
            }
            den += dsum;
        }
        for (; jj < deg; ++jj) {
            int sA = ssrc[wid][jj];
            float wA = se[wid][head][jj];
            den += wA;
            if (lane < 48) {
                float2 ha = bf2f2(*(const unsigned*)&h1b[(size_t)sA * 96 + 2 * lane]);
                acc.x += wA * ha.x; acc.y += wA * ha.y;
            }
        }
    } else {
        float m0 = es0, m1 = es1, m2 = es2;
        for (int j = beg + lane; j < end; j += 64) {
            int s = csr[j];
            m0 = fmaxf(m0, leaky(a_s[s * 3 + 0] + ad0));
            m1 = fmaxf(m1, leaky(a_s[s * 3 + 1] + ad1));
            m2 = fmaxf(m2, leaky(a_s[s * 3 + 2] + ad2));
        }
#pragma unroll
        for (int sh = 32; sh >= 1; sh >>= 1) {
            m0 = fmaxf(m0, __shfl_xor(m0, sh));
            m1 = fmaxf(m1, __shfl_xor(m1, sh));
            m2 = fmaxf(m2, __shfl_xor(m2, sh));
        }
        float w0 = __expf(es0 - m0), w1 = __expf(es1 - m1), w2 = __expf(es2 - m2);
        den = (head == 0) ? w0 : ((head == 1) ? w1 : w2);
        float wSelf = (lane < 16) ? w0 : ((lane < 32) ? w1 : w2);
        acc.x = wSelf * hv0.x; acc.y = wSelf * hv0.y;
        for (int t0 = beg; t0 < end; t0 += 64) {
            int cnt = min(64, end - t0);
            int s = 0;
            float e0 = 0.f, e1 = 0.f, e2 = 0.f;
            if (lane < cnt) {
                s = csr[t0 + lane];
                e0 = __expf(leaky(a_s[s * 3 + 0] + ad0) - m0);
                e1 = __expf(leaky(a_s[s * 3 + 1] + ad1) - m1);
                e2 = __expf(leaky(a_s[s * 3 + 2] + ad2) - m2);
            }
            ssrc[wid][lane] = s;
            se[wid][0][lane] = e0; se[wid][1][lane] = e1; se[wid][2][lane] = e2;
            int jj = 0;
            for (; jj + 7 < cnt; jj += 8) {
                int sA[8]; float wA[8]; unsigned ph[8];
#pragma unroll
                for (int q = 0; q < 8; ++q) {
                    sA[q] = ssrc[wid][jj + q];
                    wA[q] = se[wid][head][jj + q];
                }
#pragma unroll
                for (int q = 0; q < 8; ++q)
                    ph[q] = (lane < 48) ? *(const unsigned*)&h1b[(size_t)sA[q] * 96 + 2 * lane] : 0u;
                float dsum = 0.f;
#pragma unroll
                for (int q = 0; q < 8; ++q) {
                    dsum += wA[q];
                    if (lane < 48) {
                        float2 h = bf2f2(ph[q]);
                        acc.x += wA[q] * h.x; acc.y += wA[q] * h.y;
                    }
                }
                den += dsum;
            }
            for (; jj < cnt; ++jj) {
                int sA = ssrc[wid][jj];
                float wA = se[wid][head][jj];
                den += wA;
                if (lane < 48) {
                    float2 ha = bf2f2(*(const unsigned*)&h1b[(size_t)sA * 96 + 2 * lane]);
                    acc.x += wA * ha.x; acc.y += wA * ha.y;
                }
            }
        }
    }

    if (lane < 48) {
        float inv = 1.f / (den + 1e-16f);
        ushort2 o;
        o.x = f2bf(acc.x * inv + b1[2 * lane]);
        o.y = f2bf(acc.y * inv + b1[2 * lane + 1]);
        *(ushort2*)&out1b[(size_t)node * 96 + 2 * lane] = o;
    }
}

// gat2: 128 ch, 1 head; writes bf16 out2 AND accumulates BN partial sums.
__global__ __launch_bounds__(256) void gat2_agg(const unsigned short* __restrict__ h2b,
                                                const float* __restrict__ a_s,
                                                const float* __restrict__ a_d,
                                                const int* __restrict__ offs,
                                                const int* __restrict__ csr,
                                                const float* __restrict__ b2,
                                                unsigned short* __restrict__ out2b,
                                                float* __restrict__ part, int n) {
    __shared__ int ssrc[4][64];
    __shared__ float se[4][64];
    __shared__ float4 red[4][64];
    int wid = threadIdx.x >> 6;
    int node = blockIdx.x * 4 + wid;
    int lane = threadIdx.x & 63;
    float2 o = make_float2(0.f, 0.f);

    if (node < n) {
        int beg = offs[node], end = offs[node + 1];
        int deg = end - beg;
        float ad = a_d[node];
        float es = leaky(a_s[node] + ad);
        float2 hv0 = bf2f2(*(const unsigned int*)&h2b[(size_t)node * 128 + 2 * lane]);
        float den;
        float2 acc;

        if (deg <= 64) {
            int s = 0;
            float l = NEG_INF;
            if (lane < deg) {
                s = csr[beg + lane];
                l = leaky(a_s[s] + ad);
            }
            float m = l;
#pragma unroll
            for (int sh = 32; sh >= 1; sh >>= 1) m = fmaxf(m, __shfl_xor(m, sh));
            m = fmaxf(m, es);
            float e = (lane < deg) ? __expf(l - m) : 0.f;
            ssrc[wid][lane] = s;
            se[wid][lane] = e;
            float wSelf = __expf(es - m);
            den = wSelf;
            acc.x = wSelf * hv0.x; acc.y = wSelf * hv0.y;

            int jj = 0;
            for (; jj + 7 < deg; jj += 8) {
                int sA[8]; float wA[8]; unsigned ph[8];
#pragma unroll
                for (int q = 0; q < 8; ++q) {
                    sA[q] = ssrc[wid][jj + q];
                    wA[q] = se[wid][jj + q];
                }
#pragma unroll
                for (int q = 0; q < 8; ++q)
                    ph[q] = *(const unsigned*)&h2b[(size_t)sA[q] * 128 + 2 * lane];
                float dsum = 0.f;
#pragma unroll
                for (int q = 0; q < 8; ++q) {
                    dsum += wA[q];
                    float2 h = bf2f2(ph[q]);
                    acc.x += wA[q] * h.x; acc.y += wA[q] * h.y;
                }
                den += dsum;
            }
            for (; jj + 3 < deg; jj += 4) {
                int sA[4]; float wA[4]; unsigned ph[4];
#pragma unroll
                for (int q = 0; q < 4; ++q) {
                    sA[q] = ssrc[wid][jj + q];
                    wA[q] = se[wid][jj + q];
                }
#pragma unroll
                for (int q = 0; q < 4; ++q)
                    ph[q] = *(const unsigned*)&h2b[(size_t)sA[q] * 128 + 2 * lane];
                float dsum = 0.f;
#pragma unroll
                for (int q = 0; q < 4; ++q) {
                    dsum += wA[q];
                    float2 h = bf2f2(ph[q]);
                    acc.x += wA[q] * h.x; acc.y += wA[q] * h.y;
                }
                den += dsum;
            }
            for (; jj < deg; ++jj) {
                int sA = ssrc[wid][jj];
                float wA = se[wid][jj];
                den += wA;
                float2 ha = bf2f2(*(const unsigned*)&h2b[(size_t)sA * 128 + 2 * lane]);
                acc.x += wA * ha.x; acc.y += wA * ha.y;
            }
        } else {
            float m = es;
            for (int j = beg + lane; j < end; j += 64) {
                int s = csr[j];
                m = fmaxf(m, leaky(a_s[s] + ad));
            }
#pragma unroll
            for (int sh = 32; sh >= 1; sh >>= 1) m = fmaxf(m, __shfl_xor(m, sh));
            float wSelf = __expf(es - m);
            den = wSelf;
            acc.x = wSelf * hv0.x; acc.y = wSelf * hv0.y;
            for (int t0 = beg; t0 < end; t0 += 64) {
                int cnt = min(64, end - t0);
                int s = 0;
                float e = 0.f;
                if (lane < cnt) {
                    s = csr[t0 + lane];
                    e = __expf(leaky(a_s[s] + ad) - m);
                }
                ssrc[wid][lane] = s;
                se[wid][lane] = e;
                int jj = 0;
                for (; jj + 7 < cnt; jj += 8) {
                    int sA[8]; float wA[8]; unsigned ph[8];
#pragma unroll
                    for (int q = 0; q < 8; ++q) {
                        sA[q] = ssrc[wid][jj + q];
                        wA[q] = se[wid][jj + q];
                    }
#pragma unroll
                    for (int q = 0; q < 8; ++q)
                        ph[q] = *(const unsigned*)&h2b[(size_t)sA[q] * 128 + 2 * lane];
                    float dsum = 0.f;
#pragma unroll
                    for (int q = 0; q < 8; ++q) {
                        dsum += wA[q];
                        float2 h = bf2f2(ph[q]);
                        acc.x += wA[q] * h.x; acc.y += wA[q] * h.y;
                    }
                    den += dsum;
                }
                for (; jj < cnt; ++jj) {
                    int sA = ssrc[wid][jj];
                    float wA = se[wid][jj];
                    den += wA;
                    float2 ha = bf2f2(*(const unsigned*)&h2b[(size_t)sA * 128 + 2 * lane]);
                    acc.x += wA * ha.x; acc.y += wA * ha.y;
                }
            }
        }

        float inv = 1.f / (den + 1e-16f);
        o.x = acc.x * inv + b2[2 * lane];
        o.y = acc.y * inv + b2[2 * lane + 1];
        ushort2 ob;
        ob.x = f2bf(o.x); ob.y = f2bf(o.y);
        *(ushort2*)&out2b[(size_t)node * 128 + 2 * lane] = ob;
    }

    // ---- block-level BN partial reduction ----
    red[wid][lane] = make_float4(o.x, o.y, o.x * o.x, o.y * o.y);
    __syncthreads();
    if (wid == 0) {
        float4 a = red[0][lane], b = red[1][lane], c = red[2][lane], d = red[3][lane];
        float sx = a.x + b.x + c.x + d.x;
        float sy = a.y + b.y + c.y + d.y;
        float qx = a.z + b.z + c.z + d.z;
        float qy = a.w + b.w + c.w + d.w;
        float* p = part + (size_t)(blockIdx.x & 63) * 256;
        atomicAdd(&p[2 * lane + 0], sx);
        atomicAdd(&p[2 * lane + 1], sy);
        atomicAdd(&p[128 + 2 * lane + 0], qx);
        atomicAdd(&p[128 + 2 * lane + 1], qy);
    }
}

// ---------------- BN finalize ----------------
__global__ void bn_finalize(const float* __restrict__ part, const float* __restrict__ gamma,
                            const float* __restrict__ beta, float* __restrict__ ss, int n) {
    int c = threadIdx.x;  // 128
    float S = 0.f, Q = 0.f;
    for (int k = 0; k < 64; ++k) {
        S += part[(size_t)k * 256 + c];
        Q += part[(size_t)k * 256 + 128 + c];
    }
    float invN = 1.f / (float)n;
    float mu = S * invN;
    float var = Q * invN - mu * mu;
    float g = gamma[c] * rsqrtf(var + 1e-5f);
    ss[c] = g;
    ss[128 + c] = beta[c] - mu * g;
}

// ---------------- fused BN-normalize + ReLU + residual ----------------
__global__ void final_kernel(const unsigned short* __restrict__ out2b,
                             const unsigned short* __restrict__ residb,
                             const float* __restrict__ ss, float* __restrict__ out, int n) {
    int i = blockIdx.x * blockDim.x + threadIdx.x;  // over n*32 groups of 4 ch
    if (i >= n * 32) return;
    int c0 = (i & 31) * 4;
    uint2 v = ((const uint2*)out2b)[i];
    uint2 r = ((const uint2*)residb)[i];
    float2 v01 = bf2f2(v.x), v23 = bf2f2(v.y);
    float2 r01 = bf2f2(r.x), r23 = bf2f2(r.y);
    float4 o;
    o.x = fmaxf(v01.x * ss[c0 + 0] + ss[128 + c0 + 0], 0.f) + r01.x;
    o.y = fmaxf(v01.y * ss[c0 + 1] + ss[128 + c0 + 1], 0.f) + r01.y;
    o.z = fmaxf(v23.x * ss[c0 + 2] + ss[128 + c0 + 2], 0.f) + r23.x;
    o.w = fmaxf(v23.y * ss[c0 + 3] + ss[128 + c0 + 3], 0.f) + r23.y;
    ((float4*)out)[i] = o;
}

extern "C" void kernel_launch(void* const* d_in, const int* in_sizes, int n_in,
                              void* d_out, int out_size, void* d_ws, size_t ws_size,
                              hipStream_t stream) {
    const float* x     = (const float*)d_in[0];
    const int*   ei    = (const int*)d_in[1];
    const float* W1    = (const float*)d_in[2];
    const float* asrc1 = (const float*)d_in[3];
    const float* adst1 = (const float*)d_in[4];
    const float* b1    = (const float*)d_in[5];
    const float* W2    = (const float*)d_in[6];
    const float* asrc2 = (const float*)d_in[7];
    const float* adst2 = (const float*)d_in[8];
    const float* b2    = (const float*)d_in[9];
    const float* gamma = (const float*)d_in[10];
    const float* beta  = (const float*)d_in[11];
    const float* Wres  = (const float*)d_in[12];
    const float* bres  = (const float*)d_in[13];

    const int n = in_sizes[0] / 128;  // 50000
    const int E = in_sizes[1] / 2;    // 800000

    char* ws = (char*)d_ws;
    size_t off = 0;
    auto alloc = [&](size_t bytes) {
        void* p = ws + off;
        off = (off + bytes + 255) & ~(size_t)255;
        return p;
    };
    float* as1  = (float*)alloc((size_t)n * 3 * 4);
    float* ad1  = (float*)alloc((size_t)n * 3 * 4);
    float* as2  = (float*)alloc((size_t)n * 4);
    float* ad2  = (float*)alloc((size_t)n * 4);
    float* part = (float*)alloc(64 * 256 * 4);
    float* ss   = (float*)alloc(256 * 4);
    unsigned short* xb     = (unsigned short*)alloc((size_t)n * 128 * 2);
    unsigned short* h1b    = (unsigned short*)alloc((size_t)n * 96 * 2);
    unsigned short* h2b    = (unsigned short*)alloc((size_t)n * 128 * 2);
    unsigned short* out1b  = (unsigned short*)alloc((size_t)n * 96 * 2);
    unsigned short* out2b  = (unsigned short*)alloc((size_t)n * 128 * 2);
    unsigned short* residb = (unsigned short*)alloc((size_t)n * 128 * 2);
    unsigned short* w1p    = (unsigned short*)alloc(128 * 96 * 2);
    unsigned short* w2p    = (unsigned short*)alloc(96 * 128 * 2);
    unsigned short* wresp  = (unsigned short*)alloc(128 * 128 * 2);
    int* offs      = (int*)alloc((size_t)(n + 1) * 4);
    int* bucketCnt = (int*)alloc(1600 * 4);
    int* pairBase  = (int*)alloc(1601 * 4);
    int* bcur      = (int*)alloc(1600 * 4);
    int2* pairBuf  = (int2*)alloc((size_t)E * 8);
    int* csr       = (int*)alloc((size_t)E * 4);

    hipMemsetAsync(bucketCnt, 0, 1600 * 4, stream);
    hipMemsetAsync(part, 0, 64 * 256 * 4, stream);

    const int* srcIdx = ei;
    const int* dstIdx = ei + E;
    const int NB = (n + 31) / 32;  // 1563 buckets
    const int binBlks = (E + 4095) / 4096;  // 196

    // fused prep: bucket-hist + x->bf16 + 3 weight packs
    const int nxb = (n * 32 + 255) / 256;
    prep_kernel<<<binBlks + nxb + 160, 256, 0, stream>>>(x, xb, n * 32, W1, w1p, W2, w2p,
                                                         Wres, wresp, dstIdx, E,
                                                         bucketCnt, NB, binBlks);

    scan_buckets<<<1, 1024, 0, stream>>>(bucketCnt, pairBase, bcur, offs, NB, n);

    // bin edges into 32-node buckets (L2-local appends)
    bin_kernel<<<binBlks, 256, 0, stream>>>(srcIdx, dstIdx, E, bcur, pairBuf, NB);

    const int mt = (n + 15) / 16;   // 3125 row tiles
    const int gblk = (mt + 3) / 4;  // 782
    const int passBlks = 391;       // 1564 waves >= NB buckets

    // phase2: passB (degree+offs+scatter) + gemm1(+att1) + gemm_res
    phase2_kernel<<<passBlks + 2 * gblk, 256, 0, stream>>>(
        pairBuf, pairBase, bcur, offs, csr, NB, xb, w1p, h1b, asrc1, adst1, as1, ad1,
        wresp, bres, residb, n, passBlks, gblk);

    gat1_agg<<<(n + 3) / 4, 256, 0, stream>>>(h1b, as1, ad1, offs, csr, b1, out1b, n);
    gemm2_kernel<<<gblk, 256, 0, stream>>>(out1b, w2p, h2b, asrc2, adst2, as2, ad2, n);
    gat2_agg<<<(n + 3) / 4, 256, 0, stream>>>(h2b, as2, ad2, offs, csr, b2, out2b, part, n);
    bn_finalize<<<1, 128, 0, stream>>>(part, gamma, beta, ss, n);
    final_kernel<<<(n * 32 + 255) / 256, 256, 0, stream>>>(out2b, residb, ss, (float*)d_out, n);
}